// Round 1
// baseline (1176.134 us; speedup 1.0000x reference)
//
#include <hip/hip_runtime.h>
#include <hip/hip_bf16.h>
#include <math.h>

typedef unsigned short u16;
typedef __attribute__((ext_vector_type(8))) __bf16 bf16x8;
typedef __attribute__((ext_vector_type(4))) float f32x4;
typedef __attribute__((ext_vector_type(8))) u16 u16x8;

#define T_SEQ 2048
#define DMODEL 2048
#define NH 16
#define DHEAD 128
#define BATCH 4
#define ATTN_SCALE 0.08838834764831845f

// async global->LDS, 16B per lane, wave-uniform LDS base + lane*16
#define GLOAD(gp, lp) __builtin_amdgcn_global_load_lds( \
    (const __attribute__((address_space(1))) void*)(gp), \
    (__attribute__((address_space(3))) void*)(lp), 16, 0, 0)

__device__ __forceinline__ float b2f(u16 u) {
  union { float f; unsigned int i; } x; x.i = ((unsigned int)u) << 16; return x.f;
}
__device__ __forceinline__ u16 f2b(float f) {
  union { float f; unsigned int i; } x; x.f = f;
  unsigned int r = x.i + 0x7fffu + ((x.i >> 16) & 1u);
  return (u16)(r >> 16);
}

// ---------------- cast x: f32 -> bf16 ----------------
__global__ __launch_bounds__(256) void cast_f32_bf16(const float* __restrict__ in,
                                                     u16* __restrict__ out) {
  long i = ((long)blockIdx.x * 256 + threadIdx.x) * 8;
  float4 a = *(const float4*)(in + i);
  float4 b = *(const float4*)(in + i + 4);
  u16x8 r;
  r[0] = f2b(a.x); r[1] = f2b(a.y); r[2] = f2b(a.z); r[3] = f2b(a.w);
  r[4] = f2b(b.x); r[5] = f2b(b.y); r[6] = f2b(b.z); r[7] = f2b(b.w);
  *(u16x8*)(out + i) = r;
}

// ---------------- weight transpose + cast: W[k][n] f32 -> Wt[n][k] bf16 ----------------
__global__ __launch_bounds__(256) void wtrans_kernel(const float* __restrict__ W,
                                                     u16* __restrict__ Wt) {
  __shared__ float tile[64][65];
  const int k0 = blockIdx.x * 64, n0 = blockIdx.y * 64;
  const int c = threadIdx.x & 63, r4 = threadIdx.x >> 6;
#pragma unroll
  for (int p = 0; p < 16; p++) {
    int r = p * 4 + r4;
    tile[r][c] = W[(long)(k0 + r) * DMODEL + n0 + c];
  }
  __syncthreads();
#pragma unroll
  for (int p = 0; p < 16; p++) {
    int r = p * 4 + r4;
    Wt[(long)(n0 + r) * DMODEL + k0 + c] = f2b(tile[c][r]);
  }
}

// ---------------- V transpose per (b,h): V[b*T+s][h*128+f] -> Vt[(bh*128+f)][s] ----------------
__global__ __launch_bounds__(256) void vtrans_kernel(const u16* __restrict__ V,
                                                     u16* __restrict__ Vt) {
  __shared__ u16 tile[64][66];
  const int s0 = blockIdx.x * 64, f0 = blockIdx.y * 64;
  const int bh = blockIdx.z;
  const int b = bh >> 4, h = bh & 15;
  const int c = threadIdx.x & 63, r4 = threadIdx.x >> 6;
#pragma unroll
  for (int p = 0; p < 16; p++) {
    int r = p * 4 + r4; // s-local
    tile[r][c] = V[(long)(b * T_SEQ + s0 + r) * DMODEL + h * DHEAD + f0 + c];
  }
  __syncthreads();
#pragma unroll
  for (int p = 0; p < 16; p++) {
    int r = p * 4 + r4; // f-local
    Vt[(long)(bh * DHEAD + f0 + r) * T_SEQ + s0 + c] = tile[c][r];
  }
}

// ---------------- RoPE in place on bf16 [B*T][D], interleaved pairs ----------------
__global__ __launch_bounds__(256) void rope_kernel(u16* __restrict__ X) {
  int idx = blockIdx.x * 256 + threadIdx.x;  // B*T*H*16 threads, 4 pairs each
  int i4 = idx & 15;
  int h = (idx >> 4) & 15;
  long bt = idx >> 8;
  int t = (int)(bt & (T_SEQ - 1));
  long off = bt * DMODEL + h * DHEAD + i4 * 8;
  u16x8 v = *(u16x8*)(X + off);
  float o[8];
#pragma unroll
  for (int j = 0; j < 4; j++) {
    int i = i4 * 4 + j;                 // pair index 0..63
    float inv = powf(10000.0f, -(float)i / 64.0f);
    float ang = (float)t * inv;
    float cs = cosf(ang), sn = sinf(ang);
    float x0 = b2f(v[2 * j]), x1 = b2f(v[2 * j + 1]);
    o[2 * j]     = x0 * cs - x1 * sn;
    o[2 * j + 1] = x1 * cs + x0 * sn;
  }
  u16x8 r;
#pragma unroll
  for (int j = 0; j < 8; j++) r[j] = f2b(o[j]);
  *(u16x8*)(X + off) = r;
}

// ---------------- GEMM: C[M][N] = A[M][K] * Bt[N][K]^T (bf16 in, f32 acc) ----------------
// m97 structure: 128x128 tile, BK=32, 4 waves in 2x2, 16x16x32 MFMA, global_load_lds w=16.
template <int OUT_F32>
__global__ __launch_bounds__(256, 2) void gemm_bt(const u16* __restrict__ A,
                                                  const u16* __restrict__ Bt,
                                                  void* __restrict__ Cv,
                                                  int M, int N, int K) {
  __shared__ u16 lA[128 * 32];
  __shared__ u16 lB[128 * 32];
  const int tid = threadIdx.x;
  const int lane = tid & 63;
  const int w = tid >> 6;
  const int wr = w >> 1, wc = w & 1;
  const int lr = lane & 15, lc = lane >> 4;
  const long row0 = (long)blockIdx.x * 128;
  const long col0 = (long)blockIdx.y * 128;
  f32x4 acc[4][4] = {};

  for (int kt = 0; kt < K; kt += 32) {
#pragma unroll
    for (int i = 0; i < 2; i++) {
      int sb = (w * 2 + i) * 64;
      int slot = sb + lane;
      int r = slot >> 2;
      int cb = (slot & 3) * 8;  // element offset of 16B chunk
      GLOAD(A + (row0 + r) * (long)K + kt + cb, &lA[sb * 8]);
      GLOAD(Bt + (col0 + r) * (long)K + kt + cb, &lB[sb * 8]);
    }
    __syncthreads();
    bf16x8 af[4], bfr[4];
#pragma unroll
    for (int m = 0; m < 4; m++)
      af[m] = *(const bf16x8*)&lA[(wr * 64 + m * 16 + lr) * 32 + lc * 8];
#pragma unroll
    for (int n = 0; n < 4; n++)
      bfr[n] = *(const bf16x8*)&lB[(wc * 64 + n * 16 + lr) * 32 + lc * 8];
#pragma unroll
    for (int m = 0; m < 4; m++)
#pragma unroll
      for (int n = 0; n < 4; n++)
        acc[m][n] = __builtin_amdgcn_mfma_f32_16x16x32_bf16(af[m], bfr[n], acc[m][n], 0, 0, 0);
    __syncthreads();
  }
#pragma unroll
  for (int m = 0; m < 4; m++)
#pragma unroll
    for (int n = 0; n < 4; n++)
#pragma unroll
      for (int i = 0; i < 4; i++) {
        long row = row0 + wr * 64 + m * 16 + lc * 4 + i;
        long col = col0 + wc * 64 + n * 16 + lr;
        float v = acc[m][n][i];
        if (OUT_F32) ((float*)Cv)[row * N + col] = v;
        else ((u16*)Cv)[row * N + col] = f2b(v);
      }
}

// ---------------- flash attention ----------------
// grid (qt=16, bh=64), 256 thr = 4 waves, each wave owns 32 q-rows of the 128-row q-tile.
// K-tile [128 s][128 f] and Vt-tile [128 f][128 s] in LDS, XOR-swizzled (chunk ^= row&7)
// via pre-swizzled global source. P reuses the K buffer after a barrier.
__global__ __launch_bounds__(256, 2) void attn_kernel(const u16* __restrict__ Q,
                                                      const u16* __restrict__ K,
                                                      const u16* __restrict__ Vt,
                                                      u16* __restrict__ Y) {
  __shared__ u16 lK[128 * 128];  // K tile, later P tile (per-wave 32-row regions)
  __shared__ u16 lV[128 * 128];  // Vt tile
  const int tid = threadIdx.x, lane = tid & 63, w = tid >> 6;
  const int qt = blockIdx.x, bh = blockIdx.y;
  const int b = bh >> 4, h = bh & 15;
  const int lr = lane & 15, lc = lane >> 4;

  // Q fragments resident in registers: rows w*32.., all 128 f
  bf16x8 qf[2][4];
  const long qbase = (long)(b * T_SEQ + qt * 128 + w * 32) * DMODEL + h * DHEAD;
#pragma unroll
  for (int m = 0; m < 2; m++)
#pragma unroll
    for (int ks = 0; ks < 4; ks++)
      qf[m][ks] = *(const bf16x8*)(Q + qbase + (long)(m * 16 + lr) * DMODEL + ks * 32 + lc * 8);

  f32x4 o_acc[2][8] = {};
  float m_st[8], l_st[8];
#pragma unroll
  for (int ri = 0; ri < 8; ri++) { m_st[ri] = -INFINITY; l_st[ri] = 0.f; }

  for (int kt = 0; kt <= qt; kt++) {
    // stage K and Vt tiles (pre-swizzled source so swizzled data lands at linear dst)
#pragma unroll
    for (int j = 0; j < 8; j++) {
      int sb = (w * 8 + j) * 64;
      int slot = sb + lane;
      int r = slot >> 4;          // row (s for K, f for Vt)
      int pc = slot & 15;         // physical 16B chunk
      int cc = pc ^ (r & 7);      // logical chunk
      GLOAD(K + (long)(b * T_SEQ + kt * 128 + r) * DMODEL + h * DHEAD + cc * 8, &lK[sb * 8]);
      GLOAD(Vt + (long)(bh * DHEAD + r) * T_SEQ + kt * 128 + cc * 8, &lV[sb * 8]);
    }
    __syncthreads();

    // S = Q K^T for this wave's 32 q-rows x 128 s
    f32x4 s_acc[2][8] = {};
#pragma unroll
    for (int ks = 0; ks < 4; ks++) {
#pragma unroll
      for (int n = 0; n < 8; n++) {
        int row = n * 16 + lr;
        int pc = (ks * 4 + lc) ^ (row & 7);
        bf16x8 kf = *(const bf16x8*)&lK[row * 128 + pc * 8];
        s_acc[0][n] = __builtin_amdgcn_mfma_f32_16x16x32_bf16(qf[0][ks], kf, s_acc[0][n], 0, 0, 0);
        s_acc[1][n] = __builtin_amdgcn_mfma_f32_16x16x32_bf16(qf[1][ks], kf, s_acc[1][n], 0, 0, 0);
      }
    }

    // scale + causal mask (only diagonal tile needs masking)
    const bool diag = (kt == qt);
#pragma unroll
    for (int m = 0; m < 2; m++)
#pragma unroll
      for (int n = 0; n < 8; n++)
#pragma unroll
        for (int i = 0; i < 4; i++) {
          float v = s_acc[m][n][i] * ATTN_SCALE;
          if (diag) {
            int sc = n * 16 + lr;
            int qr = w * 32 + m * 16 + lc * 4 + i;
            if (sc > qr) v = -1e30f;
          }
          s_acc[m][n][i] = v;
        }

    // online softmax (row state replicated over the 16 lanes sharing each row)
#pragma unroll
    for (int m = 0; m < 2; m++)
#pragma unroll
      for (int i = 0; i < 4; i++) {
        int ri = m * 4 + i;
        float mx = -1e30f;
#pragma unroll
        for (int n = 0; n < 8; n++) mx = fmaxf(mx, s_acc[m][n][i]);
#pragma unroll
        for (int d = 1; d < 16; d <<= 1) mx = fmaxf(mx, __shfl_xor(mx, d, 64));
        float mnew = fmaxf(m_st[ri], mx);
        float corr = __expf(m_st[ri] - mnew);
        float rs = 0.f;
#pragma unroll
        for (int n = 0; n < 8; n++) {
          float p = __expf(s_acc[m][n][i] - mnew);
          s_acc[m][n][i] = p;
          rs += p;
        }
#pragma unroll
        for (int d = 1; d < 16; d <<= 1) rs += __shfl_xor(rs, d, 64);
        l_st[ri] = l_st[ri] * corr + rs;
        m_st[ri] = mnew;
#pragma unroll
        for (int n = 0; n < 8; n++) o_acc[m][n][i] *= corr;
      }

    __syncthreads();  // everyone done reading K -> safe to overwrite with P

    // write P (bf16) into the K buffer, same swizzle; each wave its own 32 rows
#pragma unroll
    for (int m = 0; m < 2; m++)
#pragma unroll
      for (int n = 0; n < 8; n++)
#pragma unroll
        for (int i = 0; i < 4; i++) {
          int prow = w * 32 + m * 16 + lc * 4 + i;
          int pcol = n * 16 + lr;
          int pc = (pcol >> 3) ^ (prow & 7);
          lK[prow * 128 + pc * 8 + (pcol & 7)] = f2b(s_acc[m][n][i]);
        }
    // wave reads only its own P rows -> no barrier needed (compiler orders ds ops)

    // O += P V
#pragma unroll
    for (int ks = 0; ks < 4; ks++) {
      bf16x8 pf[2];
#pragma unroll
      for (int m = 0; m < 2; m++) {
        int row = w * 32 + m * 16 + lr;
        int pc = (ks * 4 + lc) ^ (row & 7);
        pf[m] = *(const bf16x8*)&lK[row * 128 + pc * 8];
      }
#pragma unroll
      for (int n = 0; n < 8; n++) {
        int row = n * 16 + lr;
        int pc = (ks * 4 + lc) ^ (row & 7);
        bf16x8 vf = *(const bf16x8*)&lV[row * 128 + pc * 8];
        o_acc[0][n] = __builtin_amdgcn_mfma_f32_16x16x32_bf16(pf[0], vf, o_acc[0][n], 0, 0, 0);
        o_acc[1][n] = __builtin_amdgcn_mfma_f32_16x16x32_bf16(pf[1], vf, o_acc[1][n], 0, 0, 0);
      }
    }
    __syncthreads();  // all reads of lK/lV done before next stage
  }

  // epilogue: O /= l, write bf16
  const long ybase = (long)(b * T_SEQ + qt * 128 + w * 32) * DMODEL + h * DHEAD;
#pragma unroll
  for (int m = 0; m < 2; m++)
#pragma unroll
    for (int n = 0; n < 8; n++)
#pragma unroll
      for (int i = 0; i < 4; i++) {
        float v = o_acc[m][n][i] / l_st[m * 4 + i];
        Y[ybase + (long)(m * 16 + lc * 4 + i) * DMODEL + n * 16 + lr] = f2b(v);
      }
}

extern "C" void kernel_launch(void* const* d_in, const int* in_sizes, int n_in,
                              void* d_out, int out_size, void* d_ws, size_t ws_size,
                              hipStream_t stream) {
  const float* x  = (const float*)d_in[0];
  const float* Wq = (const float*)d_in[1];
  const float* Wk = (const float*)d_in[2];
  const float* Wv = (const float*)d_in[3];
  const float* Wo = (const float*)d_in[4];
  float* out = (float*)d_out;
  char* ws = (char*)d_ws;

  const long MB32 = 33554432L;  // 8192*2048 bf16
  u16* xb  = (u16*)(ws);                       // x bf16; later aliased by Vt
  u16* Wqt = (u16*)(ws + MB32);
  u16* Wkt = (u16*)(ws + MB32 + 8388608L);
  u16* Wvt = (u16*)(ws + MB32 + 16777216L);
  u16* Wot = (u16*)(ws + MB32 + 25165824L);
  u16* Qb  = (u16*)(ws + 2 * MB32);
  u16* Kb  = (u16*)(ws + 3 * MB32);
  u16* Vb  = (u16*)(ws + 4 * MB32);
  u16* Vtb = xb;   // alias: xb dead after V projection
  u16* Yb  = Vb;   // alias: Vb dead after vtrans
  // total ws usage: 5*32MiB = 160 MiB

  cast_f32_bf16<<<8192, 256, 0, stream>>>(x, xb);
  dim3 wt_g(32, 32);
  wtrans_kernel<<<wt_g, 256, 0, stream>>>(Wq, Wqt);
  wtrans_kernel<<<wt_g, 256, 0, stream>>>(Wk, Wkt);
  wtrans_kernel<<<wt_g, 256, 0, stream>>>(Wv, Wvt);
  wtrans_kernel<<<wt_g, 256, 0, stream>>>(Wo, Wot);

  dim3 gg(64, 16);
  gemm_bt<0><<<gg, 256, 0, stream>>>(xb, Wqt, Qb, 8192, 2048, 2048);
  gemm_bt<0><<<gg, 256, 0, stream>>>(xb, Wkt, Kb, 8192, 2048, 2048);
  gemm_bt<0><<<gg, 256, 0, stream>>>(xb, Wvt, Vb, 8192, 2048, 2048);

  rope_kernel<<<8192, 256, 0, stream>>>(Qb);
  rope_kernel<<<8192, 256, 0, stream>>>(Kb);

  dim3 vt_g(32, 2, 64);
  vtrans_kernel<<<vt_g, 256, 0, stream>>>(Vb, Vtb);

  dim3 at_g(16, 64);
  attn_kernel<<<at_g, 256, 0, stream>>>(Qb, Kb, Vtb, Yb);

  gemm_bt<1><<<gg, 256, 0, stream>>>(Yb, Wot, (void*)out, 8192, 2048, 2048);
}

// Round 2
// 589.509 us; speedup vs baseline: 1.9951x; 1.9951x over previous
//
#include <hip/hip_runtime.h>
#include <hip/hip_bf16.h>
#include <math.h>

typedef unsigned short u16;
typedef __attribute__((ext_vector_type(8))) __bf16 bf16x8;
typedef __attribute__((ext_vector_type(4))) float f32x4;
typedef __attribute__((ext_vector_type(8))) u16 u16x8;

#define T_SEQ 2048
#define DMODEL 2048
#define NH 16
#define DHEAD 128
#define BATCH 4
#define ATTN_SCALE 0.08838834764831845f

// async global->LDS, 16B per lane, wave-uniform LDS base + lane*16
#define GLOAD(gp, lp) __builtin_amdgcn_global_load_lds( \
    (const __attribute__((address_space(1))) void*)(gp), \
    (__attribute__((address_space(3))) void*)(lp), 16, 0, 0)

__device__ __forceinline__ float b2f(u16 u) {
  union { float f; unsigned int i; } x; x.i = ((unsigned int)u) << 16; return x.f;
}
__device__ __forceinline__ u16 f2b(float f) {
  union { float f; unsigned int i; } x; x.f = f;
  unsigned int r = x.i + 0x7fffu + ((x.i >> 16) & 1u);
  return (u16)(r >> 16);
}

// ---------------- cast x: f32 -> bf16 ----------------
__global__ __launch_bounds__(256) void cast_f32_bf16(const float* __restrict__ in,
                                                     u16* __restrict__ out) {
  long i = ((long)blockIdx.x * 256 + threadIdx.x) * 8;
  float4 a = *(const float4*)(in + i);
  float4 b = *(const float4*)(in + i + 4);
  u16x8 r;
  r[0] = f2b(a.x); r[1] = f2b(a.y); r[2] = f2b(a.z); r[3] = f2b(a.w);
  r[4] = f2b(b.x); r[5] = f2b(b.y); r[6] = f2b(b.z); r[7] = f2b(b.w);
  *(u16x8*)(out + i) = r;
}

// ---------------- weight transpose + cast: W[k][n] f32 -> Wt[n][k] bf16 ----------------
__global__ __launch_bounds__(256) void wtrans_kernel(const float* __restrict__ W,
                                                     u16* __restrict__ Wt) {
  __shared__ float tile[64][65];
  const int k0 = blockIdx.x * 64, n0 = blockIdx.y * 64;
  const int c = threadIdx.x & 63, r4 = threadIdx.x >> 6;
#pragma unroll
  for (int p = 0; p < 16; p++) {
    int r = p * 4 + r4;
    tile[r][c] = W[(long)(k0 + r) * DMODEL + n0 + c];
  }
  __syncthreads();
#pragma unroll
  for (int p = 0; p < 16; p++) {
    int r = p * 4 + r4;
    Wt[(long)(n0 + r) * DMODEL + k0 + c] = f2b(tile[c][r]);
  }
}

// ---------------- V transpose per (b,h): V[b*T+s][h*128+f] -> Vt[(bh*128+f)][s] ----------------
__global__ __launch_bounds__(256) void vtrans_kernel(const u16* __restrict__ V,
                                                     u16* __restrict__ Vt) {
  __shared__ u16 tile[64][66];
  const int s0 = blockIdx.x * 64, f0 = blockIdx.y * 64;
  const int bh = blockIdx.z;
  const int b = bh >> 4, h = bh & 15;
  const int c = threadIdx.x & 63, r4 = threadIdx.x >> 6;
#pragma unroll
  for (int p = 0; p < 16; p++) {
    int r = p * 4 + r4; // s-local
    tile[r][c] = V[(long)(b * T_SEQ + s0 + r) * DMODEL + h * DHEAD + f0 + c];
  }
  __syncthreads();
#pragma unroll
  for (int p = 0; p < 16; p++) {
    int r = p * 4 + r4; // f-local
    Vt[(long)(bh * DHEAD + f0 + r) * T_SEQ + s0 + c] = tile[c][r];
  }
}

// ---------------- RoPE in place on bf16 [B*T][D], interleaved pairs ----------------
__global__ __launch_bounds__(256) void rope_kernel(u16* __restrict__ X) {
  int idx = blockIdx.x * 256 + threadIdx.x;  // B*T*H*16 threads, 4 pairs each
  int i4 = idx & 15;
  int h = (idx >> 4) & 15;
  long bt = idx >> 8;
  int t = (int)(bt & (T_SEQ - 1));
  long off = bt * DMODEL + h * DHEAD + i4 * 8;
  u16x8 v = *(u16x8*)(X + off);
  float o[8];
#pragma unroll
  for (int j = 0; j < 4; j++) {
    int i = i4 * 4 + j;                 // pair index 0..63
    float inv = powf(10000.0f, -(float)i / 64.0f);
    float ang = (float)t * inv;
    float cs = cosf(ang), sn = sinf(ang);
    float x0 = b2f(v[2 * j]), x1 = b2f(v[2 * j + 1]);
    o[2 * j]     = x0 * cs - x1 * sn;
    o[2 * j + 1] = x1 * cs + x0 * sn;
  }
  u16x8 r;
#pragma unroll
  for (int j = 0; j < 8; j++) r[j] = f2b(o[j]);
  *(u16x8*)(X + off) = r;
}

// ---------------- GEMM: C[M][N] = A[M][K] * Bt[N][K]^T (bf16 in, f32 acc) ----------------
// m97 structure: 128x128 tile, BK=32, 4 waves in 2x2, 16x16x32 MFMA, global_load_lds w=16.
template <int OUT_F32>
__global__ __launch_bounds__(256, 2) void gemm_bt(const u16* __restrict__ A,
                                                  const u16* __restrict__ Bt,
                                                  void* __restrict__ Cv,
                                                  int M, int N, int K) {
  __shared__ u16 lA[128 * 32];
  __shared__ u16 lB[128 * 32];
  const int tid = threadIdx.x;
  const int lane = tid & 63;
  const int w = tid >> 6;
  const int wr = w >> 1, wc = w & 1;
  const int lr = lane & 15, lc = lane >> 4;
  const long row0 = (long)blockIdx.x * 128;
  const long col0 = (long)blockIdx.y * 128;
  f32x4 acc[4][4] = {};

  for (int kt = 0; kt < K; kt += 32) {
#pragma unroll
    for (int i = 0; i < 2; i++) {
      int sb = (w * 2 + i) * 64;
      int slot = sb + lane;
      int r = slot >> 2;
      int cb = (slot & 3) * 8;  // element offset of 16B chunk
      GLOAD(A + (row0 + r) * (long)K + kt + cb, &lA[sb * 8]);
      GLOAD(Bt + (col0 + r) * (long)K + kt + cb, &lB[sb * 8]);
    }
    __syncthreads();
    bf16x8 af[4], bfr[4];
#pragma unroll
    for (int m = 0; m < 4; m++)
      af[m] = *(const bf16x8*)&lA[(wr * 64 + m * 16 + lr) * 32 + lc * 8];
#pragma unroll
    for (int n = 0; n < 4; n++)
      bfr[n] = *(const bf16x8*)&lB[(wc * 64 + n * 16 + lr) * 32 + lc * 8];
#pragma unroll
    for (int m = 0; m < 4; m++)
#pragma unroll
      for (int n = 0; n < 4; n++)
        acc[m][n] = __builtin_amdgcn_mfma_f32_16x16x32_bf16(af[m], bfr[n], acc[m][n], 0, 0, 0);
    __syncthreads();
  }
#pragma unroll
  for (int m = 0; m < 4; m++)
#pragma unroll
    for (int n = 0; n < 4; n++)
#pragma unroll
      for (int i = 0; i < 4; i++) {
        long row = row0 + wr * 64 + m * 16 + lc * 4 + i;
        long col = col0 + wc * 64 + n * 16 + lr;
        float v = acc[m][n][i];
        if (OUT_F32) ((float*)Cv)[row * N + col] = v;
        else ((u16*)Cv)[row * N + col] = f2b(v);
      }
}

// ---------------- flash attention, double-buffered ----------------
// 1024 blocks (qt 0..15 x bh 0..63), longest-first dispatch. 256 thr = 4 waves,
// each wave owns 32 q-rows of the 128-row q-tile. KVBLK=64.
// LDS: K dbuf 2x16KB + Vt dbuf 2x16KB + P 16KB = 80KB -> 2 blocks/CU.
// Prefetch tile kt+1 before computing kt; single barrier per iteration.
__global__ __launch_bounds__(256, 2) void attn_kernel(const u16* __restrict__ Q,
                                                      const u16* __restrict__ K,
                                                      const u16* __restrict__ Vt,
                                                      u16* __restrict__ Y) {
  __shared__ u16 lK[2][64 * 128];   // K tile: 64 s-rows x 128 f (swizzled)
  __shared__ u16 lV[2][128 * 64];   // Vt tile: 128 f-rows x 64 s (swizzled)
  __shared__ u16 lP[128 * 64];      // P tile: 128 q-rows x 64 s (per-wave regions)
  const int tid = threadIdx.x, lane = tid & 63, w = tid >> 6;
  const int id = blockIdx.x;
  const int qt = 15 - (id >> 6);    // longest blocks dispatched first
  const int bh = id & 63;
  const int b = bh >> 4, h = bh & 15;
  const int lr = lane & 15, lc = lane >> 4;

  // Q fragments resident in registers: rows w*32.., all 128 f
  bf16x8 qf[2][4];
  const long qbase = (long)(b * T_SEQ + qt * 128 + w * 32) * DMODEL + h * DHEAD;
#pragma unroll
  for (int m = 0; m < 2; m++)
#pragma unroll
    for (int ks = 0; ks < 4; ks++)
      qf[m][ks] = *(const bf16x8*)(Q + qbase + (long)(m * 16 + lr) * DMODEL + ks * 32 + lc * 8);

  f32x4 o_acc[2][8] = {};
  float m_st[8], l_st[8];
#pragma unroll
  for (int ri = 0; ri < 8; ri++) { m_st[ri] = -INFINITY; l_st[ri] = 0.f; }

  const int nt = (qt + 1) * 2;

  // stage K+V tile kt into buffer nb (pre-swizzled global source, linear LDS dst)
#define STAGE(nb, kt_)                                                              \
  {                                                                                 \
    _Pragma("unroll")                                                               \
    for (int j = 0; j < 4; j++) {                                                   \
      int sb = (w * 4 + j) * 64;                                                    \
      int slot = sb + lane;                                                         \
      { int r = slot >> 4, pc = slot & 15, cc = pc ^ (r & 7);                       \
        GLOAD(K + (long)(b * T_SEQ + (kt_) * 64 + r) * DMODEL + h * DHEAD + cc * 8, \
              &lK[nb][sb * 8]); }                                                   \
      { int r = slot >> 3, pc = slot & 7, cc = pc ^ (r & 7);                        \
        GLOAD(Vt + (long)(bh * DHEAD + r) * T_SEQ + (kt_) * 64 + cc * 8,            \
              &lV[nb][sb * 8]); }                                                   \
    }                                                                               \
  }

  STAGE(0, 0);
  __syncthreads();  // buf0 ready (barrier drains vmcnt)

  for (int kt = 0; kt < nt; kt++) {
    const int cur = kt & 1;
    if (kt + 1 < nt) STAGE(cur ^ 1, kt + 1);  // in flight during this iter's compute

    // S = Q K^T for this wave's 32 q-rows x 64 s
    f32x4 s_acc[2][4] = {};
    __builtin_amdgcn_s_setprio(1);
#pragma unroll
    for (int ks = 0; ks < 4; ks++) {
#pragma unroll
      for (int n = 0; n < 4; n++) {
        int row = n * 16 + lr;
        int pc = (ks * 4 + lc) ^ (row & 7);
        bf16x8 kf = *(const bf16x8*)&lK[cur][row * 128 + pc * 8];
        s_acc[0][n] = __builtin_amdgcn_mfma_f32_16x16x32_bf16(qf[0][ks], kf, s_acc[0][n], 0, 0, 0);
        s_acc[1][n] = __builtin_amdgcn_mfma_f32_16x16x32_bf16(qf[1][ks], kf, s_acc[1][n], 0, 0, 0);
      }
    }
    __builtin_amdgcn_s_setprio(0);

    // scale + causal mask (only last two kv tiles overlap the diagonal)
    const bool diag = (kt >= qt * 2);
#pragma unroll
    for (int m = 0; m < 2; m++)
#pragma unroll
      for (int n = 0; n < 4; n++)
#pragma unroll
        for (int i = 0; i < 4; i++) {
          float v = s_acc[m][n][i] * ATTN_SCALE;
          if (diag) {
            int sc = kt * 64 + n * 16 + lr;
            int qr = qt * 128 + w * 32 + m * 16 + lc * 4 + i;
            if (sc > qr) v = -1e30f;
          }
          s_acc[m][n][i] = v;
        }

    // online softmax (row state replicated over the 16 lanes sharing each row)
#pragma unroll
    for (int m = 0; m < 2; m++)
#pragma unroll
      for (int i = 0; i < 4; i++) {
        int ri = m * 4 + i;
        float mx = -1e30f;
#pragma unroll
        for (int n = 0; n < 4; n++) mx = fmaxf(mx, s_acc[m][n][i]);
#pragma unroll
        for (int d = 1; d < 16; d <<= 1) mx = fmaxf(mx, __shfl_xor(mx, d, 64));
        float mnew = fmaxf(m_st[ri], mx);
        float corr = __expf(m_st[ri] - mnew);
        float rs = 0.f;
#pragma unroll
        for (int n = 0; n < 4; n++) {
          float p = __expf(s_acc[m][n][i] - mnew);
          s_acc[m][n][i] = p;
          rs += p;
        }
#pragma unroll
        for (int d = 1; d < 16; d <<= 1) rs += __shfl_xor(rs, d, 64);
        l_st[ri] = l_st[ri] * corr + rs;
        m_st[ri] = mnew;
#pragma unroll
        for (int n = 0; n < 8; n++) o_acc[m][n][i] *= corr;
      }

    // write P (bf16) into own wave's rows of lP, swizzled; read back below (same wave)
#pragma unroll
    for (int m = 0; m < 2; m++)
#pragma unroll
      for (int n = 0; n < 4; n++)
#pragma unroll
        for (int i = 0; i < 4; i++) {
          int prow = w * 32 + m * 16 + lc * 4 + i;
          int pcol = n * 16 + lr;
          int pc = (pcol >> 3) ^ (prow & 7);
          lP[prow * 64 + pc * 8 + (pcol & 7)] = f2b(s_acc[m][n][i]);
        }

    // O += P V
    __builtin_amdgcn_s_setprio(1);
#pragma unroll
    for (int ks = 0; ks < 2; ks++) {
      bf16x8 pf[2];
#pragma unroll
      for (int m = 0; m < 2; m++) {
        int row = w * 32 + m * 16 + lr;
        int pc = (ks * 4 + lc) ^ (row & 7);
        pf[m] = *(const bf16x8*)&lP[row * 64 + pc * 8];
      }
#pragma unroll
      for (int n = 0; n < 8; n++) {
        int row = n * 16 + lr;
        int pc = (ks * 4 + lc) ^ (row & 7);
        bf16x8 vf = *(const bf16x8*)&lV[cur][row * 64 + pc * 8];
        o_acc[0][n] = __builtin_amdgcn_mfma_f32_16x16x32_bf16(pf[0], vf, o_acc[0][n], 0, 0, 0);
        o_acc[1][n] = __builtin_amdgcn_mfma_f32_16x16x32_bf16(pf[1], vf, o_acc[1][n], 0, 0, 0);
      }
    }
    __builtin_amdgcn_s_setprio(0);

    __syncthreads();  // all reads of cur bufs done; prefetch (vmcnt) drained -> next buf ready
  }

  // epilogue: O /= l, write bf16
  const long ybase = (long)(b * T_SEQ + qt * 128 + w * 32) * DMODEL + h * DHEAD;
#pragma unroll
  for (int m = 0; m < 2; m++)
#pragma unroll
    for (int n = 0; n < 8; n++)
#pragma unroll
      for (int i = 0; i < 4; i++) {
        float v = o_acc[m][n][i] / l_st[m * 4 + i];
        Y[ybase + (long)(m * 16 + lc * 4 + i) * DMODEL + n * 16 + lr] = f2b(v);
      }
}

extern "C" void kernel_launch(void* const* d_in, const int* in_sizes, int n_in,
                              void* d_out, int out_size, void* d_ws, size_t ws_size,
                              hipStream_t stream) {
  const float* x  = (const float*)d_in[0];
  const float* Wq = (const float*)d_in[1];
  const float* Wk = (const float*)d_in[2];
  const float* Wv = (const float*)d_in[3];
  const float* Wo = (const float*)d_in[4];
  float* out = (float*)d_out;
  char* ws = (char*)d_ws;

  const long MB32 = 33554432L;  // 8192*2048 bf16
  u16* xb  = (u16*)(ws);                       // x bf16; later aliased by Vt
  u16* Wqt = (u16*)(ws + MB32);
  u16* Wkt = (u16*)(ws + MB32 + 8388608L);
  u16* Wvt = (u16*)(ws + MB32 + 16777216L);
  u16* Wot = (u16*)(ws + MB32 + 25165824L);
  u16* Qb  = (u16*)(ws + 2 * MB32);
  u16* Kb  = (u16*)(ws + 3 * MB32);
  u16* Vb  = (u16*)(ws + 4 * MB32);
  u16* Vtb = xb;   // alias: xb dead after V projection
  u16* Yb  = Vb;   // alias: Vb dead after vtrans
  // total ws usage: 5*32MiB = 160 MiB

  cast_f32_bf16<<<8192, 256, 0, stream>>>(x, xb);
  dim3 wt_g(32, 32);
  wtrans_kernel<<<wt_g, 256, 0, stream>>>(Wq, Wqt);
  wtrans_kernel<<<wt_g, 256, 0, stream>>>(Wk, Wkt);
  wtrans_kernel<<<wt_g, 256, 0, stream>>>(Wv, Wvt);
  wtrans_kernel<<<wt_g, 256, 0, stream>>>(Wo, Wot);

  dim3 gg(64, 16);
  gemm_bt<0><<<gg, 256, 0, stream>>>(xb, Wqt, Qb, 8192, 2048, 2048);
  gemm_bt<0><<<gg, 256, 0, stream>>>(xb, Wkt, Kb, 8192, 2048, 2048);
  gemm_bt<0><<<gg, 256, 0, stream>>>(xb, Wvt, Vb, 8192, 2048, 2048);

  rope_kernel<<<8192, 256, 0, stream>>>(Qb);
  rope_kernel<<<8192, 256, 0, stream>>>(Kb);

  dim3 vt_g(32, 2, 64);
  vtrans_kernel<<<vt_g, 256, 0, stream>>>(Vb, Vtb);

  attn_kernel<<<1024, 256, 0, stream>>>(Qb, Kb, Vtb, Yb);

  gemm_bt<1><<<gg, 256, 0, stream>>>(Yb, Wot, (void*)out, 8192, 2048, 2048);
}

// Round 3
// 549.223 us; speedup vs baseline: 2.1414x; 1.0733x over previous
//
#include <hip/hip_runtime.h>
#include <hip/hip_bf16.h>
#include <math.h>

typedef unsigned short u16;
typedef __attribute__((ext_vector_type(8))) __bf16 bf16x8;
typedef __attribute__((ext_vector_type(4))) float f32x4;
typedef __attribute__((ext_vector_type(8))) u16 u16x8;

#define T_SEQ 2048
#define DMODEL 2048
#define NH 16
#define DHEAD 128
#define BATCH 4
#define ATTN_SCALE 0.08838834764831845f

// async global->LDS, 16B per lane, wave-uniform LDS base + lane*16
#define GLOAD(gp, lp) __builtin_amdgcn_global_load_lds( \
    (const __attribute__((address_space(1))) void*)(gp), \
    (__attribute__((address_space(3))) void*)(lp), 16, 0, 0)

#define BAR() __builtin_amdgcn_s_barrier()
#define LGKM0() do { asm volatile("s_waitcnt lgkmcnt(0)" ::: "memory"); \
                     __builtin_amdgcn_sched_barrier(0); } while (0)
#define VMCNT4() asm volatile("s_waitcnt vmcnt(4)" ::: "memory")

__device__ __forceinline__ float b2f(u16 u) {
  union { float f; unsigned int i; } x; x.i = ((unsigned int)u) << 16; return x.f;
}
__device__ __forceinline__ u16 f2b(float f) {
  union { float f; unsigned int i; } x; x.f = f;
  unsigned int r = x.i + 0x7fffu + ((x.i >> 16) & 1u);
  return (u16)(r >> 16);
}

// ---------------- cast x: f32 -> bf16 ----------------
__global__ __launch_bounds__(256) void cast_f32_bf16(const float* __restrict__ in,
                                                     u16* __restrict__ out) {
  long i = ((long)blockIdx.x * 256 + threadIdx.x) * 8;
  float4 a = *(const float4*)(in + i);
  float4 b = *(const float4*)(in + i + 4);
  u16x8 r;
  r[0] = f2b(a.x); r[1] = f2b(a.y); r[2] = f2b(a.z); r[3] = f2b(a.w);
  r[4] = f2b(b.x); r[5] = f2b(b.y); r[6] = f2b(b.z); r[7] = f2b(b.w);
  *(u16x8*)(out + i) = r;
}

// ---------------- weight transpose + cast: W[k][n] f32 -> Wt[n][k] bf16 ----------------
__global__ __launch_bounds__(256) void wtrans_kernel(const float* __restrict__ W,
                                                     u16* __restrict__ Wt) {
  __shared__ float tile[64][65];
  const int k0 = blockIdx.x * 64, n0 = blockIdx.y * 64;
  const int c = threadIdx.x & 63, r4 = threadIdx.x >> 6;
#pragma unroll
  for (int p = 0; p < 16; p++) {
    int r = p * 4 + r4;
    tile[r][c] = W[(long)(k0 + r) * DMODEL + n0 + c];
  }
  __syncthreads();
#pragma unroll
  for (int p = 0; p < 16; p++) {
    int r = p * 4 + r4;
    Wt[(long)(n0 + r) * DMODEL + k0 + c] = f2b(tile[c][r]);
  }
}

// ---------------- V transpose per (b,h): V[b*T+s][h*128+f] -> Vt[(bh*128+f)][s] ----------------
__global__ __launch_bounds__(256) void vtrans_kernel(const u16* __restrict__ V,
                                                     u16* __restrict__ Vt) {
  __shared__ u16 tile[64][66];
  const int s0 = blockIdx.x * 64, f0 = blockIdx.y * 64;
  const int bh = blockIdx.z;
  const int b = bh >> 4, h = bh & 15;
  const int c = threadIdx.x & 63, r4 = threadIdx.x >> 6;
#pragma unroll
  for (int p = 0; p < 16; p++) {
    int r = p * 4 + r4; // s-local
    tile[r][c] = V[(long)(b * T_SEQ + s0 + r) * DMODEL + h * DHEAD + f0 + c];
  }
  __syncthreads();
#pragma unroll
  for (int p = 0; p < 16; p++) {
    int r = p * 4 + r4; // f-local
    Vt[(long)(bh * DHEAD + f0 + r) * T_SEQ + s0 + c] = tile[c][r];
  }
}

// ---------------- RoPE in place on bf16 [B*T][D], interleaved pairs ----------------
__global__ __launch_bounds__(256) void rope_kernel(u16* __restrict__ X) {
  int idx = blockIdx.x * 256 + threadIdx.x;  // B*T*H*16 threads, 4 pairs each
  int i4 = idx & 15;
  int h = (idx >> 4) & 15;
  long bt = idx >> 8;
  int t = (int)(bt & (T_SEQ - 1));
  long off = bt * DMODEL + h * DHEAD + i4 * 8;
  u16x8 v = *(u16x8*)(X + off);
  float o[8];
#pragma unroll
  for (int j = 0; j < 4; j++) {
    int i = i4 * 4 + j;                 // pair index 0..63
    float inv = powf(10000.0f, -(float)i / 64.0f);
    float ang = (float)t * inv;
    float cs = cosf(ang), sn = sinf(ang);
    float x0 = b2f(v[2 * j]), x1 = b2f(v[2 * j + 1]);
    o[2 * j]     = x0 * cs - x1 * sn;
    o[2 * j + 1] = x1 * cs + x0 * sn;
  }
  u16x8 r;
#pragma unroll
  for (int j = 0; j < 8; j++) r[j] = f2b(o[j]);
  *(u16x8*)(X + off) = r;
}

// ---------------- GEMM: C[M][N] = A[M][K] * Bt[N][K]^T (bf16 in, f32 acc) ----------------
// 256x256 8-phase template: BK=64, 512 thr = 8 waves (2M x 4N), per-wave 128x64 out.
// LDS 128KB: A/B panels [256][64] double-buffered by K-tile parity, chunk-swizzled
// (16B chunk ^= row&7) via pre-swizzled global source + linear global_load_lds dest.
// Per K-tile: 4 phases. ph0: ds_read all B (8xb128, held in regs) + A quad0 (4xb128);
// ph q: A quad q. Stages: A-halves of tile t+1 at ph0/ph1; B-halves of tile t+2 at
// ph1/ph2 (each region's last reader passed 2 barriers before issue). One counted
// vmcnt(4) per tile at ph3 keeps B(t+3) halves in flight across the wait.
#define LOAD_A(q)                                                      \
  _Pragma("unroll") for (int k = 0; k < 2; k++)                        \
  _Pragma("unroll") for (int m = 0; m < 2; m++) {                      \
    int r = wr * 128 + (q) * 32 + m * 16 + lr;                         \
    int cc = (k * 4 + lc) ^ (r & 7);                                   \
    a[k][m] = *(const bf16x8*)&sA[par][r * 64 + cc * 8];               \
  }

#define LOAD_B()                                                       \
  _Pragma("unroll") for (int k = 0; k < 2; k++)                        \
  _Pragma("unroll") for (int n = 0; n < 4; n++) {                      \
    int r = wc * 64 + n * 16 + lr;                                     \
    int cc = (k * 4 + lc) ^ (r & 7);                                   \
    b[k][n] = *(const bf16x8*)&sB[par][r * 64 + cc * 8];               \
  }

#define MFMA_QUAD(q)                                                   \
  _Pragma("unroll") for (int k = 0; k < 2; k++)                        \
  _Pragma("unroll") for (int n = 0; n < 4; n++)                        \
  _Pragma("unroll") for (int m = 0; m < 2; m++)                        \
    acc[(q) * 2 + m][n] = __builtin_amdgcn_mfma_f32_16x16x32_bf16(     \
        a[k][m], b[k][n], acc[(q) * 2 + m][n], 0, 0, 0);

// stage one 128-row half-tile (2 GLOADs/thread); dst base wave-uniform
#define STAGE_HALF(g, ldsp, rc0, t_, h_)                               \
  _Pragma("unroll") for (int j = 0; j < 2; j++) {                      \
    int rl = (h_) * 128 + wid * 16 + j * 8 + (lane >> 3);              \
    int cc = (lane & 7) ^ (lane >> 3);                                 \
    GLOAD((g) + ((rc0) + rl) * (long)K + (long)(t_) * 64 + cc * 8,     \
          (ldsp) + (h_) * 128 * 64 + (wid * 16 + j * 8) * 64);         \
  }

template <int OUT_F32>
__global__ __launch_bounds__(512, 2) void gemm_bt(const u16* __restrict__ A,
                                                  const u16* __restrict__ Bt,
                                                  void* __restrict__ Cv,
                                                  int M, int N, int K) {
  __shared__ u16 sA[2][256 * 64];
  __shared__ u16 sB[2][256 * 64];
  const int tid = threadIdx.x, lane = tid & 63, wid = tid >> 6;
  const int wr = wid >> 2, wc = wid & 3;
  const int lr = lane & 15, lc = lane >> 4;
  const long row0 = (long)blockIdx.x * 256;
  const long col0 = (long)blockIdx.y * 256;
  const int NT = K >> 6;

  f32x4 acc[8][4] = {};
  bf16x8 a[2][2], b[2][4];

  // prologue: B(0), A(0), B(1); vmcnt(4) -> first 8 loads (B0,A0) complete
  STAGE_HALF(Bt, &sB[0][0], col0, 0, 0);
  STAGE_HALF(Bt, &sB[0][0], col0, 0, 1);
  STAGE_HALF(A,  &sA[0][0], row0, 0, 0);
  STAGE_HALF(A,  &sA[0][0], row0, 0, 1);
  STAGE_HALF(Bt, &sB[1][0], col0, 1, 0);
  STAGE_HALF(Bt, &sB[1][0], col0, 1, 1);
  VMCNT4();
  BAR();

  for (int t = 0; t < NT; t++) {
    const int par = t & 1;
    // ---- phase 0 ----
    LOAD_B();
    LOAD_A(0);
    if (t + 1 < NT) { STAGE_HALF(A, &sA[par ^ 1][0], row0, t + 1, 0); }
    BAR(); LGKM0();
    __builtin_amdgcn_s_setprio(1); MFMA_QUAD(0); __builtin_amdgcn_s_setprio(0);
    BAR();
    // ---- phase 1 ----
    LOAD_A(1);
    if (t + 1 < NT) { STAGE_HALF(A, &sA[par ^ 1][0], row0, t + 1, 1); }
    if (t + 2 < NT) { STAGE_HALF(Bt, &sB[par][0], col0, t + 2, 0); }
    BAR(); LGKM0();
    __builtin_amdgcn_s_setprio(1); MFMA_QUAD(1); __builtin_amdgcn_s_setprio(0);
    BAR();
    // ---- phase 2 ----
    LOAD_A(2);
    if (t + 2 < NT) { STAGE_HALF(Bt, &sB[par][0], col0, t + 2, 1); }
    BAR(); LGKM0();
    __builtin_amdgcn_s_setprio(1); MFMA_QUAD(2); __builtin_amdgcn_s_setprio(0);
    BAR();
    // ---- phase 3 ----
    LOAD_A(3);
    VMCNT4();  // A(t+1),B(t+1) complete; B(t+2) halves stay in flight
    BAR(); LGKM0();
    __builtin_amdgcn_s_setprio(1); MFMA_QUAD(3); __builtin_amdgcn_s_setprio(0);
    BAR();
  }

#pragma unroll
  for (int mf = 0; mf < 8; mf++)
#pragma unroll
    for (int n = 0; n < 4; n++)
#pragma unroll
      for (int i = 0; i < 4; i++) {
        long row = row0 + wr * 128 + mf * 16 + lc * 4 + i;
        long col = col0 + wc * 64 + n * 16 + lr;
        float v = acc[mf][n][i];
        if (OUT_F32) ((float*)Cv)[row * N + col] = v;
        else ((u16*)Cv)[row * N + col] = f2b(v);
      }
}

// ---------------- flash attention, double-buffered ----------------
// 1024 blocks (qt 0..15 x bh 0..63), longest-first dispatch. 256 thr = 4 waves,
// each wave owns 32 q-rows of the 128-row q-tile. KVBLK=64.
// LDS: K dbuf 2x16KB + Vt dbuf 2x16KB + P 16KB = 80KB -> 2 blocks/CU.
// Prefetch tile kt+1 before computing kt; single barrier per iteration.
__global__ __launch_bounds__(256, 2) void attn_kernel(const u16* __restrict__ Q,
                                                      const u16* __restrict__ K,
                                                      const u16* __restrict__ Vt,
                                                      u16* __restrict__ Y) {
  __shared__ u16 lK[2][64 * 128];   // K tile: 64 s-rows x 128 f (swizzled)
  __shared__ u16 lV[2][128 * 64];   // Vt tile: 128 f-rows x 64 s (swizzled)
  __shared__ u16 lP[128 * 64];      // P tile: 128 q-rows x 64 s (per-wave regions)
  const int tid = threadIdx.x, lane = tid & 63, w = tid >> 6;
  const int id = blockIdx.x;
  const int qt = 15 - (id >> 6);    // longest blocks dispatched first
  const int bh = id & 63;
  const int b = bh >> 4, h = bh & 15;
  const int lr = lane & 15, lc = lane >> 4;

  // Q fragments resident in registers: rows w*32.., all 128 f
  bf16x8 qf[2][4];
  const long qbase = (long)(b * T_SEQ + qt * 128 + w * 32) * DMODEL + h * DHEAD;
#pragma unroll
  for (int m = 0; m < 2; m++)
#pragma unroll
    for (int ks = 0; ks < 4; ks++)
      qf[m][ks] = *(const bf16x8*)(Q + qbase + (long)(m * 16 + lr) * DMODEL + ks * 32 + lc * 8);

  f32x4 o_acc[2][8] = {};
  float m_st[8], l_st[8];
#pragma unroll
  for (int ri = 0; ri < 8; ri++) { m_st[ri] = -INFINITY; l_st[ri] = 0.f; }

  const int nt = (qt + 1) * 2;

  // stage K+V tile kt into buffer nb (pre-swizzled global source, linear LDS dst)
#define STAGE(nb, kt_)                                                              \
  {                                                                                 \
    _Pragma("unroll")                                                               \
    for (int j = 0; j < 4; j++) {                                                   \
      int sb = (w * 4 + j) * 64;                                                    \
      int slot = sb + lane;                                                         \
      { int r = slot >> 4, pc = slot & 15, cc = pc ^ (r & 7);                       \
        GLOAD(K + (long)(b * T_SEQ + (kt_) * 64 + r) * DMODEL + h * DHEAD + cc * 8, \
              &lK[nb][sb * 8]); }                                                   \
      { int r = slot >> 3, pc = slot & 7, cc = pc ^ (r & 7);                        \
        GLOAD(Vt + (long)(bh * DHEAD + r) * T_SEQ + (kt_) * 64 + cc * 8,            \
              &lV[nb][sb * 8]); }                                                   \
    }                                                                               \
  }

  STAGE(0, 0);
  __syncthreads();  // buf0 ready (barrier drains vmcnt)

  for (int kt = 0; kt < nt; kt++) {
    const int cur = kt & 1;
    if (kt + 1 < nt) STAGE(cur ^ 1, kt + 1);  // in flight during this iter's compute

    // S = Q K^T for this wave's 32 q-rows x 64 s
    f32x4 s_acc[2][4] = {};
    __builtin_amdgcn_s_setprio(1);
#pragma unroll
    for (int ks = 0; ks < 4; ks++) {
#pragma unroll
      for (int n = 0; n < 4; n++) {
        int row = n * 16 + lr;
        int pc = (ks * 4 + lc) ^ (row & 7);
        bf16x8 kf = *(const bf16x8*)&lK[cur][row * 128 + pc * 8];
        s_acc[0][n] = __builtin_amdgcn_mfma_f32_16x16x32_bf16(qf[0][ks], kf, s_acc[0][n], 0, 0, 0);
        s_acc[1][n] = __builtin_amdgcn_mfma_f32_16x16x32_bf16(qf[1][ks], kf, s_acc[1][n], 0, 0, 0);
      }
    }
    __builtin_amdgcn_s_setprio(0);

    // scale + causal mask (only last two kv tiles overlap the diagonal)
    const bool diag = (kt >= qt * 2);
#pragma unroll
    for (int m = 0; m < 2; m++)
#pragma unroll
      for (int n = 0; n < 4; n++)
#pragma unroll
        for (int i = 0; i < 4; i++) {
          float v = s_acc[m][n][i] * ATTN_SCALE;
          if (diag) {
            int sc = kt * 64 + n * 16 + lr;
            int qr = qt * 128 + w * 32 + m * 16 + lc * 4 + i;
            if (sc > qr) v = -1e30f;
          }
          s_acc[m][n][i] = v;
        }

    // online softmax (row state replicated over the 16 lanes sharing each row)
#pragma unroll
    for (int m = 0; m < 2; m++)
#pragma unroll
      for (int i = 0; i < 4; i++) {
        int ri = m * 4 + i;
        float mx = -1e30f;
#pragma unroll
        for (int n = 0; n < 4; n++) mx = fmaxf(mx, s_acc[m][n][i]);
#pragma unroll
        for (int d = 1; d < 16; d <<= 1) mx = fmaxf(mx, __shfl_xor(mx, d, 64));
        float mnew = fmaxf(m_st[ri], mx);
        float corr = __expf(m_st[ri] - mnew);
        float rs = 0.f;
#pragma unroll
        for (int n = 0; n < 4; n++) {
          float p = __expf(s_acc[m][n][i] - mnew);
          s_acc[m][n][i] = p;
          rs += p;
        }
#pragma unroll
        for (int d = 1; d < 16; d <<= 1) rs += __shfl_xor(rs, d, 64);
        l_st[ri] = l_st[ri] * corr + rs;
        m_st[ri] = mnew;
#pragma unroll
        for (int n = 0; n < 8; n++) o_acc[m][n][i] *= corr;
      }

    // write P (bf16) into own wave's rows of lP, swizzled; read back below (same wave)
#pragma unroll
    for (int m = 0; m < 2; m++)
#pragma unroll
      for (int n = 0; n < 4; n++)
#pragma unroll
        for (int i = 0; i < 4; i++) {
          int prow = w * 32 + m * 16 + lc * 4 + i;
          int pcol = n * 16 + lr;
          int pc = (pcol >> 3) ^ (prow & 7);
          lP[prow * 64 + pc * 8 + (pcol & 7)] = f2b(s_acc[m][n][i]);
        }

    // O += P V
    __builtin_amdgcn_s_setprio(1);
#pragma unroll
    for (int ks = 0; ks < 2; ks++) {
      bf16x8 pf[2];
#pragma unroll
      for (int m = 0; m < 2; m++) {
        int row = w * 32 + m * 16 + lr;
        int pc = (ks * 4 + lc) ^ (row & 7);
        pf[m] = *(const bf16x8*)&lP[row * 64 + pc * 8];
      }
#pragma unroll
      for (int n = 0; n < 8; n++) {
        int row = n * 16 + lr;
        int pc = (ks * 4 + lc) ^ (row & 7);
        bf16x8 vf = *(const bf16x8*)&lV[cur][row * 64 + pc * 8];
        o_acc[0][n] = __builtin_amdgcn_mfma_f32_16x16x32_bf16(pf[0], vf, o_acc[0][n], 0, 0, 0);
        o_acc[1][n] = __builtin_amdgcn_mfma_f32_16x16x32_bf16(pf[1], vf, o_acc[1][n], 0, 0, 0);
      }
    }
    __builtin_amdgcn_s_setprio(0);

    __syncthreads();  // all reads of cur bufs done; prefetch (vmcnt) drained -> next buf ready
  }

  // epilogue: O /= l, write bf16
  const long ybase = (long)(b * T_SEQ + qt * 128 + w * 32) * DMODEL + h * DHEAD;
#pragma unroll
  for (int m = 0; m < 2; m++)
#pragma unroll
    for (int n = 0; n < 8; n++)
#pragma unroll
      for (int i = 0; i < 4; i++) {
        float v = o_acc[m][n][i] / l_st[m * 4 + i];
        Y[ybase + (long)(m * 16 + lc * 4 + i) * DMODEL + n * 16 + lr] = f2b(v);
      }
}

extern "C" void kernel_launch(void* const* d_in, const int* in_sizes, int n_in,
                              void* d_out, int out_size, void* d_ws, size_t ws_size,
                              hipStream_t stream) {
  const float* x  = (const float*)d_in[0];
  const float* Wq = (const float*)d_in[1];
  const float* Wk = (const float*)d_in[2];
  const float* Wv = (const float*)d_in[3];
  const float* Wo = (const float*)d_in[4];
  float* out = (float*)d_out;
  char* ws = (char*)d_ws;

  const long MB32 = 33554432L;  // 8192*2048 bf16
  u16* xb  = (u16*)(ws);                       // x bf16; later aliased by Vt
  u16* Wqt = (u16*)(ws + MB32);
  u16* Wkt = (u16*)(ws + MB32 + 8388608L);
  u16* Wvt = (u16*)(ws + MB32 + 16777216L);
  u16* Wot = (u16*)(ws + MB32 + 25165824L);
  u16* Qb  = (u16*)(ws + 2 * MB32);
  u16* Kb  = (u16*)(ws + 3 * MB32);
  u16* Vb  = (u16*)(ws + 4 * MB32);
  u16* Vtb = xb;   // alias: xb dead after V projection
  u16* Yb  = Vb;   // alias: Vb dead after vtrans
  // total ws usage: 5*32MiB = 160 MiB

  cast_f32_bf16<<<8192, 256, 0, stream>>>(x, xb);
  dim3 wt_g(32, 32);
  wtrans_kernel<<<wt_g, 256, 0, stream>>>(Wq, Wqt);
  wtrans_kernel<<<wt_g, 256, 0, stream>>>(Wk, Wkt);
  wtrans_kernel<<<wt_g, 256, 0, stream>>>(Wv, Wvt);
  wtrans_kernel<<<wt_g, 256, 0, stream>>>(Wo, Wot);

  dim3 gg(32, 8);  // 256x256 tiles over M=8192, N=2048 -> 256 blocks = 1/CU
  gemm_bt<0><<<gg, 512, 0, stream>>>(xb, Wqt, Qb, 8192, 2048, 2048);
  gemm_bt<0><<<gg, 512, 0, stream>>>(xb, Wkt, Kb, 8192, 2048, 2048);
  gemm_bt<0><<<gg, 512, 0, stream>>>(xb, Wvt, Vb, 8192, 2048, 2048);

  rope_kernel<<<8192, 256, 0, stream>>>(Qb);
  rope_kernel<<<8192, 256, 0, stream>>>(Kb);

  dim3 vt_g(32, 2, 64);
  vtrans_kernel<<<vt_g, 256, 0, stream>>>(Vb, Vtb);

  attn_kernel<<<1024, 256, 0, stream>>>(Qb, Kb, Vtb, Yb);

  gemm_bt<1><<<gg, 512, 0, stream>>>(Yb, Wot, (void*)out, 8192, 2048, 2048);
}

// Round 4
// 508.859 us; speedup vs baseline: 2.3113x; 1.0793x over previous
//
#include <hip/hip_runtime.h>
#include <hip/hip_bf16.h>
#include <math.h>

typedef unsigned short u16;
typedef __attribute__((ext_vector_type(8))) __bf16 bf16x8;
typedef __attribute__((ext_vector_type(4))) float f32x4;
typedef __attribute__((ext_vector_type(8))) u16 u16x8;

#define T_SEQ 2048
#define DMODEL 2048
#define NH 16
#define DHEAD 128
#define BATCH 4
#define ATTN_SCALE 0.08838834764831845f
// ATTN_SCALE * log2(e): softmax runs in exp2 domain, scale folded into Q
#define QSCALE_LOG2E 0.1275411278534803f

// async global->LDS, 16B per lane, wave-uniform LDS base + lane*16
#define GLOAD(gp, lp) __builtin_amdgcn_global_load_lds( \
    (const __attribute__((address_space(1))) void*)(gp), \
    (__attribute__((address_space(3))) void*)(lp), 16, 0, 0)

#define BAR() __builtin_amdgcn_s_barrier()
#define LGKM0() do { asm volatile("s_waitcnt lgkmcnt(0)" ::: "memory"); \
                     __builtin_amdgcn_sched_barrier(0); } while (0)
#define VMCNT4() asm volatile("s_waitcnt vmcnt(4)" ::: "memory")

__device__ __forceinline__ float b2f(u16 u) {
  union { float f; unsigned int i; } x; x.i = ((unsigned int)u) << 16; return x.f;
}
// hardware RTNE cast (v_cvt_pk_bf16_f32 when paired) instead of 5-op manual RNE
__device__ __forceinline__ u16 f2b(float f) {
  __bf16 h = (__bf16)f;
  return *(u16*)&h;
}

// ---------------- cast x: f32 -> bf16 ----------------
__global__ __launch_bounds__(256) void cast_f32_bf16(const float* __restrict__ in,
                                                     u16* __restrict__ out) {
  long i = ((long)blockIdx.x * 256 + threadIdx.x) * 8;
  float4 a = *(const float4*)(in + i);
  float4 b = *(const float4*)(in + i + 4);
  u16x8 r;
  r[0] = f2b(a.x); r[1] = f2b(a.y); r[2] = f2b(a.z); r[3] = f2b(a.w);
  r[4] = f2b(b.x); r[5] = f2b(b.y); r[6] = f2b(b.z); r[7] = f2b(b.w);
  *(u16x8*)(out + i) = r;
}

// ---------------- weight transpose + cast: W[k][n] f32 -> Wt[n][k] bf16 ----------------
__global__ __launch_bounds__(256) void wtrans_kernel(const float* __restrict__ W,
                                                     u16* __restrict__ Wt) {
  __shared__ float tile[64][65];
  const int k0 = blockIdx.x * 64, n0 = blockIdx.y * 64;
  const int c = threadIdx.x & 63, r4 = threadIdx.x >> 6;
#pragma unroll
  for (int p = 0; p < 16; p++) {
    int r = p * 4 + r4;
    tile[r][c] = W[(long)(k0 + r) * DMODEL + n0 + c];
  }
  __syncthreads();
#pragma unroll
  for (int p = 0; p < 16; p++) {
    int r = p * 4 + r4;
    Wt[(long)(n0 + r) * DMODEL + k0 + c] = f2b(tile[c][r]);
  }
}

// ---------------- V transpose per (b,h): V[b*T+s][h*128+f] -> Vt[(bh*128+f)][s] ----------------
__global__ __launch_bounds__(256) void vtrans_kernel(const u16* __restrict__ V,
                                                     u16* __restrict__ Vt) {
  __shared__ u16 tile[64][66];
  const int s0 = blockIdx.x * 64, f0 = blockIdx.y * 64;
  const int bh = blockIdx.z;
  const int b = bh >> 4, h = bh & 15;
  const int c = threadIdx.x & 63, r4 = threadIdx.x >> 6;
#pragma unroll
  for (int p = 0; p < 16; p++) {
    int r = p * 4 + r4; // s-local
    tile[r][c] = V[(long)(b * T_SEQ + s0 + r) * DMODEL + h * DHEAD + f0 + c];
  }
  __syncthreads();
#pragma unroll
  for (int p = 0; p < 16; p++) {
    int r = p * 4 + r4; // f-local
    Vt[(long)(bh * DHEAD + f0 + r) * T_SEQ + s0 + c] = tile[c][r];
  }
}

// ---------------- RoPE in place on bf16 [B*T][D], interleaved pairs ----------------
__global__ __launch_bounds__(256) void rope_kernel(u16* __restrict__ X) {
  int idx = blockIdx.x * 256 + threadIdx.x;  // B*T*H*16 threads, 4 pairs each
  int i4 = idx & 15;
  int h = (idx >> 4) & 15;
  long bt = idx >> 8;
  int t = (int)(bt & (T_SEQ - 1));
  long off = bt * DMODEL + h * DHEAD + i4 * 8;
  u16x8 v = *(u16x8*)(X + off);
  float o[8];
#pragma unroll
  for (int j = 0; j < 4; j++) {
    int i = i4 * 4 + j;                 // pair index 0..63
    // 10000^(-i/64) = 2^(-i * log2(10000)/64), v_exp_f32 native
    float inv = __builtin_amdgcn_exp2f((float)i * -0.20762050593045857f);
    float ang = (float)t * inv;
    float cs = cosf(ang), sn = sinf(ang);
    float x0 = b2f(v[2 * j]), x1 = b2f(v[2 * j + 1]);
    o[2 * j]     = x0 * cs - x1 * sn;
    o[2 * j + 1] = x1 * cs + x0 * sn;
  }
  u16x8 r;
#pragma unroll
  for (int j = 0; j < 8; j++) r[j] = f2b(o[j]);
  *(u16x8*)(X + off) = r;
}

// ---------------- GEMM: C[M][N] = A[M][K] * Bt[N][K]^T (bf16 in, f32 acc) ----------------
// 256x256 8-phase template, BK=64, 512 thr = 8 waves (2M x 4N), per-wave 128x64 out.
// Column-strip XCD mapping: 256 blocks, id%8 -> XCD (round-robin), so col0=(id&7)*256
// gives each XCD one 256-col strip: its 32 concurrent blocks share ONE 1MB B-panel
// (L2-resident) instead of streaming 8 panels -> B cache traffic 256MB -> ~8MB/GEMM.
#define LOAD_A(q)                                                      \
  _Pragma("unroll") for (int k = 0; k < 2; k++)                        \
  _Pragma("unroll") for (int m = 0; m < 2; m++) {                      \
    int r = wr * 128 + (q) * 32 + m * 16 + lr;                         \
    int cc = (k * 4 + lc) ^ (r & 7);                                   \
    a[k][m] = *(const bf16x8*)&sA[par][r * 64 + cc * 8];               \
  }

#define LOAD_B()                                                       \
  _Pragma("unroll") for (int k = 0; k < 2; k++)                        \
  _Pragma("unroll") for (int n = 0; n < 4; n++) {                      \
    int r = wc * 64 + n * 16 + lr;                                     \
    int cc = (k * 4 + lc) ^ (r & 7);                                   \
    b[k][n] = *(const bf16x8*)&sB[par][r * 64 + cc * 8];               \
  }

#define MFMA_QUAD(q)                                                   \
  _Pragma("unroll") for (int k = 0; k < 2; k++)                        \
  _Pragma("unroll") for (int n = 0; n < 4; n++)                        \
  _Pragma("unroll") for (int m = 0; m < 2; m++)                        \
    acc[(q) * 2 + m][n] = __builtin_amdgcn_mfma_f32_16x16x32_bf16(     \
        a[k][m], b[k][n], acc[(q) * 2 + m][n], 0, 0, 0);

// stage one 128-row half-tile (2 GLOADs/thread); dst base wave-uniform
#define STAGE_HALF(g, ldsp, rc0, t_, h_)                               \
  _Pragma("unroll") for (int j = 0; j < 2; j++) {                      \
    int rl = (h_) * 128 + wid * 16 + j * 8 + (lane >> 3);              \
    int cc = (lane & 7) ^ (lane >> 3);                                 \
    GLOAD((g) + ((rc0) + rl) * (long)K + (long)(t_) * 64 + cc * 8,     \
          (ldsp) + (h_) * 128 * 64 + (wid * 16 + j * 8) * 64);         \
  }

template <int OUT_F32>
__global__ __launch_bounds__(512, 2) void gemm_bt(const u16* __restrict__ A,
                                                  const u16* __restrict__ Bt,
                                                  void* __restrict__ Cv,
                                                  int M, int N, int K) {
  __shared__ u16 sA[2][256 * 64];
  __shared__ u16 sB[2][256 * 64];
  const int tid = threadIdx.x, lane = tid & 63, wid = tid >> 6;
  const int wr = wid >> 2, wc = wid & 3;
  const int lr = lane & 15, lc = lane >> 4;
  const int id = blockIdx.x;
  const long row0 = (long)(id >> 3) * 256;   // 32 row tiles
  const long col0 = (long)(id & 7) * 256;    // 8 col tiles; id%8 -> XCD strip
  const int NT = K >> 6;

  f32x4 acc[8][4] = {};
  bf16x8 a[2][2], b[2][4];

  // prologue: B(0), A(0), B(1); vmcnt(4) -> first 8 loads (B0,A0) complete
  STAGE_HALF(Bt, &sB[0][0], col0, 0, 0);
  STAGE_HALF(Bt, &sB[0][0], col0, 0, 1);
  STAGE_HALF(A,  &sA[0][0], row0, 0, 0);
  STAGE_HALF(A,  &sA[0][0], row0, 0, 1);
  STAGE_HALF(Bt, &sB[1][0], col0, 1, 0);
  STAGE_HALF(Bt, &sB[1][0], col0, 1, 1);
  VMCNT4();
  BAR();

  for (int t = 0; t < NT; t++) {
    const int par = t & 1;
    // ---- phase 0 ----
    LOAD_B();
    LOAD_A(0);
    if (t + 1 < NT) { STAGE_HALF(A, &sA[par ^ 1][0], row0, t + 1, 0); }
    BAR(); LGKM0();
    __builtin_amdgcn_s_setprio(1); MFMA_QUAD(0); __builtin_amdgcn_s_setprio(0);
    BAR();
    // ---- phase 1 ----
    LOAD_A(1);
    if (t + 1 < NT) { STAGE_HALF(A, &sA[par ^ 1][0], row0, t + 1, 1); }
    if (t + 2 < NT) { STAGE_HALF(Bt, &sB[par][0], col0, t + 2, 0); }
    BAR(); LGKM0();
    __builtin_amdgcn_s_setprio(1); MFMA_QUAD(1); __builtin_amdgcn_s_setprio(0);
    BAR();
    // ---- phase 2 ----
    LOAD_A(2);
    if (t + 2 < NT) { STAGE_HALF(Bt, &sB[par][0], col0, t + 2, 1); }
    BAR(); LGKM0();
    __builtin_amdgcn_s_setprio(1); MFMA_QUAD(2); __builtin_amdgcn_s_setprio(0);
    BAR();
    // ---- phase 3 ----
    LOAD_A(3);
    VMCNT4();  // A(t+1),B(t+1) complete; B(t+2) halves stay in flight
    BAR(); LGKM0();
    __builtin_amdgcn_s_setprio(1); MFMA_QUAD(3); __builtin_amdgcn_s_setprio(0);
    BAR();
  }

#pragma unroll
  for (int mf = 0; mf < 8; mf++)
#pragma unroll
    for (int n = 0; n < 4; n++)
#pragma unroll
      for (int i = 0; i < 4; i++) {
        long row = row0 + wr * 128 + mf * 16 + lc * 4 + i;
        long col = col0 + wc * 64 + n * 16 + lr;
        float v = acc[mf][n][i];
        if (OUT_F32) ((float*)Cv)[row * N + col] = v;
        else ((u16*)Cv)[row * N + col] = f2b(v);
      }
}

// ---------------- flash attention, double-buffered ----------------
// 1024 blocks (qt 0..15 x bh 0..63), longest-first dispatch. 256 thr = 4 waves,
// each wave owns 32 q-rows of the 128-row q-tile. KVBLK=64.
// LDS: K dbuf 2x16KB + Vt dbuf 2x16KB + P 16KB = 80KB -> 2 blocks/CU.
// Softmax in exp2 domain (scale*log2e folded into Q at load), defer-max (THR=8
// log2-units), hardware bf16 cvt for P, rcp epilogue.
__global__ __launch_bounds__(256, 2) void attn_kernel(const u16* __restrict__ Q,
                                                      const u16* __restrict__ K,
                                                      const u16* __restrict__ Vt,
                                                      u16* __restrict__ Y) {
  __shared__ u16 lK[2][64 * 128];   // K tile: 64 s-rows x 128 f (swizzled)
  __shared__ u16 lV[2][128 * 64];   // Vt tile: 128 f-rows x 64 s (swizzled)
  __shared__ u16 lP[128 * 64];      // P tile: 128 q-rows x 64 s (per-wave regions)
  const int tid = threadIdx.x, lane = tid & 63, w = tid >> 6;
  const int id = blockIdx.x;
  const int qt = 15 - (id >> 6);    // longest blocks dispatched first
  const int bh = id & 63;
  const int b = bh >> 4, h = bh & 15;
  const int lr = lane & 15, lc = lane >> 4;

  // Q fragments in registers, pre-scaled by ATTN_SCALE*log2(e)
  bf16x8 qf[2][4];
  const long qbase = (long)(b * T_SEQ + qt * 128 + w * 32) * DMODEL + h * DHEAD;
#pragma unroll
  for (int m = 0; m < 2; m++)
#pragma unroll
    for (int ks = 0; ks < 4; ks++) {
      u16x8 raw = *(const u16x8*)(Q + qbase + (long)(m * 16 + lr) * DMODEL + ks * 32 + lc * 8);
      bf16x8 q;
#pragma unroll
      for (int j = 0; j < 8; j++) q[j] = (__bf16)(b2f(raw[j]) * QSCALE_LOG2E);
      qf[m][ks] = q;
    }

  f32x4 o_acc[2][8] = {};
  float m_st[8], l_st[8];
#pragma unroll
  for (int ri = 0; ri < 8; ri++) { m_st[ri] = -INFINITY; l_st[ri] = 0.f; }

  const int nt = (qt + 1) * 2;

  // stage K+V tile kt into buffer nb (pre-swizzled global source, linear LDS dst)
#define STAGE(nb, kt_)                                                              \
  {                                                                                 \
    _Pragma("unroll")                                                               \
    for (int j = 0; j < 4; j++) {                                                   \
      int sb = (w * 4 + j) * 64;                                                    \
      int slot = sb + lane;                                                         \
      { int r = slot >> 4, pc = slot & 15, cc = pc ^ (r & 7);                       \
        GLOAD(K + (long)(b * T_SEQ + (kt_) * 64 + r) * DMODEL + h * DHEAD + cc * 8, \
              &lK[nb][sb * 8]); }                                                   \
      { int r = slot >> 3, pc = slot & 7, cc = pc ^ (r & 7);                        \
        GLOAD(Vt + (long)(bh * DHEAD + r) * T_SEQ + (kt_) * 64 + cc * 8,            \
              &lV[nb][sb * 8]); }                                                   \
    }                                                                               \
  }

  STAGE(0, 0);
  __syncthreads();  // buf0 ready (barrier drains vmcnt)

  for (int kt = 0; kt < nt; kt++) {
    const int cur = kt & 1;
    if (kt + 1 < nt) STAGE(cur ^ 1, kt + 1);  // in flight during this iter's compute

    // S = Q K^T (exp2-domain logits) for this wave's 32 q-rows x 64 s
    f32x4 s_acc[2][4] = {};
    __builtin_amdgcn_s_setprio(1);
#pragma unroll
    for (int ks = 0; ks < 4; ks++) {
#pragma unroll
      for (int n = 0; n < 4; n++) {
        int row = n * 16 + lr;
        int pc = (ks * 4 + lc) ^ (row & 7);
        bf16x8 kf = *(const bf16x8*)&lK[cur][row * 128 + pc * 8];
        s_acc[0][n] = __builtin_amdgcn_mfma_f32_16x16x32_bf16(qf[0][ks], kf, s_acc[0][n], 0, 0, 0);
        s_acc[1][n] = __builtin_amdgcn_mfma_f32_16x16x32_bf16(qf[1][ks], kf, s_acc[1][n], 0, 0, 0);
      }
    }
    __builtin_amdgcn_s_setprio(0);

    // causal mask (only last two kv tiles overlap the diagonal)
    if (kt >= qt * 2) {
#pragma unroll
      for (int m = 0; m < 2; m++)
#pragma unroll
        for (int n = 0; n < 4; n++)
#pragma unroll
          for (int i = 0; i < 4; i++) {
            int sc = kt * 64 + n * 16 + lr;
            int qr = qt * 128 + w * 32 + m * 16 + lc * 4 + i;
            if (sc > qr) s_acc[m][n][i] = -1e30f;
          }
    }

    // online softmax, exp2 domain, defer-max (row state replicated over 16 lanes)
    float mx[8];
#pragma unroll
    for (int m = 0; m < 2; m++)
#pragma unroll
      for (int i = 0; i < 4; i++) {
        float v = fmaxf(fmaxf(s_acc[m][0][i], s_acc[m][1][i]),
                        fmaxf(s_acc[m][2][i], s_acc[m][3][i]));
#pragma unroll
        for (int d = 1; d < 16; d <<= 1) v = fmaxf(v, __shfl_xor(v, d, 64));
        mx[m * 4 + i] = v;
      }
    bool need = false;
#pragma unroll
    for (int ri = 0; ri < 8; ri++) need = need || (mx[ri] > m_st[ri] + 8.0f);
    if (__any(need)) {
#pragma unroll
      for (int m = 0; m < 2; m++)
#pragma unroll
        for (int i = 0; i < 4; i++) {
          int ri = m * 4 + i;
          float mnew = fmaxf(m_st[ri], mx[ri]);
          float corr = __builtin_amdgcn_exp2f(m_st[ri] - mnew);
          m_st[ri] = mnew;
          l_st[ri] *= corr;
#pragma unroll
          for (int n = 0; n < 8; n++) o_acc[m][n][i] *= corr;
        }
    }
#pragma unroll
    for (int m = 0; m < 2; m++)
#pragma unroll
      for (int i = 0; i < 4; i++) {
        int ri = m * 4 + i;
        float rs = 0.f;
#pragma unroll
        for (int n = 0; n < 4; n++) {
          float p = __builtin_amdgcn_exp2f(s_acc[m][n][i] - m_st[ri]);
          s_acc[m][n][i] = p;
          rs += p;
        }
#pragma unroll
        for (int d = 1; d < 16; d <<= 1) rs += __shfl_xor(rs, d, 64);
        l_st[ri] += rs;
      }

    // write P (bf16) into own wave's rows of lP, swizzled; read back below (same wave)
#pragma unroll
    for (int m = 0; m < 2; m++)
#pragma unroll
      for (int n = 0; n < 4; n++)
#pragma unroll
        for (int i = 0; i < 4; i++) {
          int prow = w * 32 + m * 16 + lc * 4 + i;
          int pcol = n * 16 + lr;
          int pc = (pcol >> 3) ^ (prow & 7);
          lP[prow * 64 + pc * 8 + (pcol & 7)] = f2b(s_acc[m][n][i]);
        }

    // O += P V
    __builtin_amdgcn_s_setprio(1);
#pragma unroll
    for (int ks = 0; ks < 2; ks++) {
      bf16x8 pf[2];
#pragma unroll
      for (int m = 0; m < 2; m++) {
        int row = w * 32 + m * 16 + lr;
        int pc = (ks * 4 + lc) ^ (row & 7);
        pf[m] = *(const bf16x8*)&lP[row * 64 + pc * 8];
      }
#pragma unroll
      for (int n = 0; n < 8; n++) {
        int row = n * 16 + lr;
        int pc = (ks * 4 + lc) ^ (row & 7);
        bf16x8 vf = *(const bf16x8*)&lV[cur][row * 64 + pc * 8];
        o_acc[0][n] = __builtin_amdgcn_mfma_f32_16x16x32_bf16(pf[0], vf, o_acc[0][n], 0, 0, 0);
        o_acc[1][n] = __builtin_amdgcn_mfma_f32_16x16x32_bf16(pf[1], vf, o_acc[1][n], 0, 0, 0);
      }
    }
    __builtin_amdgcn_s_setprio(0);

    __syncthreads();  // all reads of cur bufs done; prefetch (vmcnt) drained -> next buf ready
  }

  // epilogue: O *= 1/l, write bf16
  const long ybase = (long)(b * T_SEQ + qt * 128 + w * 32) * DMODEL + h * DHEAD;
#pragma unroll
  for (int m = 0; m < 2; m++)
#pragma unroll
    for (int i = 0; i < 4; i++) {
      float inv = __builtin_amdgcn_rcpf(l_st[m * 4 + i]);
#pragma unroll
      for (int n = 0; n < 8; n++) {
        float v = o_acc[m][n][i] * inv;
        Y[ybase + (long)(m * 16 + lc * 4 + i) * DMODEL + n * 16 + lr] = f2b(v);
      }
    }
}

extern "C" void kernel_launch(void* const* d_in, const int* in_sizes, int n_in,
                              void* d_out, int out_size, void* d_ws, size_t ws_size,
                              hipStream_t stream) {
  const float* x  = (const float*)d_in[0];
  const float* Wq = (const float*)d_in[1];
  const float* Wk = (const float*)d_in[2];
  const float* Wv = (const float*)d_in[3];
  const float* Wo = (const float*)d_in[4];
  float* out = (float*)d_out;
  char* ws = (char*)d_ws;

  const long MB32 = 33554432L;  // 8192*2048 bf16
  u16* xb  = (u16*)(ws);                       // x bf16; later aliased by Vt
  u16* Wqt = (u16*)(ws + MB32);
  u16* Wkt = (u16*)(ws + MB32 + 8388608L);
  u16* Wvt = (u16*)(ws + MB32 + 16777216L);
  u16* Wot = (u16*)(ws + MB32 + 25165824L);
  u16* Qb  = (u16*)(ws + 2 * MB32);
  u16* Kb  = (u16*)(ws + 3 * MB32);
  u16* Vb  = (u16*)(ws + 4 * MB32);
  u16* Vtb = xb;   // alias: xb dead after V projection
  u16* Yb  = Vb;   // alias: Vb dead after vtrans
  // total ws usage: 5*32MiB = 160 MiB

  cast_f32_bf16<<<8192, 256, 0, stream>>>(x, xb);
  dim3 wt_g(32, 32);
  wtrans_kernel<<<wt_g, 256, 0, stream>>>(Wq, Wqt);
  wtrans_kernel<<<wt_g, 256, 0, stream>>>(Wk, Wkt);
  wtrans_kernel<<<wt_g, 256, 0, stream>>>(Wv, Wvt);
  wtrans_kernel<<<wt_g, 256, 0, stream>>>(Wo, Wot);

  gemm_bt<0><<<256, 512, 0, stream>>>(xb, Wqt, Qb, 8192, 2048, 2048);
  gemm_bt<0><<<256, 512, 0, stream>>>(xb, Wkt, Kb, 8192, 2048, 2048);
  gemm_bt<0><<<256, 512, 0, stream>>>(xb, Wvt, Vb, 8192, 2048, 2048);

  rope_kernel<<<8192, 256, 0, stream>>>(Qb);
  rope_kernel<<<8192, 256, 0, stream>>>(Kb);

  dim3 vt_g(32, 2, 64);
  vtrans_kernel<<<vt_g, 256, 0, stream>>>(Vb, Vtb);

  attn_kernel<<<1024, 256, 0, stream>>>(Qb, Kb, Vtb, Yb);

  gemm_bt<1><<<256, 512, 0, stream>>>(Yb, Wot, (void*)out, 8192, 2048, 2048);
}

// Round 5
// 470.121 us; speedup vs baseline: 2.5018x; 1.0824x over previous
//
#include <hip/hip_runtime.h>
#include <hip/hip_bf16.h>
#include <math.h>

typedef unsigned short u16;
typedef __attribute__((ext_vector_type(8))) __bf16 bf16x8;
typedef __attribute__((ext_vector_type(4))) float f32x4;
typedef __attribute__((ext_vector_type(16))) float f32x16;
typedef __attribute__((ext_vector_type(8))) u16 u16x8;
typedef __attribute__((ext_vector_type(4))) u16 u16x4;
typedef __attribute__((ext_vector_type(4))) unsigned u32x4;

#define T_SEQ 2048
#define DMODEL 2048
#define NH 16
#define DHEAD 128
#define BATCH 4
#define ATTN_SCALE 0.08838834764831845f
// ATTN_SCALE * log2(e): softmax runs in exp2 domain, scale folded into Q
#define QSCALE_LOG2E 0.1275411278534803f

// async global->LDS, 16B per lane, wave-uniform LDS base + lane*16
#define GLOAD(gp, lp) __builtin_amdgcn_global_load_lds( \
    (const __attribute__((address_space(1))) void*)(gp), \
    (__attribute__((address_space(3))) void*)(lp), 16, 0, 0)

#define BAR() __builtin_amdgcn_s_barrier()
#define LGKM0() do { asm volatile("s_waitcnt lgkmcnt(0)" ::: "memory"); \
                     __builtin_amdgcn_sched_barrier(0); } while (0)
#define VMCNT4() asm volatile("s_waitcnt vmcnt(4)" ::: "memory")
#define MFMA32(A, B, C) __builtin_amdgcn_mfma_f32_32x32x16_bf16(A, B, C, 0, 0, 0)

__device__ __forceinline__ float b2f(u16 u) {
  union { float f; unsigned int i; } x; x.i = ((unsigned int)u) << 16; return x.f;
}
// hardware RTNE cast
__device__ __forceinline__ u16 f2b(float f) {
  __bf16 h = (__bf16)f;
  return *(u16*)&h;
}
// pack two f32 -> one u32 of 2 bf16 (lo in bits 0-15)
__device__ __forceinline__ unsigned pk2(float lo, float hi2) {
  __bf16 a = (__bf16)lo, b = (__bf16)hi2;
  unsigned short ua = *(unsigned short*)&a, ub = *(unsigned short*)&b;
  return (unsigned)ua | ((unsigned)ub << 16);
}

// ---------------- cast x: f32 -> bf16 ----------------
__global__ __launch_bounds__(256) void cast_f32_bf16(const float* __restrict__ in,
                                                     u16* __restrict__ out) {
  long i = ((long)blockIdx.x * 256 + threadIdx.x) * 8;
  float4 a = *(const float4*)(in + i);
  float4 b = *(const float4*)(in + i + 4);
  u16x8 r;
  r[0] = f2b(a.x); r[1] = f2b(a.y); r[2] = f2b(a.z); r[3] = f2b(a.w);
  r[4] = f2b(b.x); r[5] = f2b(b.y); r[6] = f2b(b.z); r[7] = f2b(b.w);
  *(u16x8*)(out + i) = r;
}

// ---------------- weight transpose + cast: W[k][n] f32 -> Wt[n][k] bf16 ----------------
__global__ __launch_bounds__(256) void wtrans_kernel(const float* __restrict__ W,
                                                     u16* __restrict__ Wt) {
  __shared__ float tile[64][65];
  const int k0 = blockIdx.x * 64, n0 = blockIdx.y * 64;
  const int c = threadIdx.x & 63, r4 = threadIdx.x >> 6;
#pragma unroll
  for (int p = 0; p < 16; p++) {
    int r = p * 4 + r4;
    tile[r][c] = W[(long)(k0 + r) * DMODEL + n0 + c];
  }
  __syncthreads();
#pragma unroll
  for (int p = 0; p < 16; p++) {
    int r = p * 4 + r4;
    Wt[(long)(n0 + r) * DMODEL + k0 + c] = f2b(tile[c][r]);
  }
}

// ---------------- V transpose per (b,h): V[b*T+s][h*128+f] -> Vt[(bh*128+f)][s] ----------------
__global__ __launch_bounds__(256) void vtrans_kernel(const u16* __restrict__ V,
                                                     u16* __restrict__ Vt) {
  __shared__ u16 tile[64][66];
  const int s0 = blockIdx.x * 64, f0 = blockIdx.y * 64;
  const int bh = blockIdx.z;
  const int b = bh >> 4, h = bh & 15;
  const int c = threadIdx.x & 63, r4 = threadIdx.x >> 6;
#pragma unroll
  for (int p = 0; p < 16; p++) {
    int r = p * 4 + r4; // s-local
    tile[r][c] = V[(long)(b * T_SEQ + s0 + r) * DMODEL + h * DHEAD + f0 + c];
  }
  __syncthreads();
#pragma unroll
  for (int p = 0; p < 16; p++) {
    int r = p * 4 + r4; // f-local
    Vt[(long)(bh * DHEAD + f0 + r) * T_SEQ + s0 + c] = tile[c][r];
  }
}

// ---------------- RoPE in place on bf16 [B*T][D], interleaved pairs ----------------
__global__ __launch_bounds__(256) void rope_kernel(u16* __restrict__ X) {
  int idx = blockIdx.x * 256 + threadIdx.x;  // B*T*H*16 threads, 4 pairs each
  int i4 = idx & 15;
  int h = (idx >> 4) & 15;
  long bt = idx >> 8;
  int t = (int)(bt & (T_SEQ - 1));
  long off = bt * DMODEL + h * DHEAD + i4 * 8;
  u16x8 v = *(u16x8*)(X + off);
  float o[8];
#pragma unroll
  for (int j = 0; j < 4; j++) {
    int i = i4 * 4 + j;                 // pair index 0..63
    float inv = __builtin_amdgcn_exp2f((float)i * -0.20762050593045857f);
    float ang = (float)t * inv;
    float cs = cosf(ang), sn = sinf(ang);
    float x0 = b2f(v[2 * j]), x1 = b2f(v[2 * j + 1]);
    o[2 * j]     = x0 * cs - x1 * sn;
    o[2 * j + 1] = x1 * cs + x0 * sn;
  }
  u16x8 r;
#pragma unroll
  for (int j = 0; j < 8; j++) r[j] = f2b(o[j]);
  *(u16x8*)(X + off) = r;
}

// ---------------- GEMM: C[M][N] = A[M][K] * Bt[N][K]^T (bf16 in, f32 acc) ----------------
// 256x256 8-phase template, BK=64, 512 thr = 8 waves (2M x 4N), per-wave 128x64 out.
#define LOAD_A(q)                                                      \
  _Pragma("unroll") for (int k = 0; k < 2; k++)                        \
  _Pragma("unroll") for (int m = 0; m < 2; m++) {                      \
    int r = wr * 128 + (q) * 32 + m * 16 + lr;                         \
    int cc = (k * 4 + lc) ^ (r & 7);                                   \
    a[k][m] = *(const bf16x8*)&sA[par][r * 64 + cc * 8];               \
  }

#define LOAD_B()                                                       \
  _Pragma("unroll") for (int k = 0; k < 2; k++)                        \
  _Pragma("unroll") for (int n = 0; n < 4; n++) {                      \
    int r = wc * 64 + n * 16 + lr;                                     \
    int cc = (k * 4 + lc) ^ (r & 7);                                   \
    b[k][n] = *(const bf16x8*)&sB[par][r * 64 + cc * 8];               \
  }

#define MFMA_QUAD(q)                                                   \
  _Pragma("unroll") for (int k = 0; k < 2; k++)                        \
  _Pragma("unroll") for (int n = 0; n < 4; n++)                        \
  _Pragma("unroll") for (int m = 0; m < 2; m++)                        \
    acc[(q) * 2 + m][n] = __builtin_amdgcn_mfma_f32_16x16x32_bf16(     \
        a[k][m], b[k][n], acc[(q) * 2 + m][n], 0, 0, 0);

#define STAGE_HALF(g, ldsp, rc0, t_, h_)                               \
  _Pragma("unroll") for (int j = 0; j < 2; j++) {                      \
    int rl = (h_) * 128 + wid * 16 + j * 8 + (lane >> 3);              \
    int cc = (lane & 7) ^ (lane >> 3);                                 \
    GLOAD((g) + ((rc0) + rl) * (long)K + (long)(t_) * 64 + cc * 8,     \
          (ldsp) + (h_) * 128 * 64 + (wid * 16 + j * 8) * 64);         \
  }

template <int OUT_F32>
__global__ __launch_bounds__(512, 2) void gemm_bt(const u16* __restrict__ A,
                                                  const u16* __restrict__ Bt,
                                                  void* __restrict__ Cv,
                                                  int M, int N, int K) {
  __shared__ u16 sA[2][256 * 64];
  __shared__ u16 sB[2][256 * 64];
  const int tid = threadIdx.x, lane = tid & 63, wid = tid >> 6;
  const int wr = wid >> 2, wc = wid & 3;
  const int lr = lane & 15, lc = lane >> 4;
  const int id = blockIdx.x;
  const long row0 = (long)(id >> 3) * 256;   // 32 row tiles
  const long col0 = (long)(id & 7) * 256;    // 8 col tiles; id%8 -> XCD strip
  const int NT = K >> 6;

  f32x4 acc[8][4] = {};
  bf16x8 a[2][2], b[2][4];

  STAGE_HALF(Bt, &sB[0][0], col0, 0, 0);
  STAGE_HALF(Bt, &sB[0][0], col0, 0, 1);
  STAGE_HALF(A,  &sA[0][0], row0, 0, 0);
  STAGE_HALF(A,  &sA[0][0], row0, 0, 1);
  STAGE_HALF(Bt, &sB[1][0], col0, 1, 0);
  STAGE_HALF(Bt, &sB[1][0], col0, 1, 1);
  VMCNT4();
  BAR();

  for (int t = 0; t < NT; t++) {
    const int par = t & 1;
    // ---- phase 0 ----
    LOAD_B();
    LOAD_A(0);
    if (t + 1 < NT) { STAGE_HALF(A, &sA[par ^ 1][0], row0, t + 1, 0); }
    BAR(); LGKM0();
    __builtin_amdgcn_s_setprio(1); MFMA_QUAD(0); __builtin_amdgcn_s_setprio(0);
    BAR();
    // ---- phase 1 ----
    LOAD_A(1);
    if (t + 1 < NT) { STAGE_HALF(A, &sA[par ^ 1][0], row0, t + 1, 1); }
    if (t + 2 < NT) { STAGE_HALF(Bt, &sB[par][0], col0, t + 2, 0); }
    BAR(); LGKM0();
    __builtin_amdgcn_s_setprio(1); MFMA_QUAD(1); __builtin_amdgcn_s_setprio(0);
    BAR();
    // ---- phase 2 ----
    LOAD_A(2);
    if (t + 2 < NT) { STAGE_HALF(Bt, &sB[par][0], col0, t + 2, 1); }
    BAR(); LGKM0();
    __builtin_amdgcn_s_setprio(1); MFMA_QUAD(2); __builtin_amdgcn_s_setprio(0);
    BAR();
    // ---- phase 3 ----
    LOAD_A(3);
    VMCNT4();
    BAR(); LGKM0();
    __builtin_amdgcn_s_setprio(1); MFMA_QUAD(3); __builtin_amdgcn_s_setprio(0);
    BAR();
  }

#pragma unroll
  for (int mf = 0; mf < 8; mf++)
#pragma unroll
    for (int n = 0; n < 4; n++)
#pragma unroll
      for (int i = 0; i < 4; i++) {
        long row = row0 + wr * 128 + mf * 16 + lc * 4 + i;
        long col = col0 + wc * 64 + n * 16 + lr;
        float v = acc[mf][n][i];
        if (OUT_F32) ((float*)Cv)[row * N + col] = v;
        else ((u16*)Cv)[row * N + col] = f2b(v);
      }
}

// ---------------- flash attention: swapped QK^T, 32x32 MFMA, P in-register ----------------
// 1024 blocks (qt x bh), longest-first. 256 thr = 4 waves, each wave one 32x32 q-block
// (q = lane&31 lane-local). KVBLK=64 double-buffered (LDS 64KB -> 2 blocks/CU).
// QK^T: S^T = mfma(K-frag, Q-frag) -> lane holds q=lane&31, 32 s-values in regs.
// Softmax fully in-register: in-lane reduce + one shfl_xor(32); defer-max THR=8.
// P -> bf16 via paired casts; PV B-frags assembled with 16 shfl_xor(32) + cndmask
// (T12 pattern); PV: O^T = mfma(Vt-frag, P-frag) keeps q lane-local. No P LDS.
__global__ __launch_bounds__(256, 2) void attn_kernel(const u16* __restrict__ Q,
                                                      const u16* __restrict__ K,
                                                      const u16* __restrict__ Vt,
                                                      u16* __restrict__ Y) {
  __shared__ u16 lK[2][64 * 128];   // K tile: 64 s-rows x 128 d (chunk-swizzled)
  __shared__ u16 lV[2][128 * 64];   // Vt tile: 128 d-rows x 64 s (chunk-swizzled)
  const int tid = threadIdx.x, lane = tid & 63, w = tid >> 6;
  const int hi = lane >> 5, l31 = lane & 31;
  const int id = blockIdx.x;
  const int qt = 15 - (id >> 6);    // longest blocks dispatched first
  const int bh = id & 63;
  const int b = bh >> 4, h = bh & 15;
  const int qg = qt * 128 + w * 32 + l31;   // this lane's q row (global)
  const int swz = l31 & 7;

  // Q fragments (B-operand): qf[kd][j] = Q[qg][kd*16 + hi*8 + j], prescaled
  bf16x8 qf[8];
  const long qrow = (long)(b * T_SEQ + qg) * DMODEL + h * DHEAD;
#pragma unroll
  for (int kd = 0; kd < 8; kd++) {
    u16x8 raw = *(const u16x8*)(Q + qrow + kd * 16 + hi * 8);
    bf16x8 q;
#pragma unroll
    for (int j = 0; j < 8; j++) q[j] = (__bf16)(b2f(raw[j]) * QSCALE_LOG2E);
    qf[kd] = q;
  }

  f32x16 o0 = {}, o1 = {}, o2 = {}, o3 = {};  // O^T[d][q]: d = n*32+crow(r,hi), q lane-local
  float m_st = -INFINITY, l_st = 0.f;
  const int nt = (qt + 1) * 2;

#define STAGE(nb, kt_)                                                              \
  {                                                                                 \
    _Pragma("unroll")                                                               \
    for (int j = 0; j < 4; j++) {                                                   \
      int sb = (w * 4 + j) * 64;                                                    \
      int slot = sb + lane;                                                         \
      { int r = slot >> 4, pc = slot & 15, cc = pc ^ (r & 7);                       \
        GLOAD(K + (long)(b * T_SEQ + (kt_) * 64 + r) * DMODEL + h * DHEAD + cc * 8, \
              &lK[nb][sb * 8]); }                                                   \
      { int r = slot >> 3, pc = slot & 7, cc = pc ^ (r & 7);                        \
        GLOAD(Vt + (long)(bh * DHEAD + r) * T_SEQ + (kt_) * 64 + cc * 8,            \
              &lV[nb][sb * 8]); }                                                   \
    }                                                                               \
  }

  STAGE(0, 0);
  __syncthreads();

  for (int kt = 0; kt < nt; kt++) {
    const int cur = kt & 1;
    if (kt + 1 < nt) STAGE(cur ^ 1, kt + 1);

    // S^T = mfma(K, Q): st0 = s 0..31, st1 = s 32..63; lane: q=l31, s=crow(r,hi)
    f32x16 st0 = {}, st1 = {};
    __builtin_amdgcn_s_setprio(1);
#pragma unroll
    for (int kd = 0; kd < 8; kd++) {
      int pc = (kd * 2 + hi) ^ swz;
      bf16x8 kf0 = *(const bf16x8*)&lK[cur][l31 * 128 + pc * 8];
      bf16x8 kf1 = *(const bf16x8*)&lK[cur][(32 + l31) * 128 + pc * 8];
      st0 = MFMA32(kf0, qf[kd], st0);
      st1 = MFMA32(kf1, qf[kd], st1);
    }
    __builtin_amdgcn_s_setprio(0);

    // causal mask (diagonal region only)
    if (kt * 64 + 63 > qt * 128 + w * 32) {
#pragma unroll
      for (int r = 0; r < 16; r++) {
        int sl = kt * 64 + (r & 3) + 8 * (r >> 2) + 4 * hi;
        if (sl > qg) st0[r] = -1e30f;
        if (sl + 32 > qg) st1[r] = -1e30f;
      }
    }

    // online softmax, exp2 domain, in-lane + one cross-half shfl
    float mx = -1e30f;
#pragma unroll
    for (int r = 0; r < 16; r++) mx = fmaxf(mx, fmaxf(st0[r], st1[r]));
    mx = fmaxf(mx, __shfl_xor(mx, 32, 64));
    if (__any(mx > m_st + 8.0f)) {     // defer-max: skip rescale when growth small
      float mnew = fmaxf(m_st, mx);
      float corr = __builtin_amdgcn_exp2f(m_st - mnew);
      m_st = mnew;
      l_st *= corr;
#pragma unroll
      for (int r = 0; r < 16; r++) {
        o0[r] *= corr; o1[r] *= corr; o2[r] *= corr; o3[r] *= corr;
      }
    }
    float rs = 0.f;
#pragma unroll
    for (int r = 0; r < 16; r++) {
      st0[r] = __builtin_amdgcn_exp2f(st0[r] - m_st); rs += st0[r];
      st1[r] = __builtin_amdgcn_exp2f(st1[r] - m_st); rs += st1[r];
    }
    rs += __shfl_xor(rs, 32, 64);
    l_st += rs;

    // P -> bf16 PV B-frags in-register; O^T += mfma(Vt-frag, P-frag)
    __builtin_amdgcn_s_setprio(1);
#define PVHALF(stX, sb)                                                        \
    _Pragma("unroll")                                                          \
    for (int g = 0; g < 2; g++) {                                              \
      unsigned A0 = pk2(stX[8 * g + 0], stX[8 * g + 1]);                       \
      unsigned A1 = pk2(stX[8 * g + 2], stX[8 * g + 3]);                       \
      unsigned B0 = pk2(stX[8 * g + 4], stX[8 * g + 5]);                       \
      unsigned B1 = pk2(stX[8 * g + 6], stX[8 * g + 7]);                       \
      unsigned xA0 = __shfl_xor(A0, 32, 64);                                   \
      unsigned xA1 = __shfl_xor(A1, 32, 64);                                   \
      unsigned xB0 = __shfl_xor(B0, 32, 64);                                   \
      unsigned xB1 = __shfl_xor(B1, 32, 64);                                   \
      u32x4 pw;                                                                \
      pw[0] = hi ? xB0 : A0;                                                   \
      pw[1] = hi ? xB1 : A1;                                                   \
      pw[2] = hi ? B0 : xA0;                                                   \
      pw[3] = hi ? B1 : xA1;                                                   \
      bf16x8 pa = *(bf16x8*)&pw;                                               \
      const int ks = (sb) * 2 + g;                                             \
      int pc0 = (ks * 2 + hi) ^ swz;                                           \
      bf16x8 vb0 = *(const bf16x8*)&lV[cur][(l31) * 64 + pc0 * 8];             \
      o0 = MFMA32(vb0, pa, o0);                                                \
      bf16x8 vb1 = *(const bf16x8*)&lV[cur][(32 + l31) * 64 + pc0 * 8];        \
      o1 = MFMA32(vb1, pa, o1);                                                \
      bf16x8 vb2 = *(const bf16x8*)&lV[cur][(64 + l31) * 64 + pc0 * 8];        \
      o2 = MFMA32(vb2, pa, o2);                                                \
      bf16x8 vb3 = *(const bf16x8*)&lV[cur][(96 + l31) * 64 + pc0 * 8];        \
      o3 = MFMA32(vb3, pa, o3);                                                \
    }
    PVHALF(st0, 0)
    PVHALF(st1, 1)
#undef PVHALF
    __builtin_amdgcn_s_setprio(0);

    __syncthreads();  // all reads of cur bufs done; prefetch drained -> next buf ready
  }

  // epilogue: O^T *= 1/l, packed 8B stores; d = n*32 + rq*8 + hi*4 + j
  float inv = __builtin_amdgcn_rcpf(l_st);
#define WR(oN, n)                                                              \
  _Pragma("unroll")                                                            \
  for (int rq = 0; rq < 4; rq++) {                                             \
    u16x4 pk;                                                                  \
    _Pragma("unroll")                                                          \
    for (int j = 0; j < 4; j++) pk[j] = f2b(oN[rq * 4 + j] * inv);             \
    *(u16x4*)(Y + qrow + (n) * 32 + rq * 8 + hi * 4) = pk;                     \
  }
  WR(o0, 0) WR(o1, 1) WR(o2, 2) WR(o3, 3)
#undef WR
#undef STAGE
}

extern "C" void kernel_launch(void* const* d_in, const int* in_sizes, int n_in,
                              void* d_out, int out_size, void* d_ws, size_t ws_size,
                              hipStream_t stream) {
  const float* x  = (const float*)d_in[0];
  const float* Wq = (const float*)d_in[1];
  const float* Wk = (const float*)d_in[2];
  const float* Wv = (const float*)d_in[3];
  const float* Wo = (const float*)d_in[4];
  float* out = (float*)d_out;
  char* ws = (char*)d_ws;

  const long MB32 = 33554432L;  // 8192*2048 bf16
  u16* xb  = (u16*)(ws);                       // x bf16; later aliased by Vt
  u16* Wqt = (u16*)(ws + MB32);
  u16* Wkt = (u16*)(ws + MB32 + 8388608L);
  u16* Wvt = (u16*)(ws + MB32 + 16777216L);
  u16* Wot = (u16*)(ws + MB32 + 25165824L);
  u16* Qb  = (u16*)(ws + 2 * MB32);
  u16* Kb  = (u16*)(ws + 3 * MB32);
  u16* Vb  = (u16*)(ws + 4 * MB32);
  u16* Vtb = xb;   // alias: xb dead after V projection
  u16* Yb  = Vb;   // alias: Vb dead after vtrans
  // total ws usage: 5*32MiB = 160 MiB

  cast_f32_bf16<<<8192, 256, 0, stream>>>(x, xb);
  dim3 wt_g(32, 32);
  wtrans_kernel<<<wt_g, 256, 0, stream>>>(Wq, Wqt);
  wtrans_kernel<<<wt_g, 256, 0, stream>>>(Wk, Wkt);
  wtrans_kernel<<<wt_g, 256, 0, stream>>>(Wv, Wvt);
  wtrans_kernel<<<wt_g, 256, 0, stream>>>(Wo, Wot);

  gemm_bt<0><<<256, 512, 0, stream>>>(xb, Wqt, Qb, 8192, 2048, 2048);
  gemm_bt<0><<<256, 512, 0, stream>>>(xb, Wkt, Kb, 8192, 2048, 2048);
  gemm_bt<0><<<256, 512, 0, stream>>>(xb, Wvt, Vb, 8192, 2048, 2048);

  rope_kernel<<<8192, 256, 0, stream>>>(Qb);
  rope_kernel<<<8192, 256, 0, stream>>>(Kb);

  dim3 vt_g(32, 2, 64);
  vtrans_kernel<<<vt_g, 256, 0, stream>>>(Vb, Vtb);

  attn_kernel<<<1024, 256, 0, stream>>>(Qb, Kb, Vtb, Yb);

  gemm_bt<1><<<256, 512, 0, stream>>>(Yb, Wot, (void*)out, 8192, 2048, 2048);
}

// Round 8
// 451.777 us; speedup vs baseline: 2.6034x; 1.0406x over previous
//
#include <hip/hip_runtime.h>
#include <hip/hip_bf16.h>
#include <math.h>

typedef unsigned short u16;
typedef __attribute__((ext_vector_type(8))) __bf16 bf16x8;
typedef __attribute__((ext_vector_type(4))) float f32x4;
typedef __attribute__((ext_vector_type(16))) float f32x16;
typedef __attribute__((ext_vector_type(8))) u16 u16x8;
typedef __attribute__((ext_vector_type(4))) u16 u16x4;
typedef __attribute__((ext_vector_type(4))) unsigned u32x4;

#define T_SEQ 2048
#define DMODEL 2048
#define NH 16
#define DHEAD 128
#define BATCH 4
#define QKV_STR 6144            // fused QKV row stride (Q | K | V concatenated)
#define ATTN_SCALE 0.08838834764831845f
#define QSCALE_LOG2E 0.1275411278534803f   // ATTN_SCALE * log2(e)

#define GLOAD(gp, lp) __builtin_amdgcn_global_load_lds( \
    (const __attribute__((address_space(1))) void*)(gp), \
    (__attribute__((address_space(3))) void*)(lp), 16, 0, 0)

#define BAR() __builtin_amdgcn_s_barrier()
#define LGKM0() do { asm volatile("s_waitcnt lgkmcnt(0)" ::: "memory"); \
                     __builtin_amdgcn_sched_barrier(0); } while (0)
#define VMCNT4() asm volatile("s_waitcnt vmcnt(4)" ::: "memory")
#define MFMA32(A, B, C) __builtin_amdgcn_mfma_f32_32x32x16_bf16(A, B, C, 0, 0, 0)

__device__ __forceinline__ float b2f(u16 u) {
  union { float f; unsigned int i; } x; x.i = ((unsigned int)u) << 16; return x.f;
}
__device__ __forceinline__ u16 f2b(float f) {
  __bf16 h = (__bf16)f;
  return *(u16*)&h;
}
__device__ __forceinline__ unsigned pk2(float lo, float hi2) {
  __bf16 a = (__bf16)lo, b = (__bf16)hi2;
  unsigned short ua = *(unsigned short*)&a, ub = *(unsigned short*)&b;
  return (unsigned)ua | ((unsigned)ub << 16);
}

// ---------------- cast x: f32 -> bf16 ----------------
__global__ __launch_bounds__(256) void cast_f32_bf16(const float* __restrict__ in,
                                                     u16* __restrict__ out) {
  long i = ((long)blockIdx.x * 256 + threadIdx.x) * 8;
  float4 a = *(const float4*)(in + i);
  float4 b = *(const float4*)(in + i + 4);
  u16x8 r;
  r[0] = f2b(a.x); r[1] = f2b(a.y); r[2] = f2b(a.z); r[3] = f2b(a.w);
  r[4] = f2b(b.x); r[5] = f2b(b.y); r[6] = f2b(b.z); r[7] = f2b(b.w);
  *(u16x8*)(out + i) = r;
}

// ---------------- weight transpose + cast: W[k][n] f32 -> Wt[n][k] bf16 ----------------
__global__ __launch_bounds__(256) void wtrans_kernel(const float* __restrict__ W,
                                                     u16* __restrict__ Wt) {
  __shared__ float tile[64][65];
  const int k0 = blockIdx.x * 64, n0 = blockIdx.y * 64;
  const int c = threadIdx.x & 63, r4 = threadIdx.x >> 6;
#pragma unroll
  for (int p = 0; p < 16; p++) {
    int r = p * 4 + r4;
    tile[r][c] = W[(long)(k0 + r) * DMODEL + n0 + c];
  }
  __syncthreads();
#pragma unroll
  for (int p = 0; p < 16; p++) {
    int r = p * 4 + r4;
    Wt[(long)(n0 + r) * DMODEL + k0 + c] = f2b(tile[c][r]);
  }
}

// ---------------- V transpose: Cqkv V-region [b*T+s][4096 + h*128+f] -> Vt[(bh*128+f)][s] ----------------
__global__ __launch_bounds__(256) void vtrans_kernel(const u16* __restrict__ C,
                                                     u16* __restrict__ Vt) {
  __shared__ u16 tile[64][66];
  const int s0 = blockIdx.x * 64, f0 = blockIdx.y * 64;
  const int bh = blockIdx.z;
  const int b = bh >> 4, h = bh & 15;
  const int c = threadIdx.x & 63, r4 = threadIdx.x >> 6;
#pragma unroll
  for (int p = 0; p < 16; p++) {
    int r = p * 4 + r4; // s-local
    tile[r][c] = C[(long)(b * T_SEQ + s0 + r) * QKV_STR + 4096 + h * DHEAD + f0 + c];
  }
  __syncthreads();
#pragma unroll
  for (int p = 0; p < 16; p++) {
    int r = p * 4 + r4; // f-local
    Vt[(long)(bh * DHEAD + f0 + r) * T_SEQ + s0 + c] = tile[c][r];
  }
}

// ---------------- RoPE in place on Cqkv cols 0..4095 (Q and K regions) ----------------
__global__ __launch_bounds__(256) void rope_qk_kernel(u16* __restrict__ X) {
  int idx = blockIdx.x * 256 + threadIdx.x;  // B*T*512 threads, 8 elems each
  int c8 = idx & 511;                        // chunk of 8 within the 4096 QK cols
  long row = idx >> 9;
  int t = (int)(row & (T_SEQ - 1));
  int i4 = c8 & 15;                          // chunk within the 128-wide head
  long off = row * QKV_STR + (long)c8 * 8;
  u16x8 v = *(u16x8*)(X + off);
  float o[8];
#pragma unroll
  for (int j = 0; j < 4; j++) {
    int i = i4 * 4 + j;                      // pair index 0..63
    float inv = __builtin_amdgcn_exp2f((float)i * -0.20762050593045857f);
    float ang = (float)t * inv;
    float cs = cosf(ang), sn = sinf(ang);
    float x0 = b2f(v[2 * j]), x1 = b2f(v[2 * j + 1]);
    o[2 * j]     = x0 * cs - x1 * sn;
    o[2 * j + 1] = x1 * cs + x0 * sn;
  }
  u16x8 r;
#pragma unroll
  for (int j = 0; j < 8; j++) r[j] = f2b(o[j]);
  *(u16x8*)(X + off) = r;
}

// ---------------- GEMM: C[M][N] = A[M][K] * Bt[N][K]^T (bf16 in, f32 acc) ----------------
// 256x256 8-phase template, BK=64, 512 thr = 8 waves (2M x 4N), per-wave 128x64 out.
// LDS 128KB -> 1 block/CU. A has explicit lda (fused-QKV Y region has stride 6144).
#define LOAD_A(q)                                                      \
  _Pragma("unroll") for (int k = 0; k < 2; k++)                        \
  _Pragma("unroll") for (int m = 0; m < 2; m++) {                      \
    int r = wr * 128 + (q) * 32 + m * 16 + lr;                         \
    int cc = (k * 4 + lc) ^ (r & 7);                                   \
    a[k][m] = *(const bf16x8*)&sA[par][r * 64 + cc * 8];               \
  }

#define LOAD_B()                                                       \
  _Pragma("unroll") for (int k = 0; k < 2; k++)                        \
  _Pragma("unroll") for (int n = 0; n < 4; n++) {                      \
    int r = wc * 64 + n * 16 + lr;                                     \
    int cc = (k * 4 + lc) ^ (r & 7);                                   \
    b[k][n] = *(const bf16x8*)&sB[par][r * 64 + cc * 8];               \
  }

#define MFMA_QUAD(q)                                                   \
  _Pragma("unroll") for (int k = 0; k < 2; k++)                        \
  _Pragma("unroll") for (int n = 0; n < 4; n++)                        \
  _Pragma("unroll") for (int m = 0; m < 2; m++)                        \
    acc[(q) * 2 + m][n] = __builtin_amdgcn_mfma_f32_16x16x32_bf16(     \
        a[k][m], b[k][n], acc[(q) * 2 + m][n], 0, 0, 0);

#define STAGE_HALF(g, ld, ldsp, rc0, t_, h_)                           \
  _Pragma("unroll") for (int j = 0; j < 2; j++) {                      \
    int rl = (h_) * 128 + wid * 16 + j * 8 + (lane >> 3);              \
    int cc = (lane & 7) ^ (lane >> 3);                                 \
    GLOAD((g) + ((rc0) + rl) * (long)(ld) + (long)(t_) * 64 + cc * 8,  \
          (ldsp) + (h_) * 128 * 64 + (wid * 16 + j * 8) * 64);         \
  }

template <int OUT_F32>
__global__ __launch_bounds__(512, 2) void gemm_bt(const u16* __restrict__ A, long lda,
                                                  const u16* __restrict__ Bt,
                                                  void* __restrict__ Cv,
                                                  int M, int N, int K) {
  __shared__ u16 sA[2][256 * 64];
  __shared__ u16 sB[2][256 * 64];
  const int tid = threadIdx.x, lane = tid & 63, wid = tid >> 6;
  const int wr = wid >> 2, wc = wid & 3;
  const int lr = lane & 15, lc = lane >> 4;
  const int id = blockIdx.x;
  // XCD strip mapping: xcd = id&7 owns col-tiles {xcd, xcd+8, ...}; bijective for N%2048==0
  const int per = (N >> 8) >> 3;             // col-tiles per XCD (1 for N=2048, 3 for 6144)
  const int g8 = id >> 3;
  const long col0 = (long)((id & 7) + 8 * (g8 % per)) * 256;
  const long row0 = (long)(g8 / per) * 256;
  const int NT = K >> 6;

  f32x4 acc[8][4] = {};
  bf16x8 a[2][2], b[2][4];

  STAGE_HALF(Bt, K, &sB[0][0], col0, 0, 0);
  STAGE_HALF(Bt, K, &sB[0][0], col0, 0, 1);
  STAGE_HALF(A, lda, &sA[0][0], row0, 0, 0);
  STAGE_HALF(A, lda, &sA[0][0], row0, 0, 1);
  STAGE_HALF(Bt, K, &sB[1][0], col0, 1, 0);
  STAGE_HALF(Bt, K, &sB[1][0], col0, 1, 1);
  VMCNT4();
  BAR();

  for (int t = 0; t < NT; t++) {
    const int par = t & 1;
    // ---- phase 0 ----
    LOAD_B();
    LOAD_A(0);
    if (t + 1 < NT) { STAGE_HALF(A, lda, &sA[par ^ 1][0], row0, t + 1, 0); }
    BAR(); LGKM0();
    __builtin_amdgcn_s_setprio(1); MFMA_QUAD(0); __builtin_amdgcn_s_setprio(0);
    BAR();
    // ---- phase 1 ----
    LOAD_A(1);
    if (t + 1 < NT) { STAGE_HALF(A, lda, &sA[par ^ 1][0], row0, t + 1, 1); }
    if (t + 2 < NT) { STAGE_HALF(Bt, K, &sB[par][0], col0, t + 2, 0); }
    BAR(); LGKM0();
    __builtin_amdgcn_s_setprio(1); MFMA_QUAD(1); __builtin_amdgcn_s_setprio(0);
    BAR();
    // ---- phase 2 ----
    LOAD_A(2);
    if (t + 2 < NT) { STAGE_HALF(Bt, K, &sB[par][0], col0, t + 2, 1); }
    BAR(); LGKM0();
    __builtin_amdgcn_s_setprio(1); MFMA_QUAD(2); __builtin_amdgcn_s_setprio(0);
    BAR();
    // ---- phase 3 ----
    LOAD_A(3);
    VMCNT4();
    BAR(); LGKM0();
    __builtin_amdgcn_s_setprio(1); MFMA_QUAD(3); __builtin_amdgcn_s_setprio(0);
    BAR();
  }

#pragma unroll
  for (int mf = 0; mf < 8; mf++)
#pragma unroll
    for (int n = 0; n < 4; n++)
#pragma unroll
      for (int i = 0; i < 4; i++) {
        long row = row0 + wr * 128 + mf * 16 + lc * 4 + i;
        long col = col0 + wc * 64 + n * 16 + lr;
        float v = acc[mf][n][i];
        if (OUT_F32) ((float*)Cv)[row * N + col] = v;
        else ((u16*)Cv)[row * N + col] = f2b(v);
      }
}

// ---------------- flash attention: swapped QK^T, 32x32 MFMA, P in-register ----------------
// Reads Q (col 0..2047) and K (col 2048..4095) from fused Cqkv (stride 6144); writes Y
// into the dead V region (col 4096..6143). Cross-half moves via __shfl_xor (proven r5).
__global__ __launch_bounds__(256, 2) void attn_kernel(const u16* __restrict__ QK,
                                                      const u16* __restrict__ Vt) {
  __shared__ u16 lK[2][64 * 128];   // K tile: 64 s-rows x 128 d (chunk-swizzled)
  __shared__ u16 lV[2][128 * 64];   // Vt tile: 128 d-rows x 64 s (chunk-swizzled)
  const int tid = threadIdx.x, lane = tid & 63, w = tid >> 6;
  const int hi = lane >> 5, l31 = lane & 31;
  const int id = blockIdx.x;
  const int qt = 15 - (id >> 6);    // longest blocks dispatched first
  const int bh = id & 63;
  const int b = bh >> 4, h = bh & 15;
  const int qg = qt * 128 + w * 32 + l31;   // this lane's q row (global)
  const int swz = l31 & 7;

  // Q fragments (B-operand): qf[kd][j] = Q[qg][kd*16 + hi*8 + j], prescaled
  bf16x8 qf[8];
  const long qrow = (long)(b * T_SEQ + qg) * QKV_STR + h * DHEAD;
#pragma unroll
  for (int kd = 0; kd < 8; kd++) {
    u16x8 raw = *(const u16x8*)(QK + qrow + kd * 16 + hi * 8);
    bf16x8 q;
#pragma unroll
    for (int j = 0; j < 8; j++) q[j] = (__bf16)(b2f(raw[j]) * QSCALE_LOG2E);
    qf[kd] = q;
  }

  f32x16 o0 = {}, o1 = {}, o2 = {}, o3 = {};  // O^T[d][q]: q lane-local
  float m_st = -INFINITY, l_st = 0.f;
  const int nt = (qt + 1) * 2;

#define STAGE(nb, kt_)                                                              \
  {                                                                                 \
    _Pragma("unroll")                                                               \
    for (int j = 0; j < 4; j++) {                                                   \
      int sb = (w * 4 + j) * 64;                                                    \
      int slot = sb + lane;                                                         \
      { int r = slot >> 4, pc = slot & 15, cc = pc ^ (r & 7);                       \
        GLOAD(QK + (long)(b * T_SEQ + (kt_) * 64 + r) * QKV_STR + 2048 +            \
                  h * DHEAD + cc * 8,                                               \
              &lK[nb][sb * 8]); }                                                   \
      { int r = slot >> 3, pc = slot & 7, cc = pc ^ (r & 7);                        \
        GLOAD(Vt + (long)(bh * DHEAD + r) * T_SEQ + (kt_) * 64 + cc * 8,            \
              &lV[nb][sb * 8]); }                                                   \
    }                                                                               \
  }

  STAGE(0, 0);
  __syncthreads();

  for (int kt = 0; kt < nt; kt++) {
    const int cur = kt & 1;
    if (kt + 1 < nt) STAGE(cur ^ 1, kt + 1);

    // S^T = mfma(K, Q): st0 = s 0..31, st1 = s 32..63; lane: q=l31, s=crow(r,hi)
    f32x16 st0 = {}, st1 = {};
    __builtin_amdgcn_s_setprio(1);
#pragma unroll
    for (int kd = 0; kd < 8; kd++) {
      int pc = (kd * 2 + hi) ^ swz;
      bf16x8 kf0 = *(const bf16x8*)&lK[cur][l31 * 128 + pc * 8];
      bf16x8 kf1 = *(const bf16x8*)&lK[cur][(32 + l31) * 128 + pc * 8];
      st0 = MFMA32(kf0, qf[kd], st0);
      st1 = MFMA32(kf1, qf[kd], st1);
    }
    __builtin_amdgcn_s_setprio(0);

    // causal mask (diagonal region only)
    if (kt * 64 + 63 > qt * 128 + w * 32) {
#pragma unroll
      for (int r = 0; r < 16; r++) {
        int sl = kt * 64 + (r & 3) + 8 * (r >> 2) + 4 * hi;
        if (sl > qg) st0[r] = -1e30f;
        if (sl + 32 > qg) st1[r] = -1e30f;
      }
    }

    // online softmax, exp2 domain, in-lane + one cross-half shfl reduce
    float mx = -1e30f;
#pragma unroll
    for (int r = 0; r < 16; r++) mx = fmaxf(mx, fmaxf(st0[r], st1[r]));
    mx = fmaxf(mx, __shfl_xor(mx, 32, 64));
    if (__any(mx > m_st + 8.0f)) {     // defer-max
      float mnew = fmaxf(m_st, mx);
      float corr = __builtin_amdgcn_exp2f(m_st - mnew);
      m_st = mnew;
      l_st *= corr;
#pragma unroll
      for (int r = 0; r < 16; r++) {
        o0[r] *= corr; o1[r] *= corr; o2[r] *= corr; o3[r] *= corr;
      }
    }
    float rs = 0.f;
#pragma unroll
    for (int r = 0; r < 16; r++) {
      st0[r] = __builtin_amdgcn_exp2f(st0[r] - m_st); rs += st0[r];
      st1[r] = __builtin_amdgcn_exp2f(st1[r] - m_st); rs += st1[r];
    }
    l_st += rs + __shfl_xor(rs, 32, 64);

    // P -> bf16 PV B-frags via shfl_xor + select (proven r5); O^T += mfma(Vt, P)
    __builtin_amdgcn_s_setprio(1);
#define PVHALF(stX, sb)                                                        \
    _Pragma("unroll")                                                          \
    for (int g = 0; g < 2; g++) {                                              \
      unsigned A0 = pk2(stX[8 * g + 0], stX[8 * g + 1]);                       \
      unsigned A1 = pk2(stX[8 * g + 2], stX[8 * g + 3]);                       \
      unsigned B0 = pk2(stX[8 * g + 4], stX[8 * g + 5]);                       \
      unsigned B1 = pk2(stX[8 * g + 6], stX[8 * g + 7]);                       \
      unsigned xA0 = __shfl_xor(A0, 32, 64);                                   \
      unsigned xA1 = __shfl_xor(A1, 32, 64);                                   \
      unsigned xB0 = __shfl_xor(B0, 32, 64);                                   \
      unsigned xB1 = __shfl_xor(B1, 32, 64);                                   \
      u32x4 pw;                                                                \
      pw[0] = hi ? xB0 : A0;                                                   \
      pw[1] = hi ? xB1 : A1;                                                   \
      pw[2] = hi ? B0 : xA0;                                                   \
      pw[3] = hi ? B1 : xA1;                                                   \
      bf16x8 pa = *(bf16x8*)&pw;                                               \
      const int ks = (sb) * 2 + g;                                             \
      int pc0 = (ks * 2 + hi) ^ swz;                                           \
      bf16x8 vb0 = *(const bf16x8*)&lV[cur][(l31) * 64 + pc0 * 8];             \
      o0 = MFMA32(vb0, pa, o0);                                                \
      bf16x8 vb1 = *(const bf16x8*)&lV[cur][(32 + l31) * 64 + pc0 * 8];        \
      o1 = MFMA32(vb1, pa, o1);                                                \
      bf16x8 vb2 = *(const bf16x8*)&lV[cur][(64 + l31) * 64 + pc0 * 8];        \
      o2 = MFMA32(vb2, pa, o2);                                                \
      bf16x8 vb3 = *(const bf16x8*)&lV[cur][(96 + l31) * 64 + pc0 * 8];        \
      o3 = MFMA32(vb3, pa, o3);                                                \
    }
    PVHALF(st0, 0)
    PVHALF(st1, 1)
#undef PVHALF
    __builtin_amdgcn_s_setprio(0);

    __syncthreads();
  }

  // epilogue: O^T *= 1/l, packed 8B stores into the Y (dead V) region
  float inv = __builtin_amdgcn_rcpf(l_st);
#define WR(oN, n)                                                              \
  _Pragma("unroll")                                                            \
  for (int rq = 0; rq < 4; rq++) {                                             \
    u16x4 pk;                                                                  \
    _Pragma("unroll")                                                          \
    for (int j = 0; j < 4; j++) pk[j] = f2b(oN[rq * 4 + j] * inv);             \
    *(u16x4*)((u16*)QK + qrow + 4096 + (n) * 32 + rq * 8 + hi * 4) = pk;       \
  }
  WR(o0, 0) WR(o1, 1) WR(o2, 2) WR(o3, 3)
#undef WR
#undef STAGE
}

extern "C" void kernel_launch(void* const* d_in, const int* in_sizes, int n_in,
                              void* d_out, int out_size, void* d_ws, size_t ws_size,
                              hipStream_t stream) {
  const float* x  = (const float*)d_in[0];
  const float* Wq = (const float*)d_in[1];
  const float* Wk = (const float*)d_in[2];
  const float* Wv = (const float*)d_in[3];
  const float* Wo = (const float*)d_in[4];
  float* out = (float*)d_out;
  char* ws = (char*)d_ws;

  const long MB = 1048576L;
  // layout: xb 32MB (aliased by Vt later); Wqt/Wkt/Wvt contiguous 24MB fused Bt;
  // Wot 8MB; Cqkv 96MB = [8192][6144] (Q | K | V-then-Y). Total 160MB.
  u16* xb   = (u16*)(ws);
  u16* Wqt  = (u16*)(ws + 32 * MB);
  u16* Wkt  = (u16*)(ws + 40 * MB);
  u16* Wvt  = (u16*)(ws + 48 * MB);
  u16* Wot  = (u16*)(ws + 56 * MB);
  u16* Cqkv = (u16*)(ws + 64 * MB);
  u16* Vtb  = xb;   // alias: xb dead after QKV projection

  cast_f32_bf16<<<8192, 256, 0, stream>>>(x, xb);
  dim3 wt_g(32, 32);
  wtrans_kernel<<<wt_g, 256, 0, stream>>>(Wq, Wqt);
  wtrans_kernel<<<wt_g, 256, 0, stream>>>(Wk, Wkt);
  wtrans_kernel<<<wt_g, 256, 0, stream>>>(Wv, Wvt);
  wtrans_kernel<<<wt_g, 256, 0, stream>>>(Wo, Wot);

  // fused QKV projection: C[8192][6144] = xb @ [Wq|Wk|Wv]^T
  gemm_bt<0><<<768, 512, 0, stream>>>(xb, 2048, Wqt, Cqkv, 8192, 6144, 2048);

  rope_qk_kernel<<<16384, 256, 0, stream>>>(Cqkv);

  dim3 vt_g(32, 2, 64);
  vtrans_kernel<<<vt_g, 256, 0, stream>>>(Cqkv, Vtb);

  attn_kernel<<<1024, 256, 0, stream>>>(Cqkv, Vtb);

  // output projection: reads Y from the V region (lda = 6144)
  gemm_bt<1><<<256, 512, 0, stream>>>(Cqkv + 4096, QKV_STR, Wot, (void*)out,
                                      8192, 2048, 2048);
}

// Round 9
// 444.631 us; speedup vs baseline: 2.6452x; 1.0161x over previous
//
#include <hip/hip_runtime.h>
#include <hip/hip_bf16.h>
#include <math.h>

typedef unsigned short u16;
typedef __attribute__((ext_vector_type(8))) __bf16 bf16x8;
typedef __attribute__((ext_vector_type(4))) float f32x4;
typedef __attribute__((ext_vector_type(16))) float f32x16;
typedef __attribute__((ext_vector_type(8))) u16 u16x8;
typedef __attribute__((ext_vector_type(4))) u16 u16x4;
typedef __attribute__((ext_vector_type(4))) unsigned u32x4;

#define T_SEQ 2048
#define DMODEL 2048
#define NH 16
#define DHEAD 128
#define BATCH 4
#define QKV_STR 6144            // fused QKV row stride (Q | K | V concatenated)
#define ATTN_SCALE 0.08838834764831845f
#define QSCALE_LOG2E 0.1275411278534803f   // ATTN_SCALE * log2(e)

#define GLOAD(gp, lp) __builtin_amdgcn_global_load_lds( \
    (const __attribute__((address_space(1))) void*)(gp), \
    (__attribute__((address_space(3))) void*)(lp), 16, 0, 0)

#define BAR() __builtin_amdgcn_s_barrier()
// lgkmcnt(0) with memory clobber orders all memory ops (phase-liveness safety);
// NO sched_barrier: ds_reads are compiler-emitted (deps tracked), fence was pure cost.
#define LGKM0() asm volatile("s_waitcnt lgkmcnt(0)" ::: "memory")
#define VMCNT4() asm volatile("s_waitcnt vmcnt(4)" ::: "memory")
#define MFMA32(A, B, C) __builtin_amdgcn_mfma_f32_32x32x16_bf16(A, B, C, 0, 0, 0)

__device__ __forceinline__ float b2f(u16 u) {
  union { float f; unsigned int i; } x; x.i = ((unsigned int)u) << 16; return x.f;
}
__device__ __forceinline__ u16 f2b(float f) {
  __bf16 h = (__bf16)f;
  return *(u16*)&h;
}
__device__ __forceinline__ unsigned pk2(float lo, float hi2) {
  __bf16 a = (__bf16)lo, b = (__bf16)hi2;
  unsigned short ua = *(unsigned short*)&a, ub = *(unsigned short*)&b;
  return (unsigned)ua | ((unsigned)ub << 16);
}

// ---------------- cast x: f32 -> bf16 ----------------
__global__ __launch_bounds__(256) void cast_f32_bf16(const float* __restrict__ in,
                                                     u16* __restrict__ out) {
  long i = ((long)blockIdx.x * 256 + threadIdx.x) * 8;
  float4 a = *(const float4*)(in + i);
  float4 b = *(const float4*)(in + i + 4);
  u16x8 r;
  r[0] = f2b(a.x); r[1] = f2b(a.y); r[2] = f2b(a.z); r[3] = f2b(a.w);
  r[4] = f2b(b.x); r[5] = f2b(b.y); r[6] = f2b(b.z); r[7] = f2b(b.w);
  *(u16x8*)(out + i) = r;
}

// ---------------- all 4 weight transposes in one launch: W[k][n] f32 -> Wt[n][k] bf16 ----------------
__global__ __launch_bounds__(256) void wtrans4_kernel(const float* __restrict__ W0,
                                                      const float* __restrict__ W1,
                                                      const float* __restrict__ W2,
                                                      const float* __restrict__ W3,
                                                      u16* __restrict__ WtBase) {
  __shared__ float tile[64][65];
  const int z = blockIdx.z;
  const float* W = (z == 0) ? W0 : (z == 1) ? W1 : (z == 2) ? W2 : W3;
  u16* Wt = WtBase + (long)z * 4194304;   // 2048*2048 elements per weight
  const int k0 = blockIdx.x * 64, n0 = blockIdx.y * 64;
  const int c = threadIdx.x & 63, r4 = threadIdx.x >> 6;
#pragma unroll
  for (int p = 0; p < 16; p++) {
    int r = p * 4 + r4;
    tile[r][c] = W[(long)(k0 + r) * DMODEL + n0 + c];
  }
  __syncthreads();
#pragma unroll
  for (int p = 0; p < 16; p++) {
    int r = p * 4 + r4;
    Wt[(long)(n0 + r) * DMODEL + k0 + c] = f2b(tile[c][r]);
  }
}

// ---------------- V transpose: Cqkv V-region [b*T+s][4096 + h*128+f] -> Vt[(bh*128+f)][s] ----------------
__global__ __launch_bounds__(256) void vtrans_kernel(const u16* __restrict__ C,
                                                     u16* __restrict__ Vt) {
  __shared__ u16 tile[64][66];
  const int s0 = blockIdx.x * 64, f0 = blockIdx.y * 64;
  const int bh = blockIdx.z;
  const int b = bh >> 4, h = bh & 15;
  const int c = threadIdx.x & 63, r4 = threadIdx.x >> 6;
#pragma unroll
  for (int p = 0; p < 16; p++) {
    int r = p * 4 + r4; // s-local
    tile[r][c] = C[(long)(b * T_SEQ + s0 + r) * QKV_STR + 4096 + h * DHEAD + f0 + c];
  }
  __syncthreads();
#pragma unroll
  for (int p = 0; p < 16; p++) {
    int r = p * 4 + r4; // f-local
    Vt[(long)(bh * DHEAD + f0 + r) * T_SEQ + s0 + c] = tile[c][r];
  }
}

// ---------------- RoPE in place on Cqkv cols 0..4095 (Q and K regions) ----------------
__global__ __launch_bounds__(256) void rope_qk_kernel(u16* __restrict__ X) {
  int idx = blockIdx.x * 256 + threadIdx.x;  // B*T*512 threads, 8 elems each
  int c8 = idx & 511;                        // chunk of 8 within the 4096 QK cols
  long row = idx >> 9;
  int t = (int)(row & (T_SEQ - 1));
  int i4 = c8 & 15;                          // chunk within the 128-wide head
  long off = row * QKV_STR + (long)c8 * 8;
  u16x8 v = *(u16x8*)(X + off);
  float o[8];
#pragma unroll
  for (int j = 0; j < 4; j++) {
    int i = i4 * 4 + j;                      // pair index 0..63
    float inv = __builtin_amdgcn_exp2f((float)i * -0.20762050593045857f);
    float ang = (float)t * inv;
    float cs = cosf(ang), sn = sinf(ang);
    float x0 = b2f(v[2 * j]), x1 = b2f(v[2 * j + 1]);
    o[2 * j]     = x0 * cs - x1 * sn;
    o[2 * j + 1] = x1 * cs + x0 * sn;
  }
  u16x8 r;
#pragma unroll
  for (int j = 0; j < 8; j++) r[j] = f2b(o[j]);
  *(u16x8*)(X + off) = r;
}

// ---------------- GEMM: C[M][N] = A[M][K] * Bt[N][K]^T (bf16 in, f32 acc) ----------------
// 256x256 8-phase template, BK=64, 512 thr = 8 waves (2M x 4N), per-wave 128x64 out.
// K-loop unrolled x2 so `par` is compile-time -> static LDS bases (kills addr VALU).
#define LOAD_A(q)                                                      \
  _Pragma("unroll") for (int k = 0; k < 2; k++)                        \
  _Pragma("unroll") for (int m = 0; m < 2; m++) {                      \
    int r = wr * 128 + (q) * 32 + m * 16 + lr;                         \
    int cc = (k * 4 + lc) ^ (r & 7);                                   \
    a[k][m] = *(const bf16x8*)&sA[par][r * 64 + cc * 8];               \
  }

#define LOAD_B()                                                       \
  _Pragma("unroll") for (int k = 0; k < 2; k++)                        \
  _Pragma("unroll") for (int n = 0; n < 4; n++) {                      \
    int r = wc * 64 + n * 16 + lr;                                     \
    int cc = (k * 4 + lc) ^ (r & 7);                                   \
    b[k][n] = *(const bf16x8*)&sB[par][r * 64 + cc * 8];               \
  }

#define MFMA_QUAD(q)                                                   \
  _Pragma("unroll") for (int k = 0; k < 2; k++)                        \
  _Pragma("unroll") for (int n = 0; n < 4; n++)                        \
  _Pragma("unroll") for (int m = 0; m < 2; m++)                        \
    acc[(q) * 2 + m][n] = __builtin_amdgcn_mfma_f32_16x16x32_bf16(     \
        a[k][m], b[k][n], acc[(q) * 2 + m][n], 0, 0, 0);

#define STAGE_HALF(g, ld, ldsp, rc0, t_, h_)                           \
  _Pragma("unroll") for (int j = 0; j < 2; j++) {                      \
    int rl = (h_) * 128 + wid * 16 + j * 8 + (lane >> 3);              \
    int cc = (lane & 7) ^ (lane >> 3);                                 \
    GLOAD((g) + ((rc0) + rl) * (long)(ld) + (long)(t_) * 64 + cc * 8,  \
          (ldsp) + (h_) * 128 * 64 + (wid * 16 + j * 8) * 64);         \
  }

template <int OUT_F32>
__global__ __launch_bounds__(512, 2) void gemm_bt(const u16* __restrict__ A, long lda,
                                                  const u16* __restrict__ Bt,
                                                  void* __restrict__ Cv,
                                                  int M, int N, int K) {
  __shared__ u16 sA[2][256 * 64];
  __shared__ u16 sB[2][256 * 64];
  const int tid = threadIdx.x, lane = tid & 63, wid = tid >> 6;
  const int wr = wid >> 2, wc = wid & 3;
  const int lr = lane & 15, lc = lane >> 4;
  const int id = blockIdx.x;
  // XCD strip mapping: xcd = id&7 owns col-tiles {xcd, xcd+8, ...}; bijective for N%2048==0
  const int per = (N >> 8) >> 3;             // col-tiles per XCD (1 for N=2048, 3 for 6144)
  const int g8 = id >> 3;
  const long col0 = (long)((id & 7) + 8 * (g8 % per)) * 256;
  const long row0 = (long)(g8 / per) * 256;
  const int NT = K >> 6;                     // NOTE: NT must be even (K%128==0) for unroll 2

  f32x4 acc[8][4] = {};
  bf16x8 a[2][2], b[2][4];

  STAGE_HALF(Bt, K, &sB[0][0], col0, 0, 0);
  STAGE_HALF(Bt, K, &sB[0][0], col0, 0, 1);
  STAGE_HALF(A, lda, &sA[0][0], row0, 0, 0);
  STAGE_HALF(A, lda, &sA[0][0], row0, 0, 1);
  STAGE_HALF(Bt, K, &sB[1][0], col0, 1, 0);
  STAGE_HALF(Bt, K, &sB[1][0], col0, 1, 1);
  VMCNT4();
  BAR();

#pragma unroll 2
  for (int t = 0; t < NT; t++) {
    const int par = t & 1;
    // ---- phase 0 ----
    LOAD_B();
    LOAD_A(0);
    if (t + 1 < NT) { STAGE_HALF(A, lda, &sA[par ^ 1][0], row0, t + 1, 0); }
    BAR(); LGKM0();
    __builtin_amdgcn_s_setprio(1); MFMA_QUAD(0); __builtin_amdgcn_s_setprio(0);
    BAR();
    // ---- phase 1 ----
    LOAD_A(1);
    if (t + 1 < NT) { STAGE_HALF(A, lda, &sA[par ^ 1][0], row0, t + 1, 1); }
    if (t + 2 < NT) { STAGE_HALF(Bt, K, &sB[par][0], col0, t + 2, 0); }
    BAR(); LGKM0();
    __builtin_amdgcn_s_setprio(1); MFMA_QUAD(1); __builtin_amdgcn_s_setprio(0);
    BAR();
    // ---- phase 2 ----
    LOAD_A(2);
    if (t + 2 < NT) { STAGE_HALF(Bt, K, &sB[par][0], col0, t + 2, 1); }
    BAR(); LGKM0();
    __builtin_amdgcn_s_setprio(1); MFMA_QUAD(2); __builtin_amdgcn_s_setprio(0);
    BAR();
    // ---- phase 3 ----
    LOAD_A(3);
    VMCNT4();
    BAR(); LGKM0();
    __builtin_amdgcn_s_setprio(1); MFMA_QUAD(3); __builtin_amdgcn_s_setprio(0);
    BAR();
  }

#pragma unroll
  for (int mf = 0; mf < 8; mf++)
#pragma unroll
    for (int n = 0; n < 4; n++)
#pragma unroll
      for (int i = 0; i < 4; i++) {
        long row = row0 + wr * 128 + mf * 16 + lc * 4 + i;
        long col = col0 + wc * 64 + n * 16 + lr;
        float v = acc[mf][n][i];
        if (OUT_F32) ((float*)Cv)[row * N + col] = v;
        else ((u16*)Cv)[row * N + col] = f2b(v);
      }
}

// ---------------- flash attention: swapped QK^T, 32x32 MFMA, P in-register ----------------
// Reads Q (col 0..2047) and K (col 2048..4095) from fused Cqkv (stride 6144); writes Y
// into the dead V region (col 4096..6143). Cross-half moves via __shfl_xor (proven r5).
__global__ __launch_bounds__(256, 2) void attn_kernel(const u16* __restrict__ QK,
                                                      const u16* __restrict__ Vt) {
  __shared__ u16 lK[2][64 * 128];   // K tile: 64 s-rows x 128 d (chunk-swizzled)
  __shared__ u16 lV[2][128 * 64];   // Vt tile: 128 d-rows x 64 s (chunk-swizzled)
  const int tid = threadIdx.x, lane = tid & 63, w = tid >> 6;
  const int hi = lane >> 5, l31 = lane & 31;
  const int id = blockIdx.x;
  const int qt = 15 - (id >> 6);    // longest blocks dispatched first
  const int bh = id & 63;
  const int b = bh >> 4, h = bh & 15;
  const int qg = qt * 128 + w * 32 + l31;   // this lane's q row (global)
  const int swz = l31 & 7;

  // Q fragments (B-operand): qf[kd][j] = Q[qg][kd*16 + hi*8 + j], prescaled
  bf16x8 qf[8];
  const long qrow = (long)(b * T_SEQ + qg) * QKV_STR + h * DHEAD;
#pragma unroll
  for (int kd = 0; kd < 8; kd++) {
    u16x8 raw = *(const u16x8*)(QK + qrow + kd * 16 + hi * 8);
    bf16x8 q;
#pragma unroll
    for (int j = 0; j < 8; j++) q[j] = (__bf16)(b2f(raw[j]) * QSCALE_LOG2E);
    qf[kd] = q;
  }

  f32x16 o0 = {}, o1 = {}, o2 = {}, o3 = {};  // O^T[d][q]: q lane-local
  float m_st = -INFINITY, l_st = 0.f;
  const int nt = (qt + 1) * 2;

#define STAGE(nb, kt_)                                                              \
  {                                                                                 \
    _Pragma("unroll")                                                               \
    for (int j = 0; j < 4; j++) {                                                   \
      int sb = (w * 4 + j) * 64;                                                    \
      int slot = sb + lane;                                                         \
      { int r = slot >> 4, pc = slot & 15, cc = pc ^ (r & 7);                       \
        GLOAD(QK + (long)(b * T_SEQ + (kt_) * 64 + r) * QKV_STR + 2048 +            \
                  h * DHEAD + cc * 8,                                               \
              &lK[nb][sb * 8]); }                                                   \
      { int r = slot >> 3, pc = slot & 7, cc = pc ^ (r & 7);                        \
        GLOAD(Vt + (long)(bh * DHEAD + r) * T_SEQ + (kt_) * 64 + cc * 8,            \
              &lV[nb][sb * 8]); }                                                   \
    }                                                                               \
  }

  STAGE(0, 0);
  __syncthreads();

  for (int kt = 0; kt < nt; kt++) {
    const int cur = kt & 1;
    if (kt + 1 < nt) STAGE(cur ^ 1, kt + 1);

    // S^T = mfma(K, Q): st0 = s 0..31, st1 = s 32..63; lane: q=l31, s=crow(r,hi)
    f32x16 st0 = {}, st1 = {};
    __builtin_amdgcn_s_setprio(1);
#pragma unroll
    for (int kd = 0; kd < 8; kd++) {
      int pc = (kd * 2 + hi) ^ swz;
      bf16x8 kf0 = *(const bf16x8*)&lK[cur][l31 * 128 + pc * 8];
      bf16x8 kf1 = *(const bf16x8*)&lK[cur][(32 + l31) * 128 + pc * 8];
      st0 = MFMA32(kf0, qf[kd], st0);
      st1 = MFMA32(kf1, qf[kd], st1);
    }
    __builtin_amdgcn_s_setprio(0);

    // causal mask (diagonal region only)
    if (kt * 64 + 63 > qt * 128 + w * 32) {
#pragma unroll
      for (int r = 0; r < 16; r++) {
        int sl = kt * 64 + (r & 3) + 8 * (r >> 2) + 4 * hi;
        if (sl > qg) st0[r] = -1e30f;
        if (sl + 32 > qg) st1[r] = -1e30f;
      }
    }

    // online softmax, exp2 domain, in-lane + one cross-half shfl reduce
    float mx = -1e30f;
#pragma unroll
    for (int r = 0; r < 16; r++) mx = fmaxf(mx, fmaxf(st0[r], st1[r]));
    mx = fmaxf(mx, __shfl_xor(mx, 32, 64));
    if (__any(mx > m_st + 8.0f)) {     // defer-max
      float mnew = fmaxf(m_st, mx);
      float corr = __builtin_amdgcn_exp2f(m_st - mnew);
      m_st = mnew;
      l_st *= corr;
#pragma unroll
      for (int r = 0; r < 16; r++) {
        o0[r] *= corr; o1[r] *= corr; o2[r] *= corr; o3[r] *= corr;
      }
    }
    float rs = 0.f;
#pragma unroll
    for (int r = 0; r < 16; r++) {
      st0[r] = __builtin_amdgcn_exp2f(st0[r] - m_st); rs += st0[r];
      st1[r] = __builtin_amdgcn_exp2f(st1[r] - m_st); rs += st1[r];
    }
    l_st += rs + __shfl_xor(rs, 32, 64);

    // P -> bf16 PV B-frags via shfl_xor + select (proven r5); O^T += mfma(Vt, P)
    __builtin_amdgcn_s_setprio(1);
#define PVHALF(stX, sb)                                                        \
    _Pragma("unroll")                                                          \
    for (int g = 0; g < 2; g++) {                                              \
      unsigned A0 = pk2(stX[8 * g + 0], stX[8 * g + 1]);                       \
      unsigned A1 = pk2(stX[8 * g + 2], stX[8 * g + 3]);                       \
      unsigned B0 = pk2(stX[8 * g + 4], stX[8 * g + 5]);                       \
      unsigned B1 = pk2(stX[8 * g + 6], stX[8 * g + 7]);                       \
      unsigned xA0 = __shfl_xor(A0, 32, 64);                                   \
      unsigned xA1 = __shfl_xor(A1, 32, 64);                                   \
      unsigned xB0 = __shfl_xor(B0, 32, 64);                                   \
      unsigned xB1 = __shfl_xor(B1, 32, 64);                                   \
      u32x4 pw;                                                                \
      pw[0] = hi ? xB0 : A0;                                                   \
      pw[1] = hi ? xB1 : A1;                                                   \
      pw[2] = hi ? B0 : xA0;                                                   \
      pw[3] = hi ? B1 : xA1;                                                   \
      bf16x8 pa = *(bf16x8*)&pw;                                               \
      const int ks = (sb) * 2 + g;                                             \
      int pc0 = (ks * 2 + hi) ^ swz;                                           \
      bf16x8 vb0 = *(const bf16x8*)&lV[cur][(l31) * 64 + pc0 * 8];             \
      o0 = MFMA32(vb0, pa, o0);                                                \
      bf16x8 vb1 = *(const bf16x8*)&lV[cur][(32 + l31) * 64 + pc0 * 8];        \
      o1 = MFMA32(vb1, pa, o1);                                                \
      bf16x8 vb2 = *(const bf16x8*)&lV[cur][(64 + l31) * 64 + pc0 * 8];        \
      o2 = MFMA32(vb2, pa, o2);                                                \
      bf16x8 vb3 = *(const bf16x8*)&lV[cur][(96 + l31) * 64 + pc0 * 8];        \
      o3 = MFMA32(vb3, pa, o3);                                                \
    }
    PVHALF(st0, 0)
    PVHALF(st1, 1)
#undef PVHALF
    __builtin_amdgcn_s_setprio(0);

    __syncthreads();
  }

  // epilogue: O^T *= 1/l, packed 8B stores into the Y (dead V) region
  float inv = __builtin_amdgcn_rcpf(l_st);
#define WR(oN, n)                                                              \
  _Pragma("unroll")                                                            \
  for (int rq = 0; rq < 4; rq++) {                                             \
    u16x4 pk;                                                                  \
    _Pragma("unroll")                                                          \
    for (int j = 0; j < 4; j++) pk[j] = f2b(oN[rq * 4 + j] * inv);             \
    *(u16x4*)((u16*)QK + qrow + 4096 + (n) * 32 + rq * 8 + hi * 4) = pk;       \
  }
  WR(o0, 0) WR(o1, 1) WR(o2, 2) WR(o3, 3)
#undef WR
#undef STAGE
}

extern "C" void kernel_launch(void* const* d_in, const int* in_sizes, int n_in,
                              void* d_out, int out_size, void* d_ws, size_t ws_size,
                              hipStream_t stream) {
  const float* x  = (const float*)d_in[0];
  const float* Wq = (const float*)d_in[1];
  const float* Wk = (const float*)d_in[2];
  const float* Wv = (const float*)d_in[3];
  const float* Wo = (const float*)d_in[4];
  float* out = (float*)d_out;
  char* ws = (char*)d_ws;

  const long MB = 1048576L;
  // layout: xb 32MB (aliased by Vt later); Wqt/Wkt/Wvt contiguous 24MB fused Bt;
  // Wot 8MB; Cqkv 96MB = [8192][6144] (Q | K | V-then-Y). Total 160MB.
  u16* xb   = (u16*)(ws);
  u16* Wt4  = (u16*)(ws + 32 * MB);   // Wqt | Wkt | Wvt | Wot contiguous
  u16* Cqkv = (u16*)(ws + 64 * MB);
  u16* Vtb  = xb;   // alias: xb dead after QKV projection

  cast_f32_bf16<<<8192, 256, 0, stream>>>(x, xb);
  dim3 wt_g(32, 32, 4);
  wtrans4_kernel<<<wt_g, 256, 0, stream>>>(Wq, Wk, Wv, Wo, Wt4);

  // fused QKV projection: C[8192][6144] = xb @ [Wq|Wk|Wv]^T
  gemm_bt<0><<<768, 512, 0, stream>>>(xb, 2048, Wt4, Cqkv, 8192, 6144, 2048);

  rope_qk_kernel<<<16384, 256, 0, stream>>>(Cqkv);

  dim3 vt_g(32, 2, 64);
  vtrans_kernel<<<vt_g, 256, 0, stream>>>(Cqkv, Vtb);

  attn_kernel<<<1024, 256, 0, stream>>>(Cqkv, Vtb);

  // output projection: reads Y from the V region (lda = 6144); Wot at Wt4 + 3*8MB
  gemm_bt<1><<<256, 512, 0, stream>>>(Cqkv + 4096, QKV_STR, Wt4 + 3 * 4194304L,
                                      (void*)out, 8192, 2048, 2048);
}

// Round 10
// 432.958 us; speedup vs baseline: 2.7165x; 1.0270x over previous
//
#include <hip/hip_runtime.h>
#include <hip/hip_bf16.h>
#include <math.h>

typedef unsigned short u16;
typedef __attribute__((ext_vector_type(8))) __bf16 bf16x8;
typedef __attribute__((ext_vector_type(4))) float f32x4;
typedef __attribute__((ext_vector_type(16))) float f32x16;
typedef __attribute__((ext_vector_type(8))) u16 u16x8;
typedef __attribute__((ext_vector_type(4))) u16 u16x4;
typedef __attribute__((ext_vector_type(4))) unsigned u32x4;

#define T_SEQ 2048
#define DMODEL 2048
#define NH 16
#define DHEAD 128
#define BATCH 4
#define QKV_STR 6144            // fused QKV row stride (Q | K | V concatenated)
#define ATTN_SCALE 0.08838834764831845f
#define QSCALE_LOG2E 0.1275411278534803f   // ATTN_SCALE * log2(e)

#define GLOAD(gp, lp) __builtin_amdgcn_global_load_lds( \
    (const __attribute__((address_space(1))) void*)(gp), \
    (__attribute__((address_space(3))) void*)(lp), 16, 0, 0)

#define BAR() __builtin_amdgcn_s_barrier()
#define VMCNT4() asm volatile("s_waitcnt vmcnt(4)" ::: "memory")
#define MFMA32(A, B, C) __builtin_amdgcn_mfma_f32_32x32x16_bf16(A, B, C, 0, 0, 0)

__device__ __forceinline__ float b2f(u16 u) {
  union { float f; unsigned int i; } x; x.i = ((unsigned int)u) << 16; return x.f;
}
__device__ __forceinline__ u16 f2b(float f) {
  __bf16 h = (__bf16)f;
  return *(u16*)&h;
}
__device__ __forceinline__ unsigned pk2(float lo, float hi2) {
  __bf16 a = (__bf16)lo, b = (__bf16)hi2;
  unsigned short ua = *(unsigned short*)&a, ub = *(unsigned short*)&b;
  return (unsigned)ua | ((unsigned)ub << 16);
}

// ---------------- cast x: f32 -> bf16 ----------------
__global__ __launch_bounds__(256) void cast_f32_bf16(const float* __restrict__ in,
                                                     u16* __restrict__ out) {
  long i = ((long)blockIdx.x * 256 + threadIdx.x) * 8;
  float4 a = *(const float4*)(in + i);
  float4 b = *(const float4*)(in + i + 4);
  u16x8 r;
  r[0] = f2b(a.x); r[1] = f2b(a.y); r[2] = f2b(a.z); r[3] = f2b(a.w);
  r[4] = f2b(b.x); r[5] = f2b(b.y); r[6] = f2b(b.z); r[7] = f2b(b.w);
  *(u16x8*)(out + i) = r;
}

// ---------------- all 4 weight transposes in one launch: W[k][n] f32 -> Wt[n][k] bf16 ----------------
__global__ __launch_bounds__(256) void wtrans4_kernel(const float* __restrict__ W0,
                                                      const float* __restrict__ W1,
                                                      const float* __restrict__ W2,
                                                      const float* __restrict__ W3,
                                                      u16* __restrict__ WtBase) {
  __shared__ float tile[64][65];
  const int z = blockIdx.z;
  const float* W = (z == 0) ? W0 : (z == 1) ? W1 : (z == 2) ? W2 : W3;
  u16* Wt = WtBase + (long)z * 4194304;   // 2048*2048 elements per weight
  const int k0 = blockIdx.x * 64, n0 = blockIdx.y * 64;
  const int c = threadIdx.x & 63, r4 = threadIdx.x >> 6;
#pragma unroll
  for (int p = 0; p < 16; p++) {
    int r = p * 4 + r4;
    tile[r][c] = W[(long)(k0 + r) * DMODEL + n0 + c];
  }
  __syncthreads();
#pragma unroll
  for (int p = 0; p < 16; p++) {
    int r = p * 4 + r4;
    Wt[(long)(n0 + r) * DMODEL + k0 + c] = f2b(tile[c][r]);
  }
}

// ---------------- V transpose: Cqkv V-region [b*T+s][4096 + h*128+f] -> Vt[(bh*128+f)][s] ----------------
__global__ __launch_bounds__(256) void vtrans_kernel(const u16* __restrict__ C,
                                                     u16* __restrict__ Vt) {
  __shared__ u16 tile[64][66];
  const int s0 = blockIdx.x * 64, f0 = blockIdx.y * 64;
  const int bh = blockIdx.z;
  const int b = bh >> 4, h = bh & 15;
  const int c = threadIdx.x & 63, r4 = threadIdx.x >> 6;
#pragma unroll
  for (int p = 0; p < 16; p++) {
    int r = p * 4 + r4; // s-local
    tile[r][c] = C[(long)(b * T_SEQ + s0 + r) * QKV_STR + 4096 + h * DHEAD + f0 + c];
  }
  __syncthreads();
#pragma unroll
  for (int p = 0; p < 16; p++) {
    int r = p * 4 + r4; // f-local
    Vt[(long)(bh * DHEAD + f0 + r) * T_SEQ + s0 + c] = tile[c][r];
  }
}

// ---------------- GEMM: C[M][N] = A[M][K] * Bt[N][K]^T (bf16 in, f32 acc) ----------------
// 256x256 8-phase template, BK=64, 512 thr = 8 waves (2M x 4N), per-wave 128x64 out.
// NO explicit lgkmcnt(0) before MFMA: compiler emits counted lgkm waits, so each MFMA
// starts when its own operands land and tail ds_reads drain UNDER the cluster. Every
// ds_read's consumer is in-phase, so all reads drain before each wave's end-of-phase
// barrier -> staging into the just-read region next phase stays safe.
// ROPE=1: fuse RoPE into the epilogue for cols < 4096 (pair partner = lane lr^1).
#define LOAD_A(q)                                                      \
  _Pragma("unroll") for (int k = 0; k < 2; k++)                        \
  _Pragma("unroll") for (int m = 0; m < 2; m++) {                      \
    int r = wr * 128 + (q) * 32 + m * 16 + lr;                         \
    int cc = (k * 4 + lc) ^ (r & 7);                                   \
    a[k][m] = *(const bf16x8*)&sA[par][r * 64 + cc * 8];               \
  }

#define LOAD_B()                                                       \
  _Pragma("unroll") for (int k = 0; k < 2; k++)                        \
  _Pragma("unroll") for (int n = 0; n < 4; n++) {                      \
    int r = wc * 64 + n * 16 + lr;                                     \
    int cc = (k * 4 + lc) ^ (r & 7);                                   \
    b[k][n] = *(const bf16x8*)&sB[par][r * 64 + cc * 8];               \
  }

#define MFMA_QUAD(q)                                                   \
  _Pragma("unroll") for (int k = 0; k < 2; k++)                        \
  _Pragma("unroll") for (int n = 0; n < 4; n++)                        \
  _Pragma("unroll") for (int m = 0; m < 2; m++)                        \
    acc[(q) * 2 + m][n] = __builtin_amdgcn_mfma_f32_16x16x32_bf16(     \
        a[k][m], b[k][n], acc[(q) * 2 + m][n], 0, 0, 0);

#define STAGE_HALF(g, ld, ldsp, rc0, t_, h_)                           \
  _Pragma("unroll") for (int j = 0; j < 2; j++) {                      \
    int rl = (h_) * 128 + wid * 16 + j * 8 + (lane >> 3);              \
    int cc = (lane & 7) ^ (lane >> 3);                                 \
    GLOAD((g) + ((rc0) + rl) * (long)(ld) + (long)(t_) * 64 + cc * 8,  \
          (ldsp) + (h_) * 128 * 64 + (wid * 16 + j * 8) * 64);         \
  }

template <int OUT_F32, int ROPE>
__global__ __launch_bounds__(512, 2) void gemm_bt(const u16* __restrict__ A, long lda,
                                                  const u16* __restrict__ Bt,
                                                  void* __restrict__ Cv,
                                                  int M, int N, int K) {
  __shared__ u16 sA[2][256 * 64];
  __shared__ u16 sB[2][256 * 64];
  const int tid = threadIdx.x, lane = tid & 63, wid = tid >> 6;
  const int wr = wid >> 2, wc = wid & 3;
  const int lr = lane & 15, lc = lane >> 4;
  const int id = blockIdx.x;
  // XCD strip mapping: xcd = id&7 owns col-tiles {xcd, xcd+8, ...}; bijective for N%2048==0
  const int per = (N >> 8) >> 3;             // col-tiles per XCD (1 for N=2048, 3 for 6144)
  const int g8 = id >> 3;
  const long col0 = (long)((id & 7) + 8 * (g8 % per)) * 256;
  const long row0 = (long)(g8 / per) * 256;
  const int NT = K >> 6;                     // NT must be even (K%128==0) for unroll 2

  f32x4 acc[8][4] = {};
  bf16x8 a[2][2], b[2][4];

  STAGE_HALF(Bt, K, &sB[0][0], col0, 0, 0);
  STAGE_HALF(Bt, K, &sB[0][0], col0, 0, 1);
  STAGE_HALF(A, lda, &sA[0][0], row0, 0, 0);
  STAGE_HALF(A, lda, &sA[0][0], row0, 0, 1);
  STAGE_HALF(Bt, K, &sB[1][0], col0, 1, 0);
  STAGE_HALF(Bt, K, &sB[1][0], col0, 1, 1);
  VMCNT4();
  BAR();

#pragma unroll 2
  for (int t = 0; t < NT; t++) {
    const int par = t & 1;
    // ---- phase 0 ----
    LOAD_B();
    LOAD_A(0);
    if (t + 1 < NT) { STAGE_HALF(A, lda, &sA[par ^ 1][0], row0, t + 1, 0); }
    BAR();
    __builtin_amdgcn_s_setprio(1); MFMA_QUAD(0); __builtin_amdgcn_s_setprio(0);
    BAR();
    // ---- phase 1 ----
    LOAD_A(1);
    if (t + 1 < NT) { STAGE_HALF(A, lda, &sA[par ^ 1][0], row0, t + 1, 1); }
    if (t + 2 < NT) { STAGE_HALF(Bt, K, &sB[par][0], col0, t + 2, 0); }
    BAR();
    __builtin_amdgcn_s_setprio(1); MFMA_QUAD(1); __builtin_amdgcn_s_setprio(0);
    BAR();
    // ---- phase 2 ----
    LOAD_A(2);
    if (t + 2 < NT) { STAGE_HALF(Bt, K, &sB[par][0], col0, t + 2, 1); }
    BAR();
    __builtin_amdgcn_s_setprio(1); MFMA_QUAD(2); __builtin_amdgcn_s_setprio(0);
    BAR();
    // ---- phase 3 ----
    LOAD_A(3);
    VMCNT4();
    BAR();
    __builtin_amdgcn_s_setprio(1); MFMA_QUAD(3); __builtin_amdgcn_s_setprio(0);
    BAR();
  }

  const bool doRope = ROPE && (col0 < 4096);
#pragma unroll
  for (int mf = 0; mf < 8; mf++)
#pragma unroll
    for (int n = 0; n < 4; n++)
#pragma unroll
      for (int i = 0; i < 4; i++) {
        long row = row0 + wr * 128 + mf * 16 + lc * 4 + i;
        long col = col0 + wc * 64 + n * 16 + lr;
        float v = acc[mf][n][i];
        if (doRope) {
          float other = __shfl_xor(v, 1, 64);   // pair partner: col^1 lives in lane lr^1
          int tt = (int)(row & (T_SEQ - 1));
          int pi = ((int)col & 127) >> 1;       // pair index within the head
          float ang = (float)tt *
                      __builtin_amdgcn_exp2f((float)pi * -0.20762050593045857f);
          float cs = __cosf(ang), sn = __sinf(ang);
          v = (lr & 1) ? (v * cs + other * sn) : (v * cs - other * sn);
        }
        if (OUT_F32) ((float*)Cv)[row * N + col] = v;
        else ((u16*)Cv)[row * N + col] = f2b(v);
      }
}

// ---------------- flash attention: swapped QK^T, 32x32 MFMA, P in-register ----------------
// Reads Q (col 0..2047) and K (col 2048..4095) from fused Cqkv (stride 6144); writes Y
// into the dead V region (col 4096..6143). Cross-half moves via __shfl_xor (proven r5).
__global__ __launch_bounds__(256, 2) void attn_kernel(const u16* __restrict__ QK,
                                                      const u16* __restrict__ Vt) {
  __shared__ u16 lK[2][64 * 128];   // K tile: 64 s-rows x 128 d (chunk-swizzled)
  __shared__ u16 lV[2][128 * 64];   // Vt tile: 128 d-rows x 64 s (chunk-swizzled)
  const int tid = threadIdx.x, lane = tid & 63, w = tid >> 6;
  const int hi = lane >> 5, l31 = lane & 31;
  const int id = blockIdx.x;
  const int qt = 15 - (id >> 6);    // longest blocks dispatched first
  const int bh = id & 63;
  const int b = bh >> 4, h = bh & 15;
  const int qg = qt * 128 + w * 32 + l31;   // this lane's q row (global)
  const int swz = l31 & 7;

  // Q fragments (B-operand): qf[kd][j] = Q[qg][kd*16 + hi*8 + j], prescaled
  bf16x8 qf[8];
  const long qrow = (long)(b * T_SEQ + qg) * QKV_STR + h * DHEAD;
#pragma unroll
  for (int kd = 0; kd < 8; kd++) {
    u16x8 raw = *(const u16x8*)(QK + qrow + kd * 16 + hi * 8);
    bf16x8 q;
#pragma unroll
    for (int j = 0; j < 8; j++) q[j] = (__bf16)(b2f(raw[j]) * QSCALE_LOG2E);
    qf[kd] = q;
  }

  f32x16 o0 = {}, o1 = {}, o2 = {}, o3 = {};  // O^T[d][q]: q lane-local
  float m_st = -INFINITY, l_st = 0.f;
  const int nt = (qt + 1) * 2;

#define STAGE(nb, kt_)                                                              \
  {                                                                                 \
    _Pragma("unroll")                                                               \
    for (int j = 0; j < 4; j++) {                                                   \
      int sb = (w * 4 + j) * 64;                                                    \
      int slot = sb + lane;                                                         \
      { int r = slot >> 4, pc = slot & 15, cc = pc ^ (r & 7);                       \
        GLOAD(QK + (long)(b * T_SEQ + (kt_) * 64 + r) * QKV_STR + 2048 +            \
                  h * DHEAD + cc * 8,                                               \
              &lK[nb][sb * 8]); }                                                   \
      { int r = slot >> 3, pc = slot & 7, cc = pc ^ (r & 7);                        \
        GLOAD(Vt + (long)(bh * DHEAD + r) * T_SEQ + (kt_) * 64 + cc * 8,            \
              &lV[nb][sb * 8]); }                                                   \
    }                                                                               \
  }

  STAGE(0, 0);
  __syncthreads();

  for (int kt = 0; kt < nt; kt++) {
    const int cur = kt & 1;
    if (kt + 1 < nt) STAGE(cur ^ 1, kt + 1);

    // S^T = mfma(K, Q): st0 = s 0..31, st1 = s 32..63; lane: q=l31, s=crow(r,hi)
    f32x16 st0 = {}, st1 = {};
    __builtin_amdgcn_s_setprio(1);
#pragma unroll
    for (int kd = 0; kd < 8; kd++) {
      int pc = (kd * 2 + hi) ^ swz;
      bf16x8 kf0 = *(const bf16x8*)&lK[cur][l31 * 128 + pc * 8];
      bf16x8 kf1 = *(const bf16x8*)&lK[cur][(32 + l31) * 128 + pc * 8];
      st0 = MFMA32(kf0, qf[kd], st0);
      st1 = MFMA32(kf1, qf[kd], st1);
    }
    __builtin_amdgcn_s_setprio(0);

    // causal mask (diagonal region only)
    if (kt * 64 + 63 > qt * 128 + w * 32) {
#pragma unroll
      for (int r = 0; r < 16; r++) {
        int sl = kt * 64 + (r & 3) + 8 * (r >> 2) + 4 * hi;
        if (sl > qg) st0[r] = -1e30f;
        if (sl + 32 > qg) st1[r] = -1e30f;
      }
    }

    // online softmax, exp2 domain, in-lane + one cross-half shfl reduce
    float mx = -1e30f;
#pragma unroll
    for (int r = 0; r < 16; r++) mx = fmaxf(mx, fmaxf(st0[r], st1[r]));
    mx = fmaxf(mx, __shfl_xor(mx, 32, 64));
    if (__any(mx > m_st + 8.0f)) {     // defer-max
      float mnew = fmaxf(m_st, mx);
      float corr = __builtin_amdgcn_exp2f(m_st - mnew);
      m_st = mnew;
      l_st *= corr;
#pragma unroll
      for (int r = 0; r < 16; r++) {
        o0[r] *= corr; o1[r] *= corr; o2[r] *= corr; o3[r] *= corr;
      }
    }
    float rs = 0.f;
#pragma unroll
    for (int r = 0; r < 16; r++) {
      st0[r] = __builtin_amdgcn_exp2f(st0[r] - m_st); rs += st0[r];
      st1[r] = __builtin_amdgcn_exp2f(st1[r] - m_st); rs += st1[r];
    }
    l_st += rs + __shfl_xor(rs, 32, 64);

    // P -> bf16 PV B-frags via shfl_xor + select (proven r5); O^T += mfma(Vt, P)
    __builtin_amdgcn_s_setprio(1);
#define PVHALF(stX, sb)                                                        \
    _Pragma("unroll")                                                          \
    for (int g = 0; g < 2; g++) {                                              \
      unsigned A0 = pk2(stX[8 * g + 0], stX[8 * g + 1]);                       \
      unsigned A1 = pk2(stX[8 * g + 2], stX[8 * g + 3]);                       \
      unsigned B0 = pk2(stX[8 * g + 4], stX[8 * g + 5]);                       \
      unsigned B1 = pk2(stX[8 * g + 6], stX[8 * g + 7]);                       \
      unsigned xA0 = __shfl_xor(A0, 32, 64);                                   \
      unsigned xA1 = __shfl_xor(A1, 32, 64);                                   \
      unsigned xB0 = __shfl_xor(B0, 32, 64);                                   \
      unsigned xB1 = __shfl_xor(B1, 32, 64);                                   \
      u32x4 pw;                                                                \
      pw[0] = hi ? xB0 : A0;                                                   \
      pw[1] = hi ? xB1 : A1;                                                   \
      pw[2] = hi ? B0 : xA0;                                                   \
      pw[3] = hi ? B1 : xA1;                                                   \
      bf16x8 pa = *(bf16x8*)&pw;                                               \
      const int ks = (sb) * 2 + g;                                             \
      int pc0 = (ks * 2 + hi) ^ swz;                                           \
      bf16x8 vb0 = *(const bf16x8*)&lV[cur][(l31) * 64 + pc0 * 8];             \
      o0 = MFMA32(vb0, pa, o0);                                                \
      bf16x8 vb1 = *(const bf16x8*)&lV[cur][(32 + l31) * 64 + pc0 * 8];        \
      o1 = MFMA32(vb1, pa, o1);                                                \
      bf16x8 vb2 = *(const bf16x8*)&lV[cur][(64 + l31) * 64 + pc0 * 8];        \
      o2 = MFMA32(vb2, pa, o2);                                                \
      bf16x8 vb3 = *(const bf16x8*)&lV[cur][(96 + l31) * 64 + pc0 * 8];        \
      o3 = MFMA32(vb3, pa, o3);                                                \
    }
    PVHALF(st0, 0)
    PVHALF(st1, 1)
#undef PVHALF
    __builtin_amdgcn_s_setprio(0);

    __syncthreads();
  }

  // epilogue: O^T *= 1/l, packed 8B stores into the Y (dead V) region
  float inv = __builtin_amdgcn_rcpf(l_st);
#define WR(oN, n)                                                              \
  _Pragma("unroll")                                                            \
  for (int rq = 0; rq < 4; rq++) {                                             \
    u16x4 pk;                                                                  \
    _Pragma("unroll")                                                          \
    for (int j = 0; j < 4; j++) pk[j] = f2b(oN[rq * 4 + j] * inv);             \
    *(u16x4*)((u16*)QK + qrow + 4096 + (n) * 32 + rq * 8 + hi * 4) = pk;       \
  }
  WR(o0, 0) WR(o1, 1) WR(o2, 2) WR(o3, 3)
#undef WR
#undef STAGE
}

extern "C" void kernel_launch(void* const* d_in, const int* in_sizes, int n_in,
                              void* d_out, int out_size, void* d_ws, size_t ws_size,
                              hipStream_t stream) {
  const float* x  = (const float*)d_in[0];
  const float* Wq = (const float*)d_in[1];
  const float* Wk = (const float*)d_in[2];
  const float* Wv = (const float*)d_in[3];
  const float* Wo = (const float*)d_in[4];
  float* out = (float*)d_out;
  char* ws = (char*)d_ws;

  const long MB = 1048576L;
  // layout: xb 32MB (aliased by Vt later); Wt4 32MB (Wqt|Wkt|Wvt|Wot contiguous);
  // Cqkv 96MB = [8192][6144] (Q | K | V-then-Y). Total 160MB.
  u16* xb   = (u16*)(ws);
  u16* Wt4  = (u16*)(ws + 32 * MB);
  u16* Cqkv = (u16*)(ws + 64 * MB);
  u16* Vtb  = xb;   // alias: xb dead after QKV projection

  cast_f32_bf16<<<8192, 256, 0, stream>>>(x, xb);
  dim3 wt_g(32, 32, 4);
  wtrans4_kernel<<<wt_g, 256, 0, stream>>>(Wq, Wk, Wv, Wo, Wt4);

  // fused QKV projection + RoPE-in-epilogue: C[8192][6144] = rope(xb @ [Wq|Wk|Wv]^T)
  gemm_bt<0, 1><<<768, 512, 0, stream>>>(xb, 2048, Wt4, Cqkv, 8192, 6144, 2048);

  dim3 vt_g(32, 2, 64);
  vtrans_kernel<<<vt_g, 256, 0, stream>>>(Cqkv, Vtb);

  attn_kernel<<<1024, 256, 0, stream>>>(Cqkv, Vtb);

  // output projection: reads Y from the V region (lda = 6144); Wot at Wt4 + 3*4M elems
  gemm_bt<1, 0><<<256, 512, 0, stream>>>(Cqkv + 4096, QKV_STR, Wt4 + 3 * 4194304L,
                                         (void*)out, 8192, 2048, 2048);
}

// Round 11
// 423.420 us; speedup vs baseline: 2.7777x; 1.0225x over previous
//
#include <hip/hip_runtime.h>
#include <hip/hip_bf16.h>
#include <math.h>

typedef unsigned short u16;
typedef __attribute__((ext_vector_type(8))) __bf16 bf16x8;
typedef __attribute__((ext_vector_type(4))) float f32x4;
typedef __attribute__((ext_vector_type(16))) float f32x16;
typedef __attribute__((ext_vector_type(8))) u16 u16x8;
typedef __attribute__((ext_vector_type(4))) u16 u16x4;
typedef __attribute__((ext_vector_type(4))) unsigned u32x4;

#define T_SEQ 2048
#define DMODEL 2048
#define NH 16
#define DHEAD 128
#define BATCH 4
#define QKV_STR 6144            // fused QKV row stride (Q | K | V concatenated)
#define ATTN_SCALE 0.08838834764831845f
#define QSCALE_LOG2E 0.1275411278534803f   // ATTN_SCALE * log2(e)
#define ROPE_EXP_C  -0.20762050593045857f  // -log2(10000)/64

#define GLOAD(gp, lp) __builtin_amdgcn_global_load_lds( \
    (const __attribute__((address_space(1))) void*)(gp), \
    (__attribute__((address_space(3))) void*)(lp), 16, 0, 0)

#define BAR() __builtin_amdgcn_s_barrier()
#define VMCNT4() asm volatile("s_waitcnt vmcnt(4)" ::: "memory")
#define MFMA32(A, B, C) __builtin_amdgcn_mfma_f32_32x32x16_bf16(A, B, C, 0, 0, 0)

__device__ __forceinline__ float b2f(u16 u) {
  union { float f; unsigned int i; } x; x.i = ((unsigned int)u) << 16; return x.f;
}
__device__ __forceinline__ u16 f2b(float f) {
  __bf16 h = (__bf16)f;
  return *(u16*)&h;
}
__device__ __forceinline__ unsigned pk2(float lo, float hi2) {
  __bf16 a = (__bf16)lo, b = (__bf16)hi2;
  unsigned short ua = *(unsigned short*)&a, ub = *(unsigned short*)&b;
  return (unsigned)ua | ((unsigned)ub << 16);
}

// ---------------- cast x: f32 -> bf16 ----------------
__global__ __launch_bounds__(256) void cast_f32_bf16(const float* __restrict__ in,
                                                     u16* __restrict__ out) {
  long i = ((long)blockIdx.x * 256 + threadIdx.x) * 8;
  float4 a = *(const float4*)(in + i);
  float4 b = *(const float4*)(in + i + 4);
  u16x8 r;
  r[0] = f2b(a.x); r[1] = f2b(a.y); r[2] = f2b(a.z); r[3] = f2b(a.w);
  r[4] = f2b(b.x); r[5] = f2b(b.y); r[6] = f2b(b.z); r[7] = f2b(b.w);
  *(u16x8*)(out + i) = r;
}

// ---------------- all 4 weight transposes in one launch: W[k][n] f32 -> Wt[n][k] bf16 ----------------
__global__ __launch_bounds__(256) void wtrans4_kernel(const float* __restrict__ W0,
                                                      const float* __restrict__ W1,
                                                      const float* __restrict__ W2,
                                                      const float* __restrict__ W3,
                                                      u16* __restrict__ WtBase) {
  __shared__ float tile[64][65];
  const int z = blockIdx.z;
  const float* W = (z == 0) ? W0 : (z == 1) ? W1 : (z == 2) ? W2 : W3;
  u16* Wt = WtBase + (long)z * 4194304;   // 2048*2048 elements per weight
  const int k0 = blockIdx.x * 64, n0 = blockIdx.y * 64;
  const int c = threadIdx.x & 63, r4 = threadIdx.x >> 6;
#pragma unroll
  for (int p = 0; p < 16; p++) {
    int r = p * 4 + r4;
    tile[r][c] = W[(long)(k0 + r) * DMODEL + n0 + c];
  }
  __syncthreads();
#pragma unroll
  for (int p = 0; p < 16; p++) {
    int r = p * 4 + r4;
    Wt[(long)(n0 + r) * DMODEL + k0 + c] = f2b(tile[c][r]);
  }
}

// ---------------- V transpose: Cqkv V-region [b*T+s][4096 + h*128+f] -> Vt[(bh*128+f)][s] ----------------
__global__ __launch_bounds__(256) void vtrans_kernel(const u16* __restrict__ C,
                                                     u16* __restrict__ Vt) {
  __shared__ u16 tile[64][66];
  const int s0 = blockIdx.x * 64, f0 = blockIdx.y * 64;
  const int bh = blockIdx.z;
  const int b = bh >> 4, h = bh & 15;
  const int c = threadIdx.x & 63, r4 = threadIdx.x >> 6;
#pragma unroll
  for (int p = 0; p < 16; p++) {
    int r = p * 4 + r4; // s-local
    tile[r][c] = C[(long)(b * T_SEQ + s0 + r) * QKV_STR + 4096 + h * DHEAD + f0 + c];
  }
  __syncthreads();
#pragma unroll
  for (int p = 0; p < 16; p++) {
    int r = p * 4 + r4; // f-local
    Vt[(long)(bh * DHEAD + f0 + r) * T_SEQ + s0 + c] = tile[c][r];
  }
}

// ---------------- GEMM: C[M][N] = A[M][K] * Bt[N][K]^T (bf16 in, f32 acc) ----------------
// 256x256 8-phase template, BK=64, 512 thr = 8 waves (2M x 4N), per-wave 128x64 out.
// ROPE=1: fuse RoPE into the epilogue for K columns ONLY (2048 <= col < 4096).
// Q is written RAW: attn applies RoPE on its Q-load (in-register pairs, one-time).
#define LOAD_A(q)                                                      \
  _Pragma("unroll") for (int k = 0; k < 2; k++)                        \
  _Pragma("unroll") for (int m = 0; m < 2; m++) {                      \
    int r = wr * 128 + (q) * 32 + m * 16 + lr;                         \
    int cc = (k * 4 + lc) ^ (r & 7);                                   \
    a[k][m] = *(const bf16x8*)&sA[par][r * 64 + cc * 8];               \
  }

#define LOAD_B()                                                       \
  _Pragma("unroll") for (int k = 0; k < 2; k++)                        \
  _Pragma("unroll") for (int n = 0; n < 4; n++) {                      \
    int r = wc * 64 + n * 16 + lr;                                     \
    int cc = (k * 4 + lc) ^ (r & 7);                                   \
    b[k][n] = *(const bf16x8*)&sB[par][r * 64 + cc * 8];               \
  }

#define MFMA_QUAD(q)                                                   \
  _Pragma("unroll") for (int k = 0; k < 2; k++)                        \
  _Pragma("unroll") for (int n = 0; n < 4; n++)                        \
  _Pragma("unroll") for (int m = 0; m < 2; m++)                        \
    acc[(q) * 2 + m][n] = __builtin_amdgcn_mfma_f32_16x16x32_bf16(     \
        a[k][m], b[k][n], acc[(q) * 2 + m][n], 0, 0, 0);

#define STAGE_HALF(g, ld, ldsp, rc0, t_, h_)                           \
  _Pragma("unroll") for (int j = 0; j < 2; j++) {                      \
    int rl = (h_) * 128 + wid * 16 + j * 8 + (lane >> 3);              \
    int cc = (lane & 7) ^ (lane >> 3);                                 \
    GLOAD((g) + ((rc0) + rl) * (long)(ld) + (long)(t_) * 64 + cc * 8,  \
          (ldsp) + (h_) * 128 * 64 + (wid * 16 + j * 8) * 64);         \
  }

template <int OUT_F32, int ROPE>
__global__ __launch_bounds__(512, 2) void gemm_bt(const u16* __restrict__ A, long lda,
                                                  const u16* __restrict__ Bt,
                                                  void* __restrict__ Cv,
                                                  int M, int N, int K) {
  __shared__ u16 sA[2][256 * 64];
  __shared__ u16 sB[2][256 * 64];
  const int tid = threadIdx.x, lane = tid & 63, wid = tid >> 6;
  const int wr = wid >> 2, wc = wid & 3;
  const int lr = lane & 15, lc = lane >> 4;
  const int id = blockIdx.x;
  // XCD strip mapping: xcd = id&7 owns col-tiles {xcd, xcd+8, ...}; bijective for N%2048==0
  const int per = (N >> 8) >> 3;             // col-tiles per XCD (1 for N=2048, 3 for 6144)
  const int g8 = id >> 3;
  const long col0 = (long)((id & 7) + 8 * (g8 % per)) * 256;
  const long row0 = (long)(g8 / per) * 256;
  const int NT = K >> 6;                     // NT must be even (K%128==0) for unroll 2

  f32x4 acc[8][4] = {};
  bf16x8 a[2][2], b[2][4];

  STAGE_HALF(Bt, K, &sB[0][0], col0, 0, 0);
  STAGE_HALF(Bt, K, &sB[0][0], col0, 0, 1);
  STAGE_HALF(A, lda, &sA[0][0], row0, 0, 0);
  STAGE_HALF(A, lda, &sA[0][0], row0, 0, 1);
  STAGE_HALF(Bt, K, &sB[1][0], col0, 1, 0);
  STAGE_HALF(Bt, K, &sB[1][0], col0, 1, 1);
  VMCNT4();
  BAR();

#pragma unroll 2
  for (int t = 0; t < NT; t++) {
    const int par = t & 1;
    // ---- phase 0 ----
    LOAD_B();
    LOAD_A(0);
    if (t + 1 < NT) { STAGE_HALF(A, lda, &sA[par ^ 1][0], row0, t + 1, 0); }
    BAR();
    __builtin_amdgcn_s_setprio(1); MFMA_QUAD(0); __builtin_amdgcn_s_setprio(0);
    BAR();
    // ---- phase 1 ----
    LOAD_A(1);
    if (t + 1 < NT) { STAGE_HALF(A, lda, &sA[par ^ 1][0], row0, t + 1, 1); }
    if (t + 2 < NT) { STAGE_HALF(Bt, K, &sB[par][0], col0, t + 2, 0); }
    BAR();
    __builtin_amdgcn_s_setprio(1); MFMA_QUAD(1); __builtin_amdgcn_s_setprio(0);
    BAR();
    // ---- phase 2 ----
    LOAD_A(2);
    if (t + 2 < NT) { STAGE_HALF(Bt, K, &sB[par][0], col0, t + 2, 1); }
    BAR();
    __builtin_amdgcn_s_setprio(1); MFMA_QUAD(2); __builtin_amdgcn_s_setprio(0);
    BAR();
    // ---- phase 3 ----
    LOAD_A(3);
    VMCNT4();
    BAR();
    __builtin_amdgcn_s_setprio(1); MFMA_QUAD(3); __builtin_amdgcn_s_setprio(0);
    BAR();
  }

  // RoPE only for K columns; Q stays raw (attn ropes Q at load, in-register)
  const bool doRope = ROPE && (col0 >= 2048) && (col0 < 4096);
#pragma unroll
  for (int mf = 0; mf < 8; mf++)
#pragma unroll
    for (int n = 0; n < 4; n++)
#pragma unroll
      for (int i = 0; i < 4; i++) {
        long row = row0 + wr * 128 + mf * 16 + lc * 4 + i;
        long col = col0 + wc * 64 + n * 16 + lr;
        float v = acc[mf][n][i];
        if (doRope) {
          float other = __shfl_xor(v, 1, 64);   // pair partner: col^1 lives in lane lr^1
          int tt = (int)(row & (T_SEQ - 1));
          int pi = ((int)col & 127) >> 1;       // pair index within the head
          float ang = (float)tt * __builtin_amdgcn_exp2f((float)pi * ROPE_EXP_C);
          float cs = __cosf(ang), sn = __sinf(ang);
          v = (lr & 1) ? (v * cs + other * sn) : (v * cs - other * sn);
        }
        if (OUT_F32) ((float*)Cv)[row * N + col] = v;
        else ((u16*)Cv)[row * N + col] = f2b(v);
      }
}

// ---------------- flash attention: swapped QK^T, 32x32 MFMA, P in-register ----------------
// Reads RAW Q (col 0..2047) and roped K (col 2048..4095) from fused Cqkv (stride 6144);
// applies RoPE to Q at load (pairs are register-internal); writes Y into the dead V
// region (col 4096..6143). PV exchange uses 2 shfls/group (pre-selected send values).
__global__ __launch_bounds__(256, 2) void attn_kernel(const u16* __restrict__ QK,
                                                      const u16* __restrict__ Vt) {
  __shared__ u16 lK[2][64 * 128];   // K tile: 64 s-rows x 128 d (chunk-swizzled)
  __shared__ u16 lV[2][128 * 64];   // Vt tile: 128 d-rows x 64 s (chunk-swizzled)
  const int tid = threadIdx.x, lane = tid & 63, w = tid >> 6;
  const int hi = lane >> 5, l31 = lane & 31;
  const int id = blockIdx.x;
  const int qt = 15 - (id >> 6);    // longest blocks dispatched first
  const int bh = id & 63;
  const int b = bh >> 4, h = bh & 15;
  const int qg = qt * 128 + w * 32 + l31;   // this lane's q row (global)
  const int swz = l31 & 7;

  // Q fragments (B-operand): qf[kd][j] = rope(Q[qg])[kd*16 + hi*8 + j] * scale
  // d = kd*16 + hi*8 + 2*jj (+1): even/odd pair within the register -> no cross-lane
  bf16x8 qf[8];
  const long qrow = (long)(b * T_SEQ + qg) * QKV_STR + h * DHEAD;
#pragma unroll
  for (int kd = 0; kd < 8; kd++) {
    u16x8 raw = *(const u16x8*)(QK + qrow + kd * 16 + hi * 8);
    bf16x8 q;
#pragma unroll
    for (int jj = 0; jj < 4; jj++) {
      int pi = kd * 8 + hi * 4 + jj;          // pair index 0..63
      float ang = (float)qg * __builtin_amdgcn_exp2f((float)pi * ROPE_EXP_C);
      float cs = __cosf(ang), sn = __sinf(ang);
      float x0 = b2f(raw[2 * jj]), x1 = b2f(raw[2 * jj + 1]);
      q[2 * jj]     = (__bf16)((x0 * cs - x1 * sn) * QSCALE_LOG2E);
      q[2 * jj + 1] = (__bf16)((x1 * cs + x0 * sn) * QSCALE_LOG2E);
    }
    qf[kd] = q;
  }

  f32x16 o0 = {}, o1 = {}, o2 = {}, o3 = {};  // O^T[d][q]: q lane-local
  float m_st = -INFINITY, l_st = 0.f;
  const int nt = (qt + 1) * 2;

#define STAGE(nb, kt_)                                                              \
  {                                                                                 \
    _Pragma("unroll")                                                               \
    for (int j = 0; j < 4; j++) {                                                   \
      int sb = (w * 4 + j) * 64;                                                    \
      int slot = sb + lane;                                                         \
      { int r = slot >> 4, pc = slot & 15, cc = pc ^ (r & 7);                       \
        GLOAD(QK + (long)(b * T_SEQ + (kt_) * 64 + r) * QKV_STR + 2048 +            \
                  h * DHEAD + cc * 8,                                               \
              &lK[nb][sb * 8]); }                                                   \
      { int r = slot >> 3, pc = slot & 7, cc = pc ^ (r & 7);                        \
        GLOAD(Vt + (long)(bh * DHEAD + r) * T_SEQ + (kt_) * 64 + cc * 8,            \
              &lV[nb][sb * 8]); }                                                   \
    }                                                                               \
  }

  STAGE(0, 0);
  __syncthreads();

  for (int kt = 0; kt < nt; kt++) {
    const int cur = kt & 1;
    if (kt + 1 < nt) STAGE(cur ^ 1, kt + 1);

    // S^T = mfma(K, Q): st0 = s 0..31, st1 = s 32..63; lane: q=l31, s=crow(r,hi)
    f32x16 st0 = {}, st1 = {};
    __builtin_amdgcn_s_setprio(1);
#pragma unroll
    for (int kd = 0; kd < 8; kd++) {
      int pc = (kd * 2 + hi) ^ swz;
      bf16x8 kf0 = *(const bf16x8*)&lK[cur][l31 * 128 + pc * 8];
      bf16x8 kf1 = *(const bf16x8*)&lK[cur][(32 + l31) * 128 + pc * 8];
      st0 = MFMA32(kf0, qf[kd], st0);
      st1 = MFMA32(kf1, qf[kd], st1);
    }
    __builtin_amdgcn_s_setprio(0);

    // causal mask (diagonal region only)
    if (kt * 64 + 63 > qt * 128 + w * 32) {
#pragma unroll
      for (int r = 0; r < 16; r++) {
        int sl = kt * 64 + (r & 3) + 8 * (r >> 2) + 4 * hi;
        if (sl > qg) st0[r] = -1e30f;
        if (sl + 32 > qg) st1[r] = -1e30f;
      }
    }

    // online softmax, exp2 domain, in-lane + one cross-half shfl reduce
    float mx = -1e30f;
#pragma unroll
    for (int r = 0; r < 16; r++) mx = fmaxf(mx, fmaxf(st0[r], st1[r]));
    mx = fmaxf(mx, __shfl_xor(mx, 32, 64));
    if (__any(mx > m_st + 8.0f)) {     // defer-max
      float mnew = fmaxf(m_st, mx);
      float corr = __builtin_amdgcn_exp2f(m_st - mnew);
      m_st = mnew;
      l_st *= corr;
#pragma unroll
      for (int r = 0; r < 16; r++) {
        o0[r] *= corr; o1[r] *= corr; o2[r] *= corr; o3[r] *= corr;
      }
    }
    float rs = 0.f;
#pragma unroll
    for (int r = 0; r < 16; r++) {
      st0[r] = __builtin_amdgcn_exp2f(st0[r] - m_st); rs += st0[r];
      st1[r] = __builtin_amdgcn_exp2f(st1[r] - m_st); rs += st1[r];
    }
    l_st += rs + __shfl_xor(rs, 32, 64);

    // P -> bf16 PV B-frags: 2 shfls/group (send hi?A:B, each side receives exactly
    // what it needs: hi=0 gets partner.A (=xA), hi=1 gets partner.B (=xB)).
    __builtin_amdgcn_s_setprio(1);
#define PVHALF(stX, sb)                                                        \
    _Pragma("unroll")                                                          \
    for (int g = 0; g < 2; g++) {                                              \
      unsigned A0 = pk2(stX[8 * g + 0], stX[8 * g + 1]);                       \
      unsigned A1 = pk2(stX[8 * g + 2], stX[8 * g + 3]);                       \
      unsigned B0 = pk2(stX[8 * g + 4], stX[8 * g + 5]);                       \
      unsigned B1 = pk2(stX[8 * g + 6], stX[8 * g + 7]);                       \
      unsigned r0 = __shfl_xor(hi ? A0 : B0, 32, 64);                          \
      unsigned r1 = __shfl_xor(hi ? A1 : B1, 32, 64);                          \
      u32x4 pw;                                                                \
      pw[0] = hi ? r0 : A0;                                                    \
      pw[1] = hi ? r1 : A1;                                                    \
      pw[2] = hi ? B0 : r0;                                                    \
      pw[3] = hi ? B1 : r1;                                                    \
      bf16x8 pa = *(bf16x8*)&pw;                                               \
      const int ks = (sb) * 2 + g;                                             \
      int pc0 = (ks * 2 + hi) ^ swz;                                           \
      bf16x8 vb0 = *(const bf16x8*)&lV[cur][(l31) * 64 + pc0 * 8];             \
      o0 = MFMA32(vb0, pa, o0);                                                \
      bf16x8 vb1 = *(const bf16x8*)&lV[cur][(32 + l31) * 64 + pc0 * 8];        \
      o1 = MFMA32(vb1, pa, o1);                                                \
      bf16x8 vb2 = *(const bf16x8*)&lV[cur][(64 + l31) * 64 + pc0 * 8];        \
      o2 = MFMA32(vb2, pa, o2);                                                \
      bf16x8 vb3 = *(const bf16x8*)&lV[cur][(96 + l31) * 64 + pc0 * 8];        \
      o3 = MFMA32(vb3, pa, o3);                                                \
    }
    PVHALF(st0, 0)
    PVHALF(st1, 1)
#undef PVHALF
    __builtin_amdgcn_s_setprio(0);

    __syncthreads();
  }

  // epilogue: O^T *= 1/l, packed 8B stores into the Y (dead V) region
  float inv = __builtin_amdgcn_rcpf(l_st);
#define WR(oN, n)                                                              \
  _Pragma("unroll")                                                            \
  for (int rq = 0; rq < 4; rq++) {                                             \
    u16x4 pk;                                                                  \
    _Pragma("unroll")                                                          \
    for (int j = 0; j < 4; j++) pk[j] = f2b(oN[rq * 4 + j] * inv);             \
    *(u16x4*)((u16*)QK + qrow + 4096 + (n) * 32 + rq * 8 + hi * 4) = pk;       \
  }
  WR(o0, 0) WR(o1, 1) WR(o2, 2) WR(o3, 3)
#undef WR
#undef STAGE
}

extern "C" void kernel_launch(void* const* d_in, const int* in_sizes, int n_in,
                              void* d_out, int out_size, void* d_ws, size_t ws_size,
                              hipStream_t stream) {
  const float* x  = (const float*)d_in[0];
  const float* Wq = (const float*)d_in[1];
  const float* Wk = (const float*)d_in[2];
  const float* Wv = (const float*)d_in[3];
  const float* Wo = (const float*)d_in[4];
  float* out = (float*)d_out;
  char* ws = (char*)d_ws;

  const long MB = 1048576L;
  // layout: xb 32MB (aliased by Vt later); Wt4 32MB (Wqt|Wkt|Wvt|Wot contiguous);
  // Cqkv 96MB = [8192][6144] (Q-raw | K-roped | V-then-Y). Total 160MB.
  u16* xb   = (u16*)(ws);
  u16* Wt4  = (u16*)(ws + 32 * MB);
  u16* Cqkv = (u16*)(ws + 64 * MB);
  u16* Vtb  = xb;   // alias: xb dead after QKV projection

  cast_f32_bf16<<<8192, 256, 0, stream>>>(x, xb);
  dim3 wt_g(32, 32, 4);
  wtrans4_kernel<<<wt_g, 256, 0, stream>>>(Wq, Wk, Wv, Wo, Wt4);

  // fused QKV projection; RoPE fused into epilogue for K cols only
  gemm_bt<0, 1><<<768, 512, 0, stream>>>(xb, 2048, Wt4, Cqkv, 8192, 6144, 2048);

  dim3 vt_g(32, 2, 64);
  vtrans_kernel<<<vt_g, 256, 0, stream>>>(Cqkv, Vtb);

  attn_kernel<<<1024, 256, 0, stream>>>(Cqkv, Vtb);

  // output projection: reads Y from the V region (lda = 6144); Wot at Wt4 + 3*4M elems
  gemm_bt<1, 0><<<256, 512, 0, stream>>>(Cqkv + 4096, QKV_STR, Wt4 + 3 * 4194304L,
                                         (void*)out, 8192, 2048, 2048);
}

// Round 12
// 422.417 us; speedup vs baseline: 2.7843x; 1.0024x over previous
//
#include <hip/hip_runtime.h>
#include <hip/hip_bf16.h>
#include <math.h>

typedef unsigned short u16;
typedef __attribute__((ext_vector_type(8))) __bf16 bf16x8;
typedef __attribute__((ext_vector_type(4))) float f32x4;
typedef __attribute__((ext_vector_type(16))) float f32x16;
typedef __attribute__((ext_vector_type(8))) u16 u16x8;
typedef __attribute__((ext_vector_type(4))) u16 u16x4;
typedef __attribute__((ext_vector_type(4))) unsigned u32x4;

#define T_SEQ 2048
#define DMODEL 2048
#define NH 16
#define DHEAD 128
#define BATCH 4
#define QKV_STR 6144            // fused QKV row stride (Q | K | V concatenated)
#define ATTN_SCALE 0.08838834764831845f
#define QSCALE_LOG2E 0.1275411278534803f   // ATTN_SCALE * log2(e)
#define ROPE_EXP_C  -0.20762050593045857f  // -log2(10000)/64

#define GLOAD(gp, lp) __builtin_amdgcn_global_load_lds( \
    (const __attribute__((address_space(1))) void*)(gp), \
    (__attribute__((address_space(3))) void*)(lp), 16, 0, 0)

#define BAR() __builtin_amdgcn_s_barrier()
#define VMCNT4() asm volatile("s_waitcnt vmcnt(4)" ::: "memory")
#define MFMA32(A, B, C) __builtin_amdgcn_mfma_f32_32x32x16_bf16(A, B, C, 0, 0, 0)

__device__ __forceinline__ float b2f(u16 u) {
  union { float f; unsigned int i; } x; x.i = ((unsigned int)u) << 16; return x.f;
}
__device__ __forceinline__ u16 f2b(float f) {
  __bf16 h = (__bf16)f;
  return *(u16*)&h;
}
__device__ __forceinline__ unsigned pk2(float lo, float hi2) {
  __bf16 a = (__bf16)lo, b = (__bf16)hi2;
  unsigned short ua = *(unsigned short*)&a, ub = *(unsigned short*)&b;
  return (unsigned)ua | ((unsigned)ub << 16);
}

// ---------------- cast x: f32 -> bf16 ----------------
__global__ __launch_bounds__(256) void cast_f32_bf16(const float* __restrict__ in,
                                                     u16* __restrict__ out) {
  long i = ((long)blockIdx.x * 256 + threadIdx.x) * 8;
  float4 a = *(const float4*)(in + i);
  float4 b = *(const float4*)(in + i + 4);
  u16x8 r;
  r[0] = f2b(a.x); r[1] = f2b(a.y); r[2] = f2b(a.z); r[3] = f2b(a.w);
  r[4] = f2b(b.x); r[5] = f2b(b.y); r[6] = f2b(b.z); r[7] = f2b(b.w);
  *(u16x8*)(out + i) = r;
}

// ---------------- all 4 weight transposes in one launch: W[k][n] f32 -> Wt[n][k] bf16 ----------------
__global__ __launch_bounds__(256) void wtrans4_kernel(const float* __restrict__ W0,
                                                      const float* __restrict__ W1,
                                                      const float* __restrict__ W2,
                                                      const float* __restrict__ W3,
                                                      u16* __restrict__ WtBase) {
  __shared__ float tile[64][65];
  const int z = blockIdx.z;
  const float* W = (z == 0) ? W0 : (z == 1) ? W1 : (z == 2) ? W2 : W3;
  u16* Wt = WtBase + (long)z * 4194304;   // 2048*2048 elements per weight
  const int k0 = blockIdx.x * 64, n0 = blockIdx.y * 64;
  const int c = threadIdx.x & 63, r4 = threadIdx.x >> 6;
#pragma unroll
  for (int p = 0; p < 16; p++) {
    int r = p * 4 + r4;
    tile[r][c] = W[(long)(k0 + r) * DMODEL + n0 + c];
  }
  __syncthreads();
#pragma unroll
  for (int p = 0; p < 16; p++) {
    int r = p * 4 + r4;
    Wt[(long)(n0 + r) * DMODEL + k0 + c] = f2b(tile[c][r]);
  }
}

// ---------------- V transpose: Cqkv V-region [b*T+s][4096 + h*128+f] -> Vt[(bh*128+f)][s] ----------------
__global__ __launch_bounds__(256) void vtrans_kernel(const u16* __restrict__ C,
                                                     u16* __restrict__ Vt) {
  __shared__ u16 tile[64][66];
  const int s0 = blockIdx.x * 64, f0 = blockIdx.y * 64;
  const int bh = blockIdx.z;
  const int b = bh >> 4, h = bh & 15;
  const int c = threadIdx.x & 63, r4 = threadIdx.x >> 6;
#pragma unroll
  for (int p = 0; p < 16; p++) {
    int r = p * 4 + r4; // s-local
    tile[r][c] = C[(long)(b * T_SEQ + s0 + r) * QKV_STR + 4096 + h * DHEAD + f0 + c];
  }
  __syncthreads();
#pragma unroll
  for (int p = 0; p < 16; p++) {
    int r = p * 4 + r4; // f-local
    Vt[(long)(bh * DHEAD + f0 + r) * T_SEQ + s0 + c] = tile[c][r];
  }
}

// ---------------- standalone RoPE on the K region only (cols 2048..4095) ----------------
// Memory-bound: 64MB r+w. Q is roped in attn at register-load; fusing rope into the
// GEMM epilogue measured as a net LOSS (r10/r11: +15us fusion tax vs 10us standalone).
__global__ __launch_bounds__(256) void rope_k_kernel(u16* __restrict__ X) {
  int idx = blockIdx.x * 256 + threadIdx.x;  // B*T*256 threads, 8 elems each
  int c8 = idx & 255;                        // chunk of 8 within the 2048 K cols
  long row = idx >> 8;
  int t = (int)(row & (T_SEQ - 1));
  int i4 = c8 & 15;                          // chunk within the 128-wide head
  long off = row * QKV_STR + 2048 + (long)c8 * 8;
  u16x8 v = *(u16x8*)(X + off);
  float o[8];
#pragma unroll
  for (int j = 0; j < 4; j++) {
    int i = i4 * 4 + j;                      // pair index 0..63
    float inv = __builtin_amdgcn_exp2f((float)i * ROPE_EXP_C);
    float ang = (float)t * inv;
    float cs = __cosf(ang), sn = __sinf(ang);
    float x0 = b2f(v[2 * j]), x1 = b2f(v[2 * j + 1]);
    o[2 * j]     = x0 * cs - x1 * sn;
    o[2 * j + 1] = x1 * cs + x0 * sn;
  }
  u16x8 r;
#pragma unroll
  for (int j = 0; j < 8; j++) r[j] = f2b(o[j]);
  *(u16x8*)(X + off) = r;
}

// ---------------- GEMM: C[M][N] = A[M][K] * Bt[N][K]^T (bf16 in, f32 acc) ----------------
// 256x256 8-phase template, BK=64, 512 thr = 8 waves (2M x 4N), per-wave 128x64 out.
// Clean epilogue (no fused rope — measured net loss). This config measured 207us /
// MfmaUtil 42 on the N=6144 QKV shape (r8).
#define LOAD_A(q)                                                      \
  _Pragma("unroll") for (int k = 0; k < 2; k++)                        \
  _Pragma("unroll") for (int m = 0; m < 2; m++) {                      \
    int r = wr * 128 + (q) * 32 + m * 16 + lr;                         \
    int cc = (k * 4 + lc) ^ (r & 7);                                   \
    a[k][m] = *(const bf16x8*)&sA[par][r * 64 + cc * 8];               \
  }

#define LOAD_B()                                                       \
  _Pragma("unroll") for (int k = 0; k < 2; k++)                        \
  _Pragma("unroll") for (int n = 0; n < 4; n++) {                      \
    int r = wc * 64 + n * 16 + lr;                                     \
    int cc = (k * 4 + lc) ^ (r & 7);                                   \
    b[k][n] = *(const bf16x8*)&sB[par][r * 64 + cc * 8];               \
  }

#define MFMA_QUAD(q)                                                   \
  _Pragma("unroll") for (int k = 0; k < 2; k++)                        \
  _Pragma("unroll") for (int n = 0; n < 4; n++)                        \
  _Pragma("unroll") for (int m = 0; m < 2; m++)                        \
    acc[(q) * 2 + m][n] = __builtin_amdgcn_mfma_f32_16x16x32_bf16(     \
        a[k][m], b[k][n], acc[(q) * 2 + m][n], 0, 0, 0);

#define STAGE_HALF(g, ld, ldsp, rc0, t_, h_)                           \
  _Pragma("unroll") for (int j = 0; j < 2; j++) {                      \
    int rl = (h_) * 128 + wid * 16 + j * 8 + (lane >> 3);              \
    int cc = (lane & 7) ^ (lane >> 3);                                 \
    GLOAD((g) + ((rc0) + rl) * (long)(ld) + (long)(t_) * 64 + cc * 8,  \
          (ldsp) + (h_) * 128 * 64 + (wid * 16 + j * 8) * 64);         \
  }

template <int OUT_F32>
__global__ __launch_bounds__(512, 2) void gemm_bt(const u16* __restrict__ A, long lda,
                                                  const u16* __restrict__ Bt,
                                                  void* __restrict__ Cv,
                                                  int M, int N, int K) {
  __shared__ u16 sA[2][256 * 64];
  __shared__ u16 sB[2][256 * 64];
  const int tid = threadIdx.x, lane = tid & 63, wid = tid >> 6;
  const int wr = wid >> 2, wc = wid & 3;
  const int lr = lane & 15, lc = lane >> 4;
  const int id = blockIdx.x;
  // XCD strip mapping: xcd = id&7 owns col-tiles {xcd, xcd+8, ...}; bijective for N%2048==0
  const int per = (N >> 8) >> 3;             // col-tiles per XCD (1 for N=2048, 3 for 6144)
  const int g8 = id >> 3;
  const long col0 = (long)((id & 7) + 8 * (g8 % per)) * 256;
  const long row0 = (long)(g8 / per) * 256;
  const int NT = K >> 6;                     // NT must be even (K%128==0) for unroll 2

  f32x4 acc[8][4] = {};
  bf16x8 a[2][2], b[2][4];

  STAGE_HALF(Bt, K, &sB[0][0], col0, 0, 0);
  STAGE_HALF(Bt, K, &sB[0][0], col0, 0, 1);
  STAGE_HALF(A, lda, &sA[0][0], row0, 0, 0);
  STAGE_HALF(A, lda, &sA[0][0], row0, 0, 1);
  STAGE_HALF(Bt, K, &sB[1][0], col0, 1, 0);
  STAGE_HALF(Bt, K, &sB[1][0], col0, 1, 1);
  VMCNT4();
  BAR();

#pragma unroll 2
  for (int t = 0; t < NT; t++) {
    const int par = t & 1;
    // ---- phase 0 ----
    LOAD_B();
    LOAD_A(0);
    if (t + 1 < NT) { STAGE_HALF(A, lda, &sA[par ^ 1][0], row0, t + 1, 0); }
    BAR();
    __builtin_amdgcn_s_setprio(1); MFMA_QUAD(0); __builtin_amdgcn_s_setprio(0);
    BAR();
    // ---- phase 1 ----
    LOAD_A(1);
    if (t + 1 < NT) { STAGE_HALF(A, lda, &sA[par ^ 1][0], row0, t + 1, 1); }
    if (t + 2 < NT) { STAGE_HALF(Bt, K, &sB[par][0], col0, t + 2, 0); }
    BAR();
    __builtin_amdgcn_s_setprio(1); MFMA_QUAD(1); __builtin_amdgcn_s_setprio(0);
    BAR();
    // ---- phase 2 ----
    LOAD_A(2);
    if (t + 2 < NT) { STAGE_HALF(Bt, K, &sB[par][0], col0, t + 2, 1); }
    BAR();
    __builtin_amdgcn_s_setprio(1); MFMA_QUAD(2); __builtin_amdgcn_s_setprio(0);
    BAR();
    // ---- phase 3 ----
    LOAD_A(3);
    VMCNT4();
    BAR();
    __builtin_amdgcn_s_setprio(1); MFMA_QUAD(3); __builtin_amdgcn_s_setprio(0);
    BAR();
  }

#pragma unroll
  for (int mf = 0; mf < 8; mf++)
#pragma unroll
    for (int n = 0; n < 4; n++)
#pragma unroll
      for (int i = 0; i < 4; i++) {
        long row = row0 + wr * 128 + mf * 16 + lc * 4 + i;
        long col = col0 + wc * 64 + n * 16 + lr;
        float v = acc[mf][n][i];
        if (OUT_F32) ((float*)Cv)[row * N + col] = v;
        else ((u16*)Cv)[row * N + col] = f2b(v);
      }
}

// ---------------- flash attention: swapped QK^T, 32x32 MFMA, P in-register ----------------
// Reads RAW Q (col 0..2047) and roped K (col 2048..4095) from fused Cqkv (stride 6144);
// applies RoPE to Q at load (pairs are register-internal); writes Y into the dead V
// region (col 4096..6143). PV exchange uses 2 shfls/group (pre-selected send values).
__global__ __launch_bounds__(256, 2) void attn_kernel(const u16* __restrict__ QK,
                                                      const u16* __restrict__ Vt) {
  __shared__ u16 lK[2][64 * 128];   // K tile: 64 s-rows x 128 d (chunk-swizzled)
  __shared__ u16 lV[2][128 * 64];   // Vt tile: 128 d-rows x 64 s (chunk-swizzled)
  const int tid = threadIdx.x, lane = tid & 63, w = tid >> 6;
  const int hi = lane >> 5, l31 = lane & 31;
  const int id = blockIdx.x;
  const int qt = 15 - (id >> 6);    // longest blocks dispatched first
  const int bh = id & 63;
  const int b = bh >> 4, h = bh & 15;
  const int qg = qt * 128 + w * 32 + l31;   // this lane's q row (global)
  const int swz = l31 & 7;

  // Q fragments (B-operand): qf[kd][j] = rope(Q[qg])[kd*16 + hi*8 + j] * scale
  // d = kd*16 + hi*8 + 2*jj (+1): even/odd pair within the register -> no cross-lane
  bf16x8 qf[8];
  const long qrow = (long)(b * T_SEQ + qg) * QKV_STR + h * DHEAD;
#pragma unroll
  for (int kd = 0; kd < 8; kd++) {
    u16x8 raw = *(const u16x8*)(QK + qrow + kd * 16 + hi * 8);
    bf16x8 q;
#pragma unroll
    for (int jj = 0; jj < 4; jj++) {
      int pi = kd * 8 + hi * 4 + jj;          // pair index 0..63
      float ang = (float)qg * __builtin_amdgcn_exp2f((float)pi * ROPE_EXP_C);
      float cs = __cosf(ang), sn = __sinf(ang);
      float x0 = b2f(raw[2 * jj]), x1 = b2f(raw[2 * jj + 1]);
      q[2 * jj]     = (__bf16)((x0 * cs - x1 * sn) * QSCALE_LOG2E);
      q[2 * jj + 1] = (__bf16)((x1 * cs + x0 * sn) * QSCALE_LOG2E);
    }
    qf[kd] = q;
  }

  f32x16 o0 = {}, o1 = {}, o2 = {}, o3 = {};  // O^T[d][q]: q lane-local
  float m_st = -INFINITY, l_st = 0.f;
  const int nt = (qt + 1) * 2;

#define STAGE(nb, kt_)                                                              \
  {                                                                                 \
    _Pragma("unroll")                                                               \
    for (int j = 0; j < 4; j++) {                                                   \
      int sb = (w * 4 + j) * 64;                                                    \
      int slot = sb + lane;                                                         \
      { int r = slot >> 4, pc = slot & 15, cc = pc ^ (r & 7);                       \
        GLOAD(QK + (long)(b * T_SEQ + (kt_) * 64 + r) * QKV_STR + 2048 +            \
                  h * DHEAD + cc * 8,                                               \
              &lK[nb][sb * 8]); }                                                   \
      { int r = slot >> 3, pc = slot & 7, cc = pc ^ (r & 7);                        \
        GLOAD(Vt + (long)(bh * DHEAD + r) * T_SEQ + (kt_) * 64 + cc * 8,            \
              &lV[nb][sb * 8]); }                                                   \
    }                                                                               \
  }

  STAGE(0, 0);
  __syncthreads();

  for (int kt = 0; kt < nt; kt++) {
    const int cur = kt & 1;
    if (kt + 1 < nt) STAGE(cur ^ 1, kt + 1);

    // S^T = mfma(K, Q): st0 = s 0..31, st1 = s 32..63; lane: q=l31, s=crow(r,hi)
    f32x16 st0 = {}, st1 = {};
    __builtin_amdgcn_s_setprio(1);
#pragma unroll
    for (int kd = 0; kd < 8; kd++) {
      int pc = (kd * 2 + hi) ^ swz;
      bf16x8 kf0 = *(const bf16x8*)&lK[cur][l31 * 128 + pc * 8];
      bf16x8 kf1 = *(const bf16x8*)&lK[cur][(32 + l31) * 128 + pc * 8];
      st0 = MFMA32(kf0, qf[kd], st0);
      st1 = MFMA32(kf1, qf[kd], st1);
    }
    __builtin_amdgcn_s_setprio(0);

    // causal mask (diagonal region only)
    if (kt * 64 + 63 > qt * 128 + w * 32) {
#pragma unroll
      for (int r = 0; r < 16; r++) {
        int sl = kt * 64 + (r & 3) + 8 * (r >> 2) + 4 * hi;
        if (sl > qg) st0[r] = -1e30f;
        if (sl + 32 > qg) st1[r] = -1e30f;
      }
    }

    // online softmax, exp2 domain, in-lane + one cross-half shfl reduce
    float mx = -1e30f;
#pragma unroll
    for (int r = 0; r < 16; r++) mx = fmaxf(mx, fmaxf(st0[r], st1[r]));
    mx = fmaxf(mx, __shfl_xor(mx, 32, 64));
    if (__any(mx > m_st + 8.0f)) {     // defer-max
      float mnew = fmaxf(m_st, mx);
      float corr = __builtin_amdgcn_exp2f(m_st - mnew);
      m_st = mnew;
      l_st *= corr;
#pragma unroll
      for (int r = 0; r < 16; r++) {
        o0[r] *= corr; o1[r] *= corr; o2[r] *= corr; o3[r] *= corr;
      }
    }
    float rs = 0.f;
#pragma unroll
    for (int r = 0; r < 16; r++) {
      st0[r] = __builtin_amdgcn_exp2f(st0[r] - m_st); rs += st0[r];
      st1[r] = __builtin_amdgcn_exp2f(st1[r] - m_st); rs += st1[r];
    }
    l_st += rs + __shfl_xor(rs, 32, 64);

    // P -> bf16 PV B-frags: 2 shfls/group (send hi?A:B, each side receives exactly
    // what it needs: hi=0 gets partner.A (=xA), hi=1 gets partner.B (=xB)).
    __builtin_amdgcn_s_setprio(1);
#define PVHALF(stX, sb)                                                        \
    _Pragma("unroll")                                                          \
    for (int g = 0; g < 2; g++) {                                              \
      unsigned A0 = pk2(stX[8 * g + 0], stX[8 * g + 1]);                       \
      unsigned A1 = pk2(stX[8 * g + 2], stX[8 * g + 3]);                       \
      unsigned B0 = pk2(stX[8 * g + 4], stX[8 * g + 5]);                       \
      unsigned B1 = pk2(stX[8 * g + 6], stX[8 * g + 7]);                       \
      unsigned r0 = __shfl_xor(hi ? A0 : B0, 32, 64);                          \
      unsigned r1 = __shfl_xor(hi ? A1 : B1, 32, 64);                          \
      u32x4 pw;                                                                \
      pw[0] = hi ? r0 : A0;                                                    \
      pw[1] = hi ? r1 : A1;                                                    \
      pw[2] = hi ? B0 : r0;                                                    \
      pw[3] = hi ? B1 : r1;                                                    \
      bf16x8 pa = *(bf16x8*)&pw;                                               \
      const int ks = (sb) * 2 + g;                                             \
      int pc0 = (ks * 2 + hi) ^ swz;                                           \
      bf16x8 vb0 = *(const bf16x8*)&lV[cur][(l31) * 64 + pc0 * 8];             \
      o0 = MFMA32(vb0, pa, o0);                                                \
      bf16x8 vb1 = *(const bf16x8*)&lV[cur][(32 + l31) * 64 + pc0 * 8];        \
      o1 = MFMA32(vb1, pa, o1);                                                \
      bf16x8 vb2 = *(const bf16x8*)&lV[cur][(64 + l31) * 64 + pc0 * 8];        \
      o2 = MFMA32(vb2, pa, o2);                                                \
      bf16x8 vb3 = *(const bf16x8*)&lV[cur][(96 + l31) * 64 + pc0 * 8];        \
      o3 = MFMA32(vb3, pa, o3);                                                \
    }
    PVHALF(st0, 0)
    PVHALF(st1, 1)
#undef PVHALF
    __builtin_amdgcn_s_setprio(0);

    __syncthreads();
  }

  // epilogue: O^T *= 1/l, packed 8B stores into the Y (dead V) region
  float inv = __builtin_amdgcn_rcpf(l_st);
#define WR(oN, n)                                                              \
  _Pragma("unroll")                                                            \
  for (int rq = 0; rq < 4; rq++) {                                             \
    u16x4 pk;                                                                  \
    _Pragma("unroll")                                                          \
    for (int j = 0; j < 4; j++) pk[j] = f2b(oN[rq * 4 + j] * inv);             \
    *(u16x4*)((u16*)QK + qrow + 4096 + (n) * 32 + rq * 8 + hi * 4) = pk;       \
  }
  WR(o0, 0) WR(o1, 1) WR(o2, 2) WR(o3, 3)
#undef WR
#undef STAGE
}

extern "C" void kernel_launch(void* const* d_in, const int* in_sizes, int n_in,
                              void* d_out, int out_size, void* d_ws, size_t ws_size,
                              hipStream_t stream) {
  const float* x  = (const float*)d_in[0];
  const float* Wq = (const float*)d_in[1];
  const float* Wk = (const float*)d_in[2];
  const float* Wv = (const float*)d_in[3];
  const float* Wo = (const float*)d_in[4];
  float* out = (float*)d_out;
  char* ws = (char*)d_ws;

  const long MB = 1048576L;
  // layout: xb 32MB (aliased by Vt later); Wt4 32MB (Wqt|Wkt|Wvt|Wot contiguous);
  // Cqkv 96MB = [8192][6144] (Q-raw | K-roped | V-then-Y). Total 160MB.
  u16* xb   = (u16*)(ws);
  u16* Wt4  = (u16*)(ws + 32 * MB);
  u16* Cqkv = (u16*)(ws + 64 * MB);
  u16* Vtb  = xb;   // alias: xb dead after QKV projection

  cast_f32_bf16<<<8192, 256, 0, stream>>>(x, xb);
  dim3 wt_g(32, 32, 4);
  wtrans4_kernel<<<wt_g, 256, 0, stream>>>(Wq, Wk, Wv, Wo, Wt4);

  // fused QKV projection (clean epilogue)
  gemm_bt<0><<<768, 512, 0, stream>>>(xb, 2048, Wt4, Cqkv, 8192, 6144, 2048);

  // standalone K-rope (memory-bound, ~10us); Q roped in attn at load
  rope_k_kernel<<<8192, 256, 0, stream>>>(Cqkv);

  dim3 vt_g(32, 2, 64);
  vtrans_kernel<<<vt_g, 256, 0, stream>>>(Cqkv, Vtb);

  attn_kernel<<<1024, 256, 0, stream>>>(Cqkv, Vtb);

  // output projection: reads Y from the V region (lda = 6144); Wot at Wt4 + 3*4M elems
  gemm_bt<1><<<256, 512, 0, stream>>>(Cqkv + 4096, QKV_STR, Wt4 + 3 * 4194304L,
                                      (void*)out, 8192, 2048, 2048);
}